// Round 8
// baseline (347.515 us; speedup 1.0000x reference)
//
#include <hip/hip_runtime.h>

#define NEGV (-100000000.0f)
typedef __attribute__((ext_vector_type(2))) float f32x2;

constexpr int BB = 32, MM = 24, RR = 384, DD = 2048;

// DPP helpers: row-scan add / max (VALU pipe). ctrl must be immediate.
template <int CTRL>
static __device__ __forceinline__ float dpp_add(float x) {
  int y = __builtin_amdgcn_update_dpp(0, __float_as_int(x), CTRL, 0xf, 0xf, true);
  return x + __int_as_float(y);
}
template <int CTRL>
static __device__ __forceinline__ float dpp_max(float x) {
  int y = __builtin_amdgcn_update_dpp(0, __float_as_int(x), CTRL, 0xf, 0xf, true);
  return fmaxf(x, __int_as_float(y));
}

// ---------------- Kernel A ----------------
__global__ __launch_bounds__(256) void kA(const float* __restrict__ region,
    const float* __restrict__ t0w, const float* __restrict__ t0b,
    const float* __restrict__ t1w, const float* __restrict__ t1b,
    float* __restrict__ h0h1) {
  __shared__ float rlds[32][260];
  __shared__ float wlds[256][36];
  const int t = threadIdx.x;
  const int r = t & 31;
  const int q = t >> 5;
  const int row0 = blockIdx.x * 32;
  float acc[32];
#pragma unroll
  for (int h = 0; h < 32; ++h) acc[h] = 0.f;

  for (int tile = 0; tile < 8; ++tile) {
    const int d0 = tile * 256;
    __syncthreads();
#pragma unroll
    for (int i = 0; i < 8; ++i) {
      int flat = i * 256 + t;
      int rr2 = flat >> 6;
      int cc = (flat & 63) << 2;
      *(float4*)&rlds[rr2][cc] =
          *(const float4*)(region + (size_t)(row0 + rr2) * DD + d0 + cc);
    }
#pragma unroll
    for (int h = 0; h < 32; ++h) {
      const float* wsrc = (h < 16) ? (t0w + (size_t)h * DD)
                                   : (t1w + (size_t)(h - 16) * DD);
      wlds[t][h] = wsrc[d0 + t];
    }
    __syncthreads();
    const int djb = q * 32;
#pragma unroll 4
    for (int dj = djb; dj < djb + 32; ++dj) {
      float rv = rlds[r][dj];
      const float4* wp = (const float4*)&wlds[dj][0];
#pragma unroll
      for (int h4 = 0; h4 < 8; ++h4) {
        float4 wv = wp[h4];
        acc[h4 * 4 + 0] = fmaf(rv, wv.x, acc[h4 * 4 + 0]);
        acc[h4 * 4 + 1] = fmaf(rv, wv.y, acc[h4 * 4 + 1]);
        acc[h4 * 4 + 2] = fmaf(rv, wv.z, acc[h4 * 4 + 2]);
        acc[h4 * 4 + 3] = fmaf(rv, wv.w, acc[h4 * 4 + 3]);
      }
    }
  }
  __syncthreads();
  float* red = &wlds[0][0];
#pragma unroll
  for (int h4 = 0; h4 < 8; ++h4) {
    *(float4*)&red[(q * 32 + r) * 36 + h4 * 4] =
        make_float4(acc[h4 * 4 + 0], acc[h4 * 4 + 1], acc[h4 * 4 + 2], acc[h4 * 4 + 3]);
  }
  __syncthreads();
  {
    const int r2 = t & 31;
    const int hb = (t >> 5) * 4;
    float s0 = 0, s1 = 0, s2 = 0, s3 = 0;
#pragma unroll
    for (int qq = 0; qq < 8; ++qq) {
      float4 v = *(const float4*)&red[(qq * 32 + r2) * 36 + hb];
      s0 += v.x; s1 += v.y; s2 += v.z; s3 += v.w;
    }
    float4 bias = (hb < 16) ? *(const float4*)(t0b + hb)
                            : *(const float4*)(t1b + hb - 16);
    *(float4*)(h0h1 + (size_t)(row0 + r2) * 32 + hb) =
        make_float4(s0 + bias.x, s1 + bias.y, s2 + bias.z, s3 + bias.w);
  }
}

// ---------------- Kernel CM: rsum + Em + compact active-m list --------------
__global__ __launch_bounds__(64) void kCM(const float* __restrict__ gt,
    const float* __restrict__ aff, const int* __restrict__ nmen,
    const int* __restrict__ nreg, float* __restrict__ rsum,
    float* __restrict__ Em, int* __restrict__ mlist, int* __restrict__ kcnt) {
  const int b = blockIdx.x;
  const int lane = threadIdx.x;
  const int nm = nmen[b], nr = nreg[b];
  int c = 0;
  for (int m = 0; m < MM; ++m) {
    const size_t bm = (size_t)(b * MM + m);
    float p = 0.f, t1 = 0.f, t2 = 0.f;
#pragma unroll
    for (int i = 0; i < 6; ++i) {
      int s = lane * 6 + i;
      float g = gt[bm * RR + s];
      float a = (g >= 0.5f && s < nr && m < nm) ? g : 0.f;
      float e = aff[bm * RR + s];
      p += a;
      t1 += a * e;
      t2 += (a > 0.f) ? a * __logf(a) : 0.f;
    }
#pragma unroll
    for (int off = 32; off > 0; off >>= 1) {
      p += __shfl_xor(p, off);
      t1 += __shfl_xor(t1, off);
      t2 += __shfl_xor(t2, off);
    }
    if (lane == 0) {
      rsum[bm] = p;
      Em[bm] = (p > 0.f) ? (t1 - t2) / p + __logf(p) : 0.f;
      if (p > 0.f) mlist[b * MM + (c++)] = m;
    }
  }
  if (lane == 0) {
    kcnt[b] = c;
    for (int j = c; j < MM; ++j) mlist[b * MM + j] = 0;
  }
}

// ---------------- Kernel YT: bilinP partials + fp8 expT export --------------
// grid 256 = (b x 8 chunks of 48 rows), 192 threads = (48 rows x 4 jq of 96 s)
__global__ __launch_bounds__(192) void kYT(const float* __restrict__ h0h1,
    const float* __restrict__ trw, const float* __restrict__ trb,
    const float* __restrict__ gt, const int* __restrict__ nreg,
    const float* __restrict__ rsum, const int* __restrict__ mlist,
    const int* __restrict__ kcnt, float* __restrict__ bilinP,
    unsigned char* __restrict__ expb, float* __restrict__ expTmax) {
  __shared__ float h1T[16][388];
  __shared__ float h0L[48][16];
  __shared__ float Tl[48][388];
  __shared__ float RP[MM][392];
  __shared__ float part[48][26];
  const int b = blockIdx.x & 31;
  const int chunk = blockIdx.x >> 5;
  const int r0 = chunk * 48;
  const int tid = threadIdx.x;
  const int K = kcnt[b];
  const int nr = nreg[b];

  for (int h = 0; h < 16; ++h)
    for (int s = tid; s < RR; s += 192)
      h1T[h][s] = h0h1[((size_t)b * RR + s) * 32 + 16 + h];
  for (int i = tid; i < 768; i += 192) {
    int row = i >> 4, h = i & 15;
    h0L[row][h] = h0h1[((size_t)b * RR + r0 + row) * 32 + h];
  }
  for (int j = 0; j < MM; ++j) {
    if (j < K) {
      int m = mlist[b * MM + j];
      float inv = 1.f / rsum[b * MM + m];
      for (int s = tid; s < RR; s += 192) {
        float g = gt[((size_t)(b * MM + m)) * RR + s];
        RP[j][s] = (g >= 0.5f && s < nr) ? g * inv : 0.f;
      }
    } else {
      for (int s = tid; s < RR; s += 192) RP[j][s] = 0.f;
    }
  }
  float w0[16];
#pragma unroll
  for (int h = 0; h < 16; ++h) w0[h] = trw[h];
  const float tb = trb[0];
  __syncthreads();

  const int r = tid >> 2;
  const int jq = tid & 3;
  const int gr = r0 + r;

  for (int s = jq * 96; s < jq * 96 + 96; ++s) {
    float a = tb;
#pragma unroll
    for (int h = 0; h < 16; ++h)
      a += fmaxf(h0L[r][h] + h1T[h][s], 0.f) * w0[h];
    Tl[r][s] = a;
  }
  __syncthreads();

  // ---- fp8 export: row max over 4 jq lanes, exp(t - rmax) packed e4m3 ----
  {
    float rmax = -3.0e38f;
    for (int c = 0; c < 96; c += 4) {
      float4 v = *(const float4*)&Tl[r][jq * 96 + c];
      rmax = fmaxf(rmax, fmaxf(fmaxf(v.x, v.y), fmaxf(v.z, v.w)));
    }
    rmax = fmaxf(rmax, __shfl_xor(rmax, 1));
    rmax = fmaxf(rmax, __shfl_xor(rmax, 2));
    if (jq == 0) expTmax[b * RR + gr] = __expf(rmax);
    unsigned char* obase = expb + ((size_t)b * RR + gr) * RR + jq * 96;
#pragma unroll
    for (int c16 = 0; c16 < 6; ++c16) {
      int w4[4];
#pragma unroll
      for (int ii = 0; ii < 4; ++ii) {
        float4 v = *(const float4*)&Tl[r][jq * 96 + c16 * 16 + ii * 4];
        int pk = __builtin_amdgcn_cvt_pk_fp8_f32(__expf(v.x - rmax),
                                                 __expf(v.y - rmax), 0, false);
        pk = __builtin_amdgcn_cvt_pk_fp8_f32(__expf(v.z - rmax),
                                             __expf(v.w - rmax), pk, true);
        w4[ii] = pk;
      }
      *(int4*)(obase + c16 * 16) = make_int4(w4[0], w4[1], w4[2], w4[3]);
    }
  }

  // ---- bilinear partials (unchanged) ----
  float acc[6] = {0, 0, 0, 0, 0, 0};
  for (int s0 = 0; s0 < RR; s0 += 4) {
    float4 tv = *(const float4*)&Tl[r][s0];
#pragma unroll
    for (int jj = 0; jj < 6; ++jj) {
      const float4 p0 = *(const float4*)&RP[jq * 6 + jj][s0];
      acc[jj] = fmaf(tv.x, p0.x, acc[jj]);
      acc[jj] = fmaf(tv.y, p0.y, acc[jj]);
      acc[jj] = fmaf(tv.z, p0.z, acc[jj]);
      acc[jj] = fmaf(tv.w, p0.w, acc[jj]);
    }
  }
#pragma unroll
  for (int jj = 0; jj < 6; ++jj) {
    const int jp = jq * 6 + jj;
    const int j = jp + 1;
    part[r][j] = (j < K) ? RP[j][gr] * acc[jj] : 0.f;
  }
  __syncthreads();
  if (tid < MM) {
    const int j = tid;
    float s = 0.f;
    if (j >= 1) {
#pragma unroll 4
      for (int rr2 = 0; rr2 < 48; ++rr2) s += part[rr2][j];
    }
    bilinP[(size_t)(b * 8 + chunk) * MM + j] = s;
  }
}

// ---------------- Kernel D: linear-space scan, expT in registers (fp8) ------
__global__ __launch_bounds__(1024) void kD(
    const unsigned char* __restrict__ expb, const float* __restrict__ expTmax,
    const float* __restrict__ aff, const int* __restrict__ nreg,
    const int* __restrict__ mlist, const int* __restrict__ kcnt,
    const float* __restrict__ Em, const float* __restrict__ bilinP,
    float* __restrict__ result) {
  __shared__ float tL[2][16][28];
  __shared__ float wmax[2][16];
  __shared__ float fred[16];

  const int b = blockIdx.x;
  const int tid = threadIdx.x;
  const int w = tid >> 6;
  const int lane = tid & 63;
  const int lam = lane & 15;
  const int g = lane >> 4;
  const int nr = nreg[b];

  const int K = kcnt[b];
  if (K == 0) {
    if (tid == 0) result[b] = 0.f;
    return;
  }

  const int myrow0 = w * 24;
  const unsigned char* ebase = expb + (size_t)b * RR * RR;

  // ---- prologue: my expT' tile (6 rows x 24 cols fp8) into registers ----
  int pk0[6], pk1[6], pk2[6], pk3[6], pk4[6], pk5[6];
  float sF[6];
  {
#pragma unroll
    for (int p = 0; p < 6; ++p) {
      const int row = myrow0 + p * 4 + g;
      const int2* ep = (const int2*)(ebase + (size_t)row * RR + lam * 24);
      int2 a0 = ep[0], a1 = ep[1], a2 = ep[2];
      pk0[p] = a0.x; pk1[p] = a0.y; pk2[p] = a1.x;
      pk3[p] = a1.y; pk4[p] = a2.x; pk5[p] = a2.y;
      sF[p] = expTmax[b * RR + row];
    }
  }

  // prefetch step-0 emissions
  float eraw[6];
  {
    const int m0 = mlist[b * MM];
    const float* arow = aff + ((size_t)(b * MM + m0)) * RR;
#pragma unroll
    for (int p = 0; p < 6; ++p) eraw[p] = arow[myrow0 + p * 4 + g];
  }

  float L = 0.f;

  for (int k = 0; k < K; ++k) {
    const int q = k & 1;

    float nraw[6] = {0, 0, 0, 0, 0, 0};
    if (k + 1 < K) {
      const int mn = mlist[b * MM + k + 1];
      const float* arow = aff + ((size_t)(b * MM + mn)) * RR;
#pragma unroll
      for (int p = 0; p < 6; ++p) nraw[p] = arow[myrow0 + p * 4 + g];
    }

    float lmaxv = 0.f;                       // t >= 0 always
    if (k == 0) {
#pragma unroll
      for (int p = 0; p < 6; ++p) {
        const int row = myrow0 + p * 4 + g;
        const float t = (row < nr) ? __expf(eraw[p]) : 0.f;
        if (lam == 15) {
          tL[q][w][p * 4 + g] = t;
          lmaxv = fmaxf(lmaxv, t);
        }
      }
    } else {
      // Z = max over previous block maxima; fold 1/Z + row scale into factor
      const float4* wm4 = (const float4*)&wmax[q ^ 1][0];
      float4 m0 = wm4[0], m1 = wm4[1], m2 = wm4[2], m3 = wm4[3];
      float4 mm01 = make_float4(fmaxf(m0.x, m1.x), fmaxf(m0.y, m1.y),
                                fmaxf(m0.z, m1.z), fmaxf(m0.w, m1.w));
      float4 mm23 = make_float4(fmaxf(m2.x, m3.x), fmaxf(m2.y, m3.y),
                                fmaxf(m2.z, m3.z), fmaxf(m2.w, m3.w));
      const float Z = fmaxf(fmaxf(fmaxf(mm01.x, mm01.y), fmaxf(mm01.z, mm01.w)),
                            fmaxf(fmaxf(mm23.x, mm23.y), fmaxf(mm23.z, mm23.w)));
      const float invZ = 1.f / Z;
      L += __logf(Z);
      float cf[6];
#pragma unroll
      for (int p = 0; p < 6; ++p) cf[p] = __expf(eraw[p]) * invZ * sF[p];

      // xr: previous t values for my 24-column chunk
      f32x2 xr2[12];
#pragma unroll
      for (int j4 = 0; j4 < 6; ++j4) {
        float4 v = *(const float4*)&tL[q ^ 1][lam][j4 * 4];
        f32x2 lo, hiw;
        lo.x = v.x; lo.y = v.y; hiw.x = v.z; hiw.y = v.w;
        xr2[j4 * 2] = lo;
        xr2[j4 * 2 + 1] = hiw;
      }

#pragma unroll
      for (int p = 0; p < 6; ++p) {
        f32x2 acc;
        acc.x = 0.f; acc.y = 0.f;
        const int pkv[6] = {pk0[p], pk1[p], pk2[p], pk3[p], pk4[p], pk5[p]};
#pragma unroll
        for (int j = 0; j < 6; ++j) {
          f32x2 lo = __builtin_amdgcn_cvt_pk_f32_fp8(pkv[j], false);
          f32x2 hi = __builtin_amdgcn_cvt_pk_f32_fp8(pkv[j], true);
          acc += lo * xr2[2 * j];              // v_pk_fma_f32
          acc += hi * xr2[2 * j + 1];
        }
        float asum = acc.x + acc.y;
        // 16-lane inclusive scan (VALU DPP): total lands at lam==15
        asum = dpp_add<0x111>(asum);
        asum = dpp_add<0x112>(asum);
        asum = dpp_add<0x114>(asum);
        asum = dpp_add<0x118>(asum);
        const float t = asum * cf[p];
        if (lam == 15) {
          tL[q][w][p * 4 + g] = t;
          lmaxv = fmaxf(lmaxv, t);
        }
      }
    }
    // wave max (valid at lam==15 lanes; 0 elsewhere) via DPP
    lmaxv = dpp_max<0x111>(lmaxv);
    lmaxv = dpp_max<0x112>(lmaxv);
    lmaxv = dpp_max<0x114>(lmaxv);
    lmaxv = dpp_max<0x118>(lmaxv);
    lmaxv = dpp_max<0x142>(lmaxv);             // bcast15
    lmaxv = dpp_max<0x143>(lmaxv);             // bcast31
    if (lane == 63) wmax[q][w] = lmaxv;
#pragma unroll
    for (int p = 0; p < 6; ++p) eraw[p] = nraw[p];
    __syncthreads();
  }

  // epilogue: fwd = L + log(sum_r t_r); gold from precomputed bilin/Em
  const int qf = (K - 1) & 1;
  float fp = (tid < RR) ? tL[qf][tid / 24][tid % 24] : 0.f;
#pragma unroll
  for (int off = 32; off > 0; off >>= 1) fp += __shfl_xor(fp, off);
  if (lane == 0) fred[w] = fp;
  __syncthreads();
  if (tid == 0) {
    float fs = 0.f;
#pragma unroll
    for (int i = 0; i < 16; ++i) fs += fred[i];
    const float fwd = L + __logf(fmaxf(fs, 1e-37f));
    float gold = Em[b * MM + mlist[b * MM + 0]];
    for (int j = 1; j < K; ++j) {
      float bil = 0.f;
#pragma unroll
      for (int c = 0; c < 8; ++c) bil += bilinP[(size_t)(b * 8 + c) * MM + j];
      gold += bil + Em[b * MM + mlist[b * MM + j]];
    }
    result[b] = fwd - gold;
  }
}

// ---------------- Kernel E: final deterministic reduction ----------
__global__ void kE(const float* __restrict__ result, const int* __restrict__ nmen,
                   float* __restrict__ out) {
  if (threadIdx.x == 0 && blockIdx.x == 0) {
    float s = 0.f;
    int d = 0;
    for (int b = 0; b < 32; ++b) { s += result[b]; d += nmen[b]; }
    if (d < 1) d = 1;
    out[0] = s / (float)d;
  }
}

extern "C" void kernel_launch(void* const* d_in, const int* in_sizes, int n_in,
                              void* d_out, int out_size, void* d_ws, size_t ws_size,
                              hipStream_t stream) {
  const float* region = (const float*)d_in[0];
  const float* aff    = (const float*)d_in[1];
  const float* gt     = (const float*)d_in[2];
  const int*   nmen   = (const int*)d_in[3];
  const int*   nreg   = (const int*)d_in[4];
  const float* t0w    = (const float*)d_in[5];
  const float* t0b    = (const float*)d_in[6];
  const float* t1w    = (const float*)d_in[7];
  const float* t1b    = (const float*)d_in[8];
  const float* trw    = (const float*)d_in[9];
  const float* trb    = (const float*)d_in[10];
  float* out = (float*)d_out;
  char* ws = (char*)d_ws;

  size_t off = 0;
  auto alloc = [&](size_t bytes) {
    void* p = ws + off;
    off += (bytes + 255) & ~(size_t)255;
    return p;
  };
  float*         h0h1    = (float*)alloc((size_t)BB * RR * 32 * 4);       // 1.57 MB
  unsigned char* expb    = (unsigned char*)alloc((size_t)BB * RR * RR);   // 4.72 MB
  float*         expTmax = (float*)alloc((size_t)BB * RR * 4);            // 49 KB
  float*         rsum    = (float*)alloc((size_t)BB * MM * 4);
  int*           mlist   = (int*)alloc((size_t)BB * MM * 4);
  int*           kcnt    = (int*)alloc((size_t)BB * 4);
  float*         Em      = (float*)alloc((size_t)BB * MM * 4);
  float*         bilinP  = (float*)alloc((size_t)BB * 8 * MM * 4);
  float*         result  = (float*)alloc((size_t)BB * 4);

  kA<<<(BB * RR) / 32, 256, 0, stream>>>(region, t0w, t0b, t1w, t1b, h0h1);
  kCM<<<BB, 64, 0, stream>>>(gt, aff, nmen, nreg, rsum, Em, mlist, kcnt);
  kYT<<<256, 192, 0, stream>>>(h0h1, trw, trb, gt, nreg, rsum, mlist, kcnt,
                               bilinP, expb, expTmax);
  kD<<<BB, 1024, 0, stream>>>(expb, expTmax, aff, nreg, mlist, kcnt, Em,
                              bilinP, result);
  kE<<<1, 64, 0, stream>>>(result, nmen, out);
}

// Round 9
// 347.151 us; speedup vs baseline: 1.0011x; 1.0011x over previous
//
#include <hip/hip_runtime.h>

#define NEGV (-100000000.0f)
typedef __attribute__((ext_vector_type(2))) float f32x2;

constexpr int BB = 32, MM = 24, RR = 384, DD = 2048;

// DPP helpers: row-scan add / max (VALU pipe). ctrl must be immediate.
template <int CTRL>
static __device__ __forceinline__ float dpp_add(float x) {
  int y = __builtin_amdgcn_update_dpp(0, __float_as_int(x), CTRL, 0xf, 0xf, true);
  return x + __int_as_float(y);
}
template <int CTRL>
static __device__ __forceinline__ float dpp_max(float x) {
  int y = __builtin_amdgcn_update_dpp(0, __float_as_int(x), CTRL, 0xf, 0xf, true);
  return fmaxf(x, __int_as_float(y));
}

// ---------------- Kernel A ----------------
__global__ __launch_bounds__(256) void kA(const float* __restrict__ region,
    const float* __restrict__ t0w, const float* __restrict__ t0b,
    const float* __restrict__ t1w, const float* __restrict__ t1b,
    float* __restrict__ h0h1) {
  __shared__ float rlds[32][260];
  __shared__ float wlds[256][36];
  const int t = threadIdx.x;
  const int r = t & 31;
  const int q = t >> 5;
  const int row0 = blockIdx.x * 32;
  float acc[32];
#pragma unroll
  for (int h = 0; h < 32; ++h) acc[h] = 0.f;

  for (int tile = 0; tile < 8; ++tile) {
    const int d0 = tile * 256;
    __syncthreads();
#pragma unroll
    for (int i = 0; i < 8; ++i) {
      int flat = i * 256 + t;
      int rr2 = flat >> 6;
      int cc = (flat & 63) << 2;
      *(float4*)&rlds[rr2][cc] =
          *(const float4*)(region + (size_t)(row0 + rr2) * DD + d0 + cc);
    }
#pragma unroll
    for (int h = 0; h < 32; ++h) {
      const float* wsrc = (h < 16) ? (t0w + (size_t)h * DD)
                                   : (t1w + (size_t)(h - 16) * DD);
      wlds[t][h] = wsrc[d0 + t];
    }
    __syncthreads();
    const int djb = q * 32;
#pragma unroll 4
    for (int dj = djb; dj < djb + 32; ++dj) {
      float rv = rlds[r][dj];
      const float4* wp = (const float4*)&wlds[dj][0];
#pragma unroll
      for (int h4 = 0; h4 < 8; ++h4) {
        float4 wv = wp[h4];
        acc[h4 * 4 + 0] = fmaf(rv, wv.x, acc[h4 * 4 + 0]);
        acc[h4 * 4 + 1] = fmaf(rv, wv.y, acc[h4 * 4 + 1]);
        acc[h4 * 4 + 2] = fmaf(rv, wv.z, acc[h4 * 4 + 2]);
        acc[h4 * 4 + 3] = fmaf(rv, wv.w, acc[h4 * 4 + 3]);
      }
    }
  }
  __syncthreads();
  float* red = &wlds[0][0];
#pragma unroll
  for (int h4 = 0; h4 < 8; ++h4) {
    *(float4*)&red[(q * 32 + r) * 36 + h4 * 4] =
        make_float4(acc[h4 * 4 + 0], acc[h4 * 4 + 1], acc[h4 * 4 + 2], acc[h4 * 4 + 3]);
  }
  __syncthreads();
  {
    const int r2 = t & 31;
    const int hb = (t >> 5) * 4;
    float s0 = 0, s1 = 0, s2 = 0, s3 = 0;
#pragma unroll
    for (int qq = 0; qq < 8; ++qq) {
      float4 v = *(const float4*)&red[(qq * 32 + r2) * 36 + hb];
      s0 += v.x; s1 += v.y; s2 += v.z; s3 += v.w;
    }
    float4 bias = (hb < 16) ? *(const float4*)(t0b + hb)
                            : *(const float4*)(t1b + hb - 16);
    *(float4*)(h0h1 + (size_t)(row0 + r2) * 32 + hb) =
        make_float4(s0 + bias.x, s1 + bias.y, s2 + bias.z, s3 + bias.w);
  }
}

// ---------------- Kernel CM: rsum + Em + compact active-m list --------------
__global__ __launch_bounds__(64) void kCM(const float* __restrict__ gt,
    const float* __restrict__ aff, const int* __restrict__ nmen,
    const int* __restrict__ nreg, float* __restrict__ rsum,
    float* __restrict__ Em, int* __restrict__ mlist, int* __restrict__ kcnt) {
  const int b = blockIdx.x;
  const int lane = threadIdx.x;
  const int nm = nmen[b], nr = nreg[b];
  int c = 0;
  for (int m = 0; m < MM; ++m) {
    const size_t bm = (size_t)(b * MM + m);
    float p = 0.f, t1 = 0.f, t2 = 0.f;
#pragma unroll
    for (int i = 0; i < 6; ++i) {
      int s = lane * 6 + i;
      float g = gt[bm * RR + s];
      float a = (g >= 0.5f && s < nr && m < nm) ? g : 0.f;
      float e = aff[bm * RR + s];
      p += a;
      t1 += a * e;
      t2 += (a > 0.f) ? a * __logf(a) : 0.f;
    }
#pragma unroll
    for (int off = 32; off > 0; off >>= 1) {
      p += __shfl_xor(p, off);
      t1 += __shfl_xor(t1, off);
      t2 += __shfl_xor(t2, off);
    }
    if (lane == 0) {
      rsum[bm] = p;
      Em[bm] = (p > 0.f) ? (t1 - t2) / p + __logf(p) : 0.f;
      if (p > 0.f) mlist[b * MM + (c++)] = m;
    }
  }
  if (lane == 0) {
    kcnt[b] = c;
    for (int j = c; j < MM; ++j) mlist[b * MM + j] = 0;
  }
}

// ---------------- Kernel YT: bilinP partials + fp8 expT export --------------
// grid 256 = (b x 8 chunks of 48 rows), 192 threads = (48 rows x 4 jq of 96 s)
__global__ __launch_bounds__(192) void kYT(const float* __restrict__ h0h1,
    const float* __restrict__ trw, const float* __restrict__ trb,
    const float* __restrict__ gt, const int* __restrict__ nreg,
    const float* __restrict__ rsum, const int* __restrict__ mlist,
    const int* __restrict__ kcnt, float* __restrict__ bilinP,
    unsigned char* __restrict__ expb, float* __restrict__ expTmax) {
  __shared__ float h1T[16][388];
  __shared__ float h0L[48][16];
  __shared__ float Tl[48][388];
  __shared__ float RP[MM][392];
  __shared__ float part[48][26];
  const int b = blockIdx.x & 31;
  const int chunk = blockIdx.x >> 5;
  const int r0 = chunk * 48;
  const int tid = threadIdx.x;
  const int K = kcnt[b];
  const int nr = nreg[b];

  for (int h = 0; h < 16; ++h)
    for (int s = tid; s < RR; s += 192)
      h1T[h][s] = h0h1[((size_t)b * RR + s) * 32 + 16 + h];
  for (int i = tid; i < 768; i += 192) {
    int row = i >> 4, h = i & 15;
    h0L[row][h] = h0h1[((size_t)b * RR + r0 + row) * 32 + h];
  }
  for (int j = 0; j < MM; ++j) {
    if (j < K) {
      int m = mlist[b * MM + j];
      float inv = 1.f / rsum[b * MM + m];
      for (int s = tid; s < RR; s += 192) {
        float g = gt[((size_t)(b * MM + m)) * RR + s];
        RP[j][s] = (g >= 0.5f && s < nr) ? g * inv : 0.f;
      }
    } else {
      for (int s = tid; s < RR; s += 192) RP[j][s] = 0.f;
    }
  }
  float w0[16];
#pragma unroll
  for (int h = 0; h < 16; ++h) w0[h] = trw[h];
  const float tb = trb[0];
  __syncthreads();

  const int r = tid >> 2;
  const int jq = tid & 3;
  const int gr = r0 + r;

  for (int s = jq * 96; s < jq * 96 + 96; ++s) {
    float a = tb;
#pragma unroll
    for (int h = 0; h < 16; ++h)
      a += fmaxf(h0L[r][h] + h1T[h][s], 0.f) * w0[h];
    Tl[r][s] = a;
  }
  __syncthreads();

  // ---- fp8 export: row max over 4 jq lanes, exp(t - rmax) packed e4m3 ----
  {
    float rmax = -3.0e38f;
    for (int c = 0; c < 96; c += 4) {
      float4 v = *(const float4*)&Tl[r][jq * 96 + c];
      rmax = fmaxf(rmax, fmaxf(fmaxf(v.x, v.y), fmaxf(v.z, v.w)));
    }
    rmax = fmaxf(rmax, __shfl_xor(rmax, 1));
    rmax = fmaxf(rmax, __shfl_xor(rmax, 2));
    if (jq == 0) expTmax[b * RR + gr] = __expf(rmax);
    unsigned char* obase = expb + ((size_t)b * RR + gr) * RR + jq * 96;
#pragma unroll
    for (int c16 = 0; c16 < 6; ++c16) {
      int w4[4];
#pragma unroll
      for (int ii = 0; ii < 4; ++ii) {
        float4 v = *(const float4*)&Tl[r][jq * 96 + c16 * 16 + ii * 4];
        int pk = __builtin_amdgcn_cvt_pk_fp8_f32(__expf(v.x - rmax),
                                                 __expf(v.y - rmax), 0, false);
        pk = __builtin_amdgcn_cvt_pk_fp8_f32(__expf(v.z - rmax),
                                             __expf(v.w - rmax), pk, true);
        w4[ii] = pk;
      }
      *(int4*)(obase + c16 * 16) = make_int4(w4[0], w4[1], w4[2], w4[3]);
    }
  }

  // ---- bilinear partials ----
  float acc[6] = {0, 0, 0, 0, 0, 0};
  for (int s0 = 0; s0 < RR; s0 += 4) {
    float4 tv = *(const float4*)&Tl[r][s0];
#pragma unroll
    for (int jj = 0; jj < 6; ++jj) {
      const float4 p0 = *(const float4*)&RP[jq * 6 + jj][s0];
      acc[jj] = fmaf(tv.x, p0.x, acc[jj]);
      acc[jj] = fmaf(tv.y, p0.y, acc[jj]);
      acc[jj] = fmaf(tv.z, p0.z, acc[jj]);
      acc[jj] = fmaf(tv.w, p0.w, acc[jj]);
    }
  }
#pragma unroll
  for (int jj = 0; jj < 6; ++jj) {
    const int jp = jq * 6 + jj;
    const int j = jp + 1;
    part[r][j] = (j < K) ? RP[j][gr] * acc[jj] : 0.f;
  }
  __syncthreads();
  if (tid < MM) {
    const int j = tid;
    float s = 0.f;
    if (j >= 1) {
#pragma unroll 4
      for (int rr2 = 0; rr2 < 48; ++rr2) s += part[rr2][j];
    }
    bilinP[(size_t)(b * 8 + chunk) * MM + j] = s;
  }
}

// ---------------- Kernel D: linear-space scan, expT in registers (fp8) ------
// __launch_bounds__(1024, 4): 4 waves/EU = our single 16-wave block per CU;
// permits 128 VGPRs/wave so the 36-int fp8 tile stays in registers (no spill).
__global__ __launch_bounds__(1024, 4) void kD(
    const unsigned char* __restrict__ expb, const float* __restrict__ expTmax,
    const float* __restrict__ aff, const int* __restrict__ nreg,
    const int* __restrict__ mlist, const int* __restrict__ kcnt,
    const float* __restrict__ Em, const float* __restrict__ bilinP,
    float* __restrict__ result) {
  __shared__ float tL[2][16][28];
  __shared__ float wmax[2][16];
  __shared__ float fred[16];

  const int b = blockIdx.x;
  const int tid = threadIdx.x;
  const int w = tid >> 6;
  const int lane = tid & 63;
  const int lam = lane & 15;
  const int g = lane >> 4;
  const int nr = nreg[b];

  const int K = kcnt[b];
  if (K == 0) {
    if (tid == 0) result[b] = 0.f;
    return;
  }

  const int myrow0 = w * 24;
  const unsigned char* ebase = expb + (size_t)b * RR * RR;

  // ---- prologue: my expT' tile (6 rows x 24 cols fp8) into registers ----
  int pk0[6], pk1[6], pk2[6], pk3[6], pk4[6], pk5[6];
  float sF[6];
  {
#pragma unroll
    for (int p = 0; p < 6; ++p) {
      const int row = myrow0 + p * 4 + g;
      const int2* ep = (const int2*)(ebase + (size_t)row * RR + lam * 24);
      int2 a0 = ep[0], a1 = ep[1], a2 = ep[2];
      pk0[p] = a0.x; pk1[p] = a0.y; pk2[p] = a1.x;
      pk3[p] = a1.y; pk4[p] = a2.x; pk5[p] = a2.y;
      sF[p] = expTmax[b * RR + row];
    }
  }

  // prefetch step-0 emissions
  float eraw[6];
  {
    const int m0 = mlist[b * MM];
    const float* arow = aff + ((size_t)(b * MM + m0)) * RR;
#pragma unroll
    for (int p = 0; p < 6; ++p) eraw[p] = arow[myrow0 + p * 4 + g];
  }

  float L = 0.f;

  for (int k = 0; k < K; ++k) {
    const int q = k & 1;

    float nraw[6] = {0, 0, 0, 0, 0, 0};
    if (k + 1 < K) {
      const int mn = mlist[b * MM + k + 1];
      const float* arow = aff + ((size_t)(b * MM + mn)) * RR;
#pragma unroll
      for (int p = 0; p < 6; ++p) nraw[p] = arow[myrow0 + p * 4 + g];
    }

    float lmaxv = 0.f;                       // t >= 0 always
    if (k == 0) {
#pragma unroll
      for (int p = 0; p < 6; ++p) {
        const int row = myrow0 + p * 4 + g;
        const float t = (row < nr) ? __expf(eraw[p]) : 0.f;
        if (lam == 15) {
          tL[q][w][p * 4 + g] = t;
          lmaxv = fmaxf(lmaxv, t);
        }
      }
    } else {
      // Z = max over previous block maxima; fold 1/Z + row scale into factor
      const float4* wm4 = (const float4*)&wmax[q ^ 1][0];
      float4 m0 = wm4[0], m1 = wm4[1], m2 = wm4[2], m3 = wm4[3];
      float4 mm01 = make_float4(fmaxf(m0.x, m1.x), fmaxf(m0.y, m1.y),
                                fmaxf(m0.z, m1.z), fmaxf(m0.w, m1.w));
      float4 mm23 = make_float4(fmaxf(m2.x, m3.x), fmaxf(m2.y, m3.y),
                                fmaxf(m2.z, m3.z), fmaxf(m2.w, m3.w));
      const float Z = fmaxf(fmaxf(fmaxf(mm01.x, mm01.y), fmaxf(mm01.z, mm01.w)),
                            fmaxf(fmaxf(mm23.x, mm23.y), fmaxf(mm23.z, mm23.w)));
      const float invZ = 1.f / Z;
      L += __logf(Z);
      float cf[6];
#pragma unroll
      for (int p = 0; p < 6; ++p) cf[p] = __expf(eraw[p]) * invZ * sF[p];

      // xr: previous t values for my 24-column chunk
      f32x2 xr2[12];
#pragma unroll
      for (int j4 = 0; j4 < 6; ++j4) {
        float4 v = *(const float4*)&tL[q ^ 1][lam][j4 * 4];
        f32x2 lo, hiw;
        lo.x = v.x; lo.y = v.y; hiw.x = v.z; hiw.y = v.w;
        xr2[j4 * 2] = lo;
        xr2[j4 * 2 + 1] = hiw;
      }

#pragma unroll
      for (int p = 0; p < 6; ++p) {
        f32x2 acc;
        acc.x = 0.f; acc.y = 0.f;
        const int pkv[6] = {pk0[p], pk1[p], pk2[p], pk3[p], pk4[p], pk5[p]};
#pragma unroll
        for (int j = 0; j < 6; ++j) {
          f32x2 lo = __builtin_amdgcn_cvt_pk_f32_fp8(pkv[j], false);
          f32x2 hi = __builtin_amdgcn_cvt_pk_f32_fp8(pkv[j], true);
          acc += lo * xr2[2 * j];              // v_pk_fma_f32
          acc += hi * xr2[2 * j + 1];
        }
        float asum = acc.x + acc.y;
        // 16-lane inclusive scan (VALU DPP): total lands at lam==15
        asum = dpp_add<0x111>(asum);
        asum = dpp_add<0x112>(asum);
        asum = dpp_add<0x114>(asum);
        asum = dpp_add<0x118>(asum);
        const float t = asum * cf[p];
        if (lam == 15) {
          tL[q][w][p * 4 + g] = t;
          lmaxv = fmaxf(lmaxv, t);
        }
      }
    }
    // wave max (valid at lam==15 lanes; 0 elsewhere) via DPP
    lmaxv = dpp_max<0x111>(lmaxv);
    lmaxv = dpp_max<0x112>(lmaxv);
    lmaxv = dpp_max<0x114>(lmaxv);
    lmaxv = dpp_max<0x118>(lmaxv);
    lmaxv = dpp_max<0x142>(lmaxv);             // bcast15
    lmaxv = dpp_max<0x143>(lmaxv);             // bcast31
    if (lane == 63) wmax[q][w] = lmaxv;
#pragma unroll
    for (int p = 0; p < 6; ++p) eraw[p] = nraw[p];
    __syncthreads();
  }

  // epilogue: fwd = L + log(sum_r t_r); gold from precomputed bilin/Em
  const int qf = (K - 1) & 1;
  float fp = (tid < RR) ? tL[qf][tid / 24][tid % 24] : 0.f;
#pragma unroll
  for (int off = 32; off > 0; off >>= 1) fp += __shfl_xor(fp, off);
  if (lane == 0) fred[w] = fp;
  __syncthreads();
  if (tid == 0) {
    float fs = 0.f;
#pragma unroll
    for (int i = 0; i < 16; ++i) fs += fred[i];
    const float fwd = L + __logf(fmaxf(fs, 1e-37f));
    float gold = Em[b * MM + mlist[b * MM + 0]];
    for (int j = 1; j < K; ++j) {
      float bil = 0.f;
#pragma unroll
      for (int c = 0; c < 8; ++c) bil += bilinP[(size_t)(b * 8 + c) * MM + j];
      gold += bil + Em[b * MM + mlist[b * MM + j]];
    }
    result[b] = fwd - gold;
  }
}

// ---------------- Kernel E: final deterministic reduction ----------
__global__ void kE(const float* __restrict__ result, const int* __restrict__ nmen,
                   float* __restrict__ out) {
  if (threadIdx.x == 0 && blockIdx.x == 0) {
    float s = 0.f;
    int d = 0;
    for (int b = 0; b < 32; ++b) { s += result[b]; d += nmen[b]; }
    if (d < 1) d = 1;
    out[0] = s / (float)d;
  }
}

extern "C" void kernel_launch(void* const* d_in, const int* in_sizes, int n_in,
                              void* d_out, int out_size, void* d_ws, size_t ws_size,
                              hipStream_t stream) {
  const float* region = (const float*)d_in[0];
  const float* aff    = (const float*)d_in[1];
  const float* gt     = (const float*)d_in[2];
  const int*   nmen   = (const int*)d_in[3];
  const int*   nreg   = (const int*)d_in[4];
  const float* t0w    = (const float*)d_in[5];
  const float* t0b    = (const float*)d_in[6];
  const float* t1w    = (const float*)d_in[7];
  const float* t1b    = (const float*)d_in[8];
  const float* trw    = (const float*)d_in[9];
  const float* trb    = (const float*)d_in[10];
  float* out = (float*)d_out;
  char* ws = (char*)d_ws;

  size_t off = 0;
  auto alloc = [&](size_t bytes) {
    void* p = ws + off;
    off += (bytes + 255) & ~(size_t)255;
    return p;
  };
  float*         h0h1    = (float*)alloc((size_t)BB * RR * 32 * 4);       // 1.57 MB
  unsigned char* expb    = (unsigned char*)alloc((size_t)BB * RR * RR);   // 4.72 MB
  float*         expTmax = (float*)alloc((size_t)BB * RR * 4);            // 49 KB
  float*         rsum    = (float*)alloc((size_t)BB * MM * 4);
  int*           mlist   = (int*)alloc((size_t)BB * MM * 4);
  int*           kcnt    = (int*)alloc((size_t)BB * 4);
  float*         Em      = (float*)alloc((size_t)BB * MM * 4);
  float*         bilinP  = (float*)alloc((size_t)BB * 8 * MM * 4);
  float*         result  = (float*)alloc((size_t)BB * 4);

  kA<<<(BB * RR) / 32, 256, 0, stream>>>(region, t0w, t0b, t1w, t1b, h0h1);
  kCM<<<BB, 64, 0, stream>>>(gt, aff, nmen, nreg, rsum, Em, mlist, kcnt);
  kYT<<<256, 192, 0, stream>>>(h0h1, trw, trb, gt, nreg, rsum, mlist, kcnt,
                               bilinP, expb, expTmax);
  kD<<<BB, 1024, 0, stream>>>(expb, expTmax, aff, nreg, mlist, kcnt, Em,
                              bilinP, result);
  kE<<<1, 64, 0, stream>>>(result, nmen, out);
}

// Round 10
// 195.121 us; speedup vs baseline: 1.7810x; 1.7792x over previous
//
#include <hip/hip_runtime.h>

#define NEGV (-100000000.0f)
typedef __attribute__((ext_vector_type(2))) float f32x2;

constexpr int BB = 32, MM = 24, RR = 384, DD = 2048;

// DPP helpers: row-scan add / max (VALU pipe). ctrl must be immediate.
template <int CTRL>
static __device__ __forceinline__ float dpp_add(float x) {
  int y = __builtin_amdgcn_update_dpp(0, __float_as_int(x), CTRL, 0xf, 0xf, true);
  return x + __int_as_float(y);
}
template <int CTRL>
static __device__ __forceinline__ float dpp_max(float x) {
  int y = __builtin_amdgcn_update_dpp(0, __float_as_int(x), CTRL, 0xf, 0xf, true);
  return fmaxf(x, __int_as_float(y));
}

// ---------------- Kernel A ----------------
__global__ __launch_bounds__(256) void kA(const float* __restrict__ region,
    const float* __restrict__ t0w, const float* __restrict__ t0b,
    const float* __restrict__ t1w, const float* __restrict__ t1b,
    float* __restrict__ h0h1) {
  __shared__ float rlds[32][260];
  __shared__ float wlds[256][36];
  const int t = threadIdx.x;
  const int r = t & 31;
  const int q = t >> 5;
  const int row0 = blockIdx.x * 32;
  float acc[32];
#pragma unroll
  for (int h = 0; h < 32; ++h) acc[h] = 0.f;

  for (int tile = 0; tile < 8; ++tile) {
    const int d0 = tile * 256;
    __syncthreads();
#pragma unroll
    for (int i = 0; i < 8; ++i) {
      int flat = i * 256 + t;
      int rr2 = flat >> 6;
      int cc = (flat & 63) << 2;
      *(float4*)&rlds[rr2][cc] =
          *(const float4*)(region + (size_t)(row0 + rr2) * DD + d0 + cc);
    }
#pragma unroll
    for (int h = 0; h < 32; ++h) {
      const float* wsrc = (h < 16) ? (t0w + (size_t)h * DD)
                                   : (t1w + (size_t)(h - 16) * DD);
      wlds[t][h] = wsrc[d0 + t];
    }
    __syncthreads();
    const int djb = q * 32;
#pragma unroll 4
    for (int dj = djb; dj < djb + 32; ++dj) {
      float rv = rlds[r][dj];
      const float4* wp = (const float4*)&wlds[dj][0];
#pragma unroll
      for (int h4 = 0; h4 < 8; ++h4) {
        float4 wv = wp[h4];
        acc[h4 * 4 + 0] = fmaf(rv, wv.x, acc[h4 * 4 + 0]);
        acc[h4 * 4 + 1] = fmaf(rv, wv.y, acc[h4 * 4 + 1]);
        acc[h4 * 4 + 2] = fmaf(rv, wv.z, acc[h4 * 4 + 2]);
        acc[h4 * 4 + 3] = fmaf(rv, wv.w, acc[h4 * 4 + 3]);
      }
    }
  }
  __syncthreads();
  float* red = &wlds[0][0];
#pragma unroll
  for (int h4 = 0; h4 < 8; ++h4) {
    *(float4*)&red[(q * 32 + r) * 36 + h4 * 4] =
        make_float4(acc[h4 * 4 + 0], acc[h4 * 4 + 1], acc[h4 * 4 + 2], acc[h4 * 4 + 3]);
  }
  __syncthreads();
  {
    const int r2 = t & 31;
    const int hb = (t >> 5) * 4;
    float s0 = 0, s1 = 0, s2 = 0, s3 = 0;
#pragma unroll
    for (int qq = 0; qq < 8; ++qq) {
      float4 v = *(const float4*)&red[(qq * 32 + r2) * 36 + hb];
      s0 += v.x; s1 += v.y; s2 += v.z; s3 += v.w;
    }
    float4 bias = (hb < 16) ? *(const float4*)(t0b + hb)
                            : *(const float4*)(t1b + hb - 16);
    *(float4*)(h0h1 + (size_t)(row0 + r2) * 32 + hb) =
        make_float4(s0 + bias.x, s1 + bias.y, s2 + bias.z, s3 + bias.w);
  }
}

// ---------------- Kernel CM: rsum + Em + compact active-m list --------------
__global__ __launch_bounds__(64) void kCM(const float* __restrict__ gt,
    const float* __restrict__ aff, const int* __restrict__ nmen,
    const int* __restrict__ nreg, float* __restrict__ rsum,
    float* __restrict__ Em, int* __restrict__ mlist, int* __restrict__ kcnt) {
  const int b = blockIdx.x;
  const int lane = threadIdx.x;
  const int nm = nmen[b], nr = nreg[b];
  int c = 0;
  for (int m = 0; m < MM; ++m) {
    const size_t bm = (size_t)(b * MM + m);
    float p = 0.f, t1 = 0.f, t2 = 0.f;
#pragma unroll
    for (int i = 0; i < 6; ++i) {
      int s = lane * 6 + i;
      float g = gt[bm * RR + s];
      float a = (g >= 0.5f && s < nr && m < nm) ? g : 0.f;
      float e = aff[bm * RR + s];
      p += a;
      t1 += a * e;
      t2 += (a > 0.f) ? a * __logf(a) : 0.f;
    }
#pragma unroll
    for (int off = 32; off > 0; off >>= 1) {
      p += __shfl_xor(p, off);
      t1 += __shfl_xor(t1, off);
      t2 += __shfl_xor(t2, off);
    }
    if (lane == 0) {
      rsum[bm] = p;
      Em[bm] = (p > 0.f) ? (t1 - t2) / p + __logf(p) : 0.f;
      if (p > 0.f) mlist[b * MM + (c++)] = m;
    }
  }
  if (lane == 0) {
    kcnt[b] = c;
    for (int j = c; j < MM; ++j) mlist[b * MM + j] = 0;
  }
}

// ---------------- Kernel YT: bilinP partials + fp8 expT export --------------
__global__ __launch_bounds__(192) void kYT(const float* __restrict__ h0h1,
    const float* __restrict__ trw, const float* __restrict__ trb,
    const float* __restrict__ gt, const int* __restrict__ nreg,
    const float* __restrict__ rsum, const int* __restrict__ mlist,
    const int* __restrict__ kcnt, float* __restrict__ bilinP,
    unsigned char* __restrict__ expb, float* __restrict__ expTmax) {
  __shared__ float h1T[16][388];
  __shared__ float h0L[48][16];
  __shared__ float Tl[48][388];
  __shared__ float RP[MM][392];
  __shared__ float part[48][26];
  const int b = blockIdx.x & 31;
  const int chunk = blockIdx.x >> 5;
  const int r0 = chunk * 48;
  const int tid = threadIdx.x;
  const int K = kcnt[b];
  const int nr = nreg[b];

  for (int h = 0; h < 16; ++h)
    for (int s = tid; s < RR; s += 192)
      h1T[h][s] = h0h1[((size_t)b * RR + s) * 32 + 16 + h];
  for (int i = tid; i < 768; i += 192) {
    int row = i >> 4, h = i & 15;
    h0L[row][h] = h0h1[((size_t)b * RR + r0 + row) * 32 + h];
  }
  for (int j = 0; j < MM; ++j) {
    if (j < K) {
      int m = mlist[b * MM + j];
      float inv = 1.f / rsum[b * MM + m];
      for (int s = tid; s < RR; s += 192) {
        float g = gt[((size_t)(b * MM + m)) * RR + s];
        RP[j][s] = (g >= 0.5f && s < nr) ? g * inv : 0.f;
      }
    } else {
      for (int s = tid; s < RR; s += 192) RP[j][s] = 0.f;
    }
  }
  float w0[16];
#pragma unroll
  for (int h = 0; h < 16; ++h) w0[h] = trw[h];
  const float tb = trb[0];
  __syncthreads();

  const int r = tid >> 2;
  const int jq = tid & 3;
  const int gr = r0 + r;

  for (int s = jq * 96; s < jq * 96 + 96; ++s) {
    float a = tb;
#pragma unroll
    for (int h = 0; h < 16; ++h)
      a += fmaxf(h0L[r][h] + h1T[h][s], 0.f) * w0[h];
    Tl[r][s] = a;
  }
  __syncthreads();

  // ---- fp8 export: row max over 4 jq lanes, exp(t - rmax) packed e4m3 ----
  {
    float rmax = -3.0e38f;
    for (int c = 0; c < 96; c += 4) {
      float4 v = *(const float4*)&Tl[r][jq * 96 + c];
      rmax = fmaxf(rmax, fmaxf(fmaxf(v.x, v.y), fmaxf(v.z, v.w)));
    }
    rmax = fmaxf(rmax, __shfl_xor(rmax, 1));
    rmax = fmaxf(rmax, __shfl_xor(rmax, 2));
    if (jq == 0) expTmax[b * RR + gr] = __expf(rmax);
    unsigned char* obase = expb + ((size_t)b * RR + gr) * RR + jq * 96;
#pragma unroll
    for (int c16 = 0; c16 < 6; ++c16) {
      int w4[4];
#pragma unroll
      for (int ii = 0; ii < 4; ++ii) {
        float4 v = *(const float4*)&Tl[r][jq * 96 + c16 * 16 + ii * 4];
        int pk = __builtin_amdgcn_cvt_pk_fp8_f32(__expf(v.x - rmax),
                                                 __expf(v.y - rmax), 0, false);
        pk = __builtin_amdgcn_cvt_pk_fp8_f32(__expf(v.z - rmax),
                                             __expf(v.w - rmax), pk, true);
        w4[ii] = pk;
      }
      *(int4*)(obase + c16 * 16) = make_int4(w4[0], w4[1], w4[2], w4[3]);
    }
  }

  // ---- bilinear partials ----
  float acc[6] = {0, 0, 0, 0, 0, 0};
  for (int s0 = 0; s0 < RR; s0 += 4) {
    float4 tv = *(const float4*)&Tl[r][s0];
#pragma unroll
    for (int jj = 0; jj < 6; ++jj) {
      const float4 p0 = *(const float4*)&RP[jq * 6 + jj][s0];
      acc[jj] = fmaf(tv.x, p0.x, acc[jj]);
      acc[jj] = fmaf(tv.y, p0.y, acc[jj]);
      acc[jj] = fmaf(tv.z, p0.z, acc[jj]);
      acc[jj] = fmaf(tv.w, p0.w, acc[jj]);
    }
  }
#pragma unroll
  for (int jj = 0; jj < 6; ++jj) {
    const int jp = jq * 6 + jj;
    const int j = jp + 1;
    part[r][j] = (j < K) ? RP[j][gr] * acc[jj] : 0.f;
  }
  __syncthreads();
  if (tid < MM) {
    const int j = tid;
    float s = 0.f;
    if (j >= 1) {
#pragma unroll 4
      for (int rr2 = 0; rr2 < 48; ++rr2) s += part[rr2][j];
    }
    bilinP[(size_t)(b * 8 + chunk) * MM + j] = s;
  }
}

// ---------------- Kernel D: linear-space scan, full fp8 expT tile in LDS ----
__global__ __launch_bounds__(1024) void kD(
    const unsigned char* __restrict__ expb, const float* __restrict__ expTmax,
    const float* __restrict__ aff, const int* __restrict__ nreg,
    const int* __restrict__ mlist, const int* __restrict__ kcnt,
    const float* __restrict__ Em, const float* __restrict__ bilinP,
    float* __restrict__ result) {
  __shared__ unsigned int eT[RR * RR / 4];     // fp8 tile, 147456 B — fits LDS
  __shared__ float tL[2][16][28];
  __shared__ float wmax[2][16];
  __shared__ float fred[16];

  const int b = blockIdx.x;
  const int tid = threadIdx.x;
  const int w = tid >> 6;
  const int lane = tid & 63;
  const int lam = lane & 15;
  const int g = lane >> 4;
  const int nr = nreg[b];

  const int K = kcnt[b];
  if (K == 0) {
    if (tid == 0) result[b] = 0.f;
    return;
  }

  {  // stage the whole fp8 tile global -> LDS (coalesced uint4)
    const uint4* src = (const uint4*)(expb + (size_t)b * RR * RR);
    uint4* dst = (uint4*)eT;
    for (int i = tid; i < RR * RR / 16; i += 1024) dst[i] = src[i];
  }
  // first read of eT is at k=1, after the k=0 end-of-step __syncthreads

  const int myrow0 = w * 24;
  float sF[6];
#pragma unroll
  for (int p = 0; p < 6; ++p) sF[p] = expTmax[b * RR + myrow0 + p * 4 + g];

  // prefetch step-0 emissions
  float eraw[6];
  {
    const int m0 = mlist[b * MM];
    const float* arow = aff + ((size_t)(b * MM + m0)) * RR;
#pragma unroll
    for (int p = 0; p < 6; ++p) eraw[p] = arow[myrow0 + p * 4 + g];
  }

  float L = 0.f;

  for (int k = 0; k < K; ++k) {
    const int q = k & 1;

    float nraw[6] = {0, 0, 0, 0, 0, 0};
    if (k + 1 < K) {
      const int mn = mlist[b * MM + k + 1];
      const float* arow = aff + ((size_t)(b * MM + mn)) * RR;
#pragma unroll
      for (int p = 0; p < 6; ++p) nraw[p] = arow[myrow0 + p * 4 + g];
    }

    float lmaxv = 0.f;                       // t >= 0 always
    if (k == 0) {
#pragma unroll
      for (int p = 0; p < 6; ++p) {
        const int row = myrow0 + p * 4 + g;
        const float t = (row < nr) ? __expf(eraw[p]) : 0.f;
        if (lam == 15) {
          tL[q][w][p * 4 + g] = t;
          lmaxv = fmaxf(lmaxv, t);
        }
      }
    } else {
      // Z = max over previous block maxima; fold 1/Z + row scale into factor
      const float4* wm4 = (const float4*)&wmax[q ^ 1][0];
      float4 m0 = wm4[0], m1 = wm4[1], m2 = wm4[2], m3 = wm4[3];
      float4 mm01 = make_float4(fmaxf(m0.x, m1.x), fmaxf(m0.y, m1.y),
                                fmaxf(m0.z, m1.z), fmaxf(m0.w, m1.w));
      float4 mm23 = make_float4(fmaxf(m2.x, m3.x), fmaxf(m2.y, m3.y),
                                fmaxf(m2.z, m3.z), fmaxf(m2.w, m3.w));
      const float Z = fmaxf(fmaxf(fmaxf(mm01.x, mm01.y), fmaxf(mm01.z, mm01.w)),
                            fmaxf(fmaxf(mm23.x, mm23.y), fmaxf(mm23.z, mm23.w)));
      const float invZ = 1.f / Z;
      L += __logf(Z);
      float cf[6];
#pragma unroll
      for (int p = 0; p < 6; ++p) cf[p] = __expf(eraw[p]) * invZ * sF[p];

      // xr: previous t values for my 24-column chunk
      f32x2 xr2[12];
#pragma unroll
      for (int j4 = 0; j4 < 6; ++j4) {
        float4 v = *(const float4*)&tL[q ^ 1][lam][j4 * 4];
        f32x2 lo, hiw;
        lo.x = v.x; lo.y = v.y; hiw.x = v.z; hiw.y = v.w;
        xr2[j4 * 2] = lo;
        xr2[j4 * 2 + 1] = hiw;
      }

#pragma unroll
      for (int p = 0; p < 6; ++p) {
        const int row = myrow0 + p * 4 + g;
        const uint2* ep =
            (const uint2*)((const unsigned char*)eT + row * RR + lam * 24);
        uint2 ua = ep[0], ub = ep[1], uc = ep[2];
        const unsigned uu[6] = {ua.x, ua.y, ub.x, ub.y, uc.x, uc.y};
        f32x2 acc;
        acc.x = 0.f; acc.y = 0.f;
#pragma unroll
        for (int j = 0; j < 6; ++j) {
          f32x2 lo = __builtin_amdgcn_cvt_pk_f32_fp8(uu[j], false);
          f32x2 hi = __builtin_amdgcn_cvt_pk_f32_fp8(uu[j], true);
          acc += lo * xr2[2 * j];              // v_pk_fma_f32
          acc += hi * xr2[2 * j + 1];
        }
        float asum = acc.x + acc.y;
        // 16-lane inclusive scan (VALU DPP): total lands at lam==15
        asum = dpp_add<0x111>(asum);
        asum = dpp_add<0x112>(asum);
        asum = dpp_add<0x114>(asum);
        asum = dpp_add<0x118>(asum);
        const float t = asum * cf[p];
        if (lam == 15) {
          tL[q][w][p * 4 + g] = t;
          lmaxv = fmaxf(lmaxv, t);
        }
      }
    }
    // wave max (valid at lam==15 lanes; 0 elsewhere) via DPP
    lmaxv = dpp_max<0x111>(lmaxv);
    lmaxv = dpp_max<0x112>(lmaxv);
    lmaxv = dpp_max<0x114>(lmaxv);
    lmaxv = dpp_max<0x118>(lmaxv);
    lmaxv = dpp_max<0x142>(lmaxv);             // bcast15
    lmaxv = dpp_max<0x143>(lmaxv);             // bcast31
    if (lane == 63) wmax[q][w] = lmaxv;
#pragma unroll
    for (int p = 0; p < 6; ++p) eraw[p] = nraw[p];
    __syncthreads();
  }

  // epilogue: fwd = L + log(sum_r t_r); gold from precomputed bilin/Em
  const int qf = (K - 1) & 1;
  float fp = (tid < RR) ? tL[qf][tid / 24][tid % 24] : 0.f;
#pragma unroll
  for (int off = 32; off > 0; off >>= 1) fp += __shfl_xor(fp, off);
  if (lane == 0) fred[w] = fp;
  __syncthreads();
  if (tid == 0) {
    float fs = 0.f;
#pragma unroll
    for (int i = 0; i < 16; ++i) fs += fred[i];
    const float fwd = L + __logf(fmaxf(fs, 1e-37f));
    float gold = Em[b * MM + mlist[b * MM + 0]];
    for (int j = 1; j < K; ++j) {
      float bil = 0.f;
#pragma unroll
      for (int c = 0; c < 8; ++c) bil += bilinP[(size_t)(b * 8 + c) * MM + j];
      gold += bil + Em[b * MM + mlist[b * MM + j]];
    }
    result[b] = fwd - gold;
  }
}

// ---------------- Kernel E: final deterministic reduction ----------
__global__ void kE(const float* __restrict__ result, const int* __restrict__ nmen,
                   float* __restrict__ out) {
  if (threadIdx.x == 0 && blockIdx.x == 0) {
    float s = 0.f;
    int d = 0;
    for (int b = 0; b < 32; ++b) { s += result[b]; d += nmen[b]; }
    if (d < 1) d = 1;
    out[0] = s / (float)d;
  }
}

extern "C" void kernel_launch(void* const* d_in, const int* in_sizes, int n_in,
                              void* d_out, int out_size, void* d_ws, size_t ws_size,
                              hipStream_t stream) {
  const float* region = (const float*)d_in[0];
  const float* aff    = (const float*)d_in[1];
  const float* gt     = (const float*)d_in[2];
  const int*   nmen   = (const int*)d_in[3];
  const int*   nreg   = (const int*)d_in[4];
  const float* t0w    = (const float*)d_in[5];
  const float* t0b    = (const float*)d_in[6];
  const float* t1w    = (const float*)d_in[7];
  const float* t1b    = (const float*)d_in[8];
  const float* trw    = (const float*)d_in[9];
  const float* trb    = (const float*)d_in[10];
  float* out = (float*)d_out;
  char* ws = (char*)d_ws;

  size_t off = 0;
  auto alloc = [&](size_t bytes) {
    void* p = ws + off;
    off += (bytes + 255) & ~(size_t)255;
    return p;
  };
  float*         h0h1    = (float*)alloc((size_t)BB * RR * 32 * 4);       // 1.57 MB
  unsigned char* expb    = (unsigned char*)alloc((size_t)BB * RR * RR);   // 4.72 MB
  float*         expTmax = (float*)alloc((size_t)BB * RR * 4);            // 49 KB
  float*         rsum    = (float*)alloc((size_t)BB * MM * 4);
  int*           mlist   = (int*)alloc((size_t)BB * MM * 4);
  int*           kcnt    = (int*)alloc((size_t)BB * 4);
  float*         Em      = (float*)alloc((size_t)BB * MM * 4);
  float*         bilinP  = (float*)alloc((size_t)BB * 8 * MM * 4);
  float*         result  = (float*)alloc((size_t)BB * 4);

  kA<<<(BB * RR) / 32, 256, 0, stream>>>(region, t0w, t0b, t1w, t1b, h0h1);
  kCM<<<BB, 64, 0, stream>>>(gt, aff, nmen, nreg, rsum, Em, mlist, kcnt);
  kYT<<<256, 192, 0, stream>>>(h0h1, trw, trb, gt, nreg, rsum, mlist, kcnt,
                               bilinP, expb, expTmax);
  kD<<<BB, 1024, 0, stream>>>(expb, expTmax, aff, nreg, mlist, kcnt, Em,
                              bilinP, result);
  kE<<<1, 64, 0, stream>>>(result, nmen, out);
}

// Round 11
// 173.371 us; speedup vs baseline: 2.0045x; 1.1255x over previous
//
#include <hip/hip_runtime.h>

#define NEGV (-100000000.0f)
typedef __attribute__((ext_vector_type(2))) float f32x2;
typedef __attribute__((ext_vector_type(8))) short bf16x8;
typedef __attribute__((ext_vector_type(4))) float f32x4v;

constexpr int BB = 32, MM = 24, RR = 384, DD = 2048;

// DPP helpers: row-scan add / max (VALU pipe). ctrl must be immediate.
template <int CTRL>
static __device__ __forceinline__ float dpp_add(float x) {
  int y = __builtin_amdgcn_update_dpp(0, __float_as_int(x), CTRL, 0xf, 0xf, true);
  return x + __int_as_float(y);
}
template <int CTRL>
static __device__ __forceinline__ float dpp_max(float x) {
  int y = __builtin_amdgcn_update_dpp(0, __float_as_int(x), CTRL, 0xf, 0xf, true);
  return fmaxf(x, __int_as_float(y));
}

// pack two f32 -> two bf16 (round half-up; unbiased enough, 2.5 ops/elem)
static __device__ __forceinline__ unsigned pk2bf(float a, float b) {
  unsigned au = __float_as_uint(a) + 0x8000u;
  unsigned bu = __float_as_uint(b) + 0x8000u;
  return (au >> 16) | (bu & 0xffff0000u);
}

// ---------------- Kernel A: fused fp32->bf16 cast + MFMA GEMM ----------------
// h0h1[row][0:16] = region@t0_w^T + t0_b ; [16:32] = t1. 384 blocks x 128 thr.
// Block: 32 rows x 32 h, K-tiles of 128, double-buffered swizzled LDS.
__global__ __launch_bounds__(128) void kA(const float* __restrict__ region,
    const float* __restrict__ t0w, const float* __restrict__ t0b,
    const float* __restrict__ t1w, const float* __restrict__ t1b,
    float* __restrict__ h0h1) {
  __shared__ unsigned short Abuf[2][32 * 128];   // [row][k] bf16, XOR-swizzled
  __shared__ unsigned short Bbuf[2][32 * 128];   // [h][k]  bf16, XOR-swizzled
  const int tid = threadIdx.x;
  const int row0 = blockIdx.x * 32;

  const int srow = tid >> 2;       // 0..31: A row / B h
  const int sq = tid & 3;          // quarter of the 128-k tile
  const float* aSrc = region + (size_t)(row0 + srow) * DD + sq * 32;
  const float* bSrc = ((srow < 16) ? (t0w + (size_t)srow * DD)
                                   : (t1w + (size_t)(srow - 16) * DD)) + sq * 32;

  float4 ra[8], rb[8];
  auto LOAD = [&](int t) {
    const int d0 = t * 128;
#pragma unroll
    for (int i = 0; i < 8; ++i) ra[i] = *(const float4*)(aSrc + d0 + i * 4);
#pragma unroll
    for (int i = 0; i < 8; ++i) rb[i] = *(const float4*)(bSrc + d0 + i * 4);
  };
  const int wbase = srow * 256 + sq * 64;
  const int wxor = (srow & 7) << 4;
  auto WRITE = [&](int buf) {
    unsigned char* Ab = (unsigned char*)&Abuf[buf][0];
    unsigned char* Bb = (unsigned char*)&Bbuf[buf][0];
#pragma unroll
    for (int i = 0; i < 4; ++i) {
      float4 x = ra[i * 2], y = ra[i * 2 + 1];
      uint4 pk;
      pk.x = pk2bf(x.x, x.y); pk.y = pk2bf(x.z, x.w);
      pk.z = pk2bf(y.x, y.y); pk.w = pk2bf(y.z, y.w);
      *(uint4*)(Ab + ((wbase + i * 16) ^ wxor)) = pk;
      float4 u = rb[i * 2], v = rb[i * 2 + 1];
      uint4 qk;
      qk.x = pk2bf(u.x, u.y); qk.y = pk2bf(u.z, u.w);
      qk.z = pk2bf(v.x, v.y); qk.w = pk2bf(v.z, v.w);
      *(uint4*)(Bb + ((wbase + i * 16) ^ wxor)) = qk;
    }
  };

  const int w = tid >> 6;                 // wave 0..1 -> rows w*16..w*16+15
  const int lane = tid & 63;
  const int arow = w * 16 + (lane & 15);  // A-frag row
  const int bh = lane & 15;               // B-frag col (h within 16-tile)
  const int koff = (lane >> 4) * 8;       // contiguous-K fragment offset

  f32x4v acc0 = {0.f, 0.f, 0.f, 0.f}, acc1 = {0.f, 0.f, 0.f, 0.f};

  LOAD(0);
  WRITE(0);
  const int axor = (arow & 7) << 4;
  const int bxor = (bh & 7) << 4;         // (bh+16)&7 == bh&7
  for (int t = 0; t < 16; ++t) {
    __syncthreads();
    if (t < 15) LOAD(t + 1);
    const unsigned char* Ab = (const unsigned char*)&Abuf[t & 1][0];
    const unsigned char* Bb = (const unsigned char*)&Bbuf[t & 1][0];
#pragma unroll
    for (int kk = 0; kk < 4; ++kk) {
      const int kb = (kk * 32 + koff) * 2;
      bf16x8 av = *(const bf16x8*)(Ab + ((arow * 256 + kb) ^ axor));
      bf16x8 b0 = *(const bf16x8*)(Bb + ((bh * 256 + kb) ^ bxor));
      bf16x8 b1 = *(const bf16x8*)(Bb + (((bh + 16) * 256 + kb) ^ bxor));
      acc0 = __builtin_amdgcn_mfma_f32_16x16x32_bf16(av, b0, acc0, 0, 0, 0);
      acc1 = __builtin_amdgcn_mfma_f32_16x16x32_bf16(av, b1, acc1, 0, 0, 0);
    }
    if (t < 15) WRITE((t + 1) & 1);
  }

  // epilogue: C/D layout col=lane&15, row=(lane>>4)*4+reg  [m89-verified]
  const float bias0 = t0b[bh];
  const float bias1 = t1b[bh];
#pragma unroll
  for (int i = 0; i < 4; ++i) {
    const int rg = row0 + w * 16 + (lane >> 4) * 4 + i;
    h0h1[(size_t)rg * 32 + bh] = acc0[i] + bias0;
    h0h1[(size_t)rg * 32 + 16 + bh] = acc1[i] + bias1;
  }
}

// ---------------- Kernel CM: rsum + Em + compact active-m list --------------
__global__ __launch_bounds__(64) void kCM(const float* __restrict__ gt,
    const float* __restrict__ aff, const int* __restrict__ nmen,
    const int* __restrict__ nreg, float* __restrict__ rsum,
    float* __restrict__ Em, int* __restrict__ mlist, int* __restrict__ kcnt) {
  const int b = blockIdx.x;
  const int lane = threadIdx.x;
  const int nm = nmen[b], nr = nreg[b];
  int c = 0;
  for (int m = 0; m < MM; ++m) {
    const size_t bm = (size_t)(b * MM + m);
    float p = 0.f, t1 = 0.f, t2 = 0.f;
#pragma unroll
    for (int i = 0; i < 6; ++i) {
      int s = lane * 6 + i;
      float g = gt[bm * RR + s];
      float a = (g >= 0.5f && s < nr && m < nm) ? g : 0.f;
      float e = aff[bm * RR + s];
      p += a;
      t1 += a * e;
      t2 += (a > 0.f) ? a * __logf(a) : 0.f;
    }
#pragma unroll
    for (int off = 32; off > 0; off >>= 1) {
      p += __shfl_xor(p, off);
      t1 += __shfl_xor(t1, off);
      t2 += __shfl_xor(t2, off);
    }
    if (lane == 0) {
      rsum[bm] = p;
      Em[bm] = (p > 0.f) ? (t1 - t2) / p + __logf(p) : 0.f;
      if (p > 0.f) mlist[b * MM + (c++)] = m;
    }
  }
  if (lane == 0) {
    kcnt[b] = c;
    for (int j = c; j < MM; ++j) mlist[b * MM + j] = 0;
  }
}

// ---------------- Kernel YT: bilinP partials + fp8 expT export --------------
__global__ __launch_bounds__(192) void kYT(const float* __restrict__ h0h1,
    const float* __restrict__ trw, const float* __restrict__ trb,
    const float* __restrict__ gt, const int* __restrict__ nreg,
    const float* __restrict__ rsum, const int* __restrict__ mlist,
    const int* __restrict__ kcnt, float* __restrict__ bilinP,
    unsigned char* __restrict__ expb, float* __restrict__ expTmax) {
  __shared__ float h1T[16][388];
  __shared__ float h0L[48][16];
  __shared__ float Tl[48][388];
  __shared__ float RP[MM][392];
  __shared__ float part[48][26];
  const int b = blockIdx.x & 31;
  const int chunk = blockIdx.x >> 5;
  const int r0 = chunk * 48;
  const int tid = threadIdx.x;
  const int K = kcnt[b];
  const int nr = nreg[b];

  for (int h = 0; h < 16; ++h)
    for (int s = tid; s < RR; s += 192)
      h1T[h][s] = h0h1[((size_t)b * RR + s) * 32 + 16 + h];
  for (int i = tid; i < 768; i += 192) {
    int row = i >> 4, h = i & 15;
    h0L[row][h] = h0h1[((size_t)b * RR + r0 + row) * 32 + h];
  }
  for (int j = 0; j < MM; ++j) {
    if (j < K) {
      int m = mlist[b * MM + j];
      float inv = 1.f / rsum[b * MM + m];
      for (int s = tid; s < RR; s += 192) {
        float g = gt[((size_t)(b * MM + m)) * RR + s];
        RP[j][s] = (g >= 0.5f && s < nr) ? g * inv : 0.f;
      }
    } else {
      for (int s = tid; s < RR; s += 192) RP[j][s] = 0.f;
    }
  }
  float w0[16];
#pragma unroll
  for (int h = 0; h < 16; ++h) w0[h] = trw[h];
  const float tb = trb[0];
  __syncthreads();

  const int r = tid >> 2;
  const int jq = tid & 3;
  const int gr = r0 + r;

  for (int s = jq * 96; s < jq * 96 + 96; ++s) {
    float a = tb;
#pragma unroll
    for (int h = 0; h < 16; ++h)
      a += fmaxf(h0L[r][h] + h1T[h][s], 0.f) * w0[h];
    Tl[r][s] = a;
  }
  __syncthreads();

  // ---- fp8 export: row max over 4 jq lanes, exp(t - rmax) packed e4m3 ----
  {
    float rmax = -3.0e38f;
    for (int c = 0; c < 96; c += 4) {
      float4 v = *(const float4*)&Tl[r][jq * 96 + c];
      rmax = fmaxf(rmax, fmaxf(fmaxf(v.x, v.y), fmaxf(v.z, v.w)));
    }
    rmax = fmaxf(rmax, __shfl_xor(rmax, 1));
    rmax = fmaxf(rmax, __shfl_xor(rmax, 2));
    if (jq == 0) expTmax[b * RR + gr] = __expf(rmax);
    unsigned char* obase = expb + ((size_t)b * RR + gr) * RR + jq * 96;
#pragma unroll
    for (int c16 = 0; c16 < 6; ++c16) {
      int w4[4];
#pragma unroll
      for (int ii = 0; ii < 4; ++ii) {
        float4 v = *(const float4*)&Tl[r][jq * 96 + c16 * 16 + ii * 4];
        int pk = __builtin_amdgcn_cvt_pk_fp8_f32(__expf(v.x - rmax),
                                                 __expf(v.y - rmax), 0, false);
        pk = __builtin_amdgcn_cvt_pk_fp8_f32(__expf(v.z - rmax),
                                             __expf(v.w - rmax), pk, true);
        w4[ii] = pk;
      }
      *(int4*)(obase + c16 * 16) = make_int4(w4[0], w4[1], w4[2], w4[3]);
    }
  }

  // ---- bilinear partials ----
  float acc[6] = {0, 0, 0, 0, 0, 0};
  for (int s0 = 0; s0 < RR; s0 += 4) {
    float4 tv = *(const float4*)&Tl[r][s0];
#pragma unroll
    for (int jj = 0; jj < 6; ++jj) {
      const float4 p0 = *(const float4*)&RP[jq * 6 + jj][s0];
      acc[jj] = fmaf(tv.x, p0.x, acc[jj]);
      acc[jj] = fmaf(tv.y, p0.y, acc[jj]);
      acc[jj] = fmaf(tv.z, p0.z, acc[jj]);
      acc[jj] = fmaf(tv.w, p0.w, acc[jj]);
    }
  }
#pragma unroll
  for (int jj = 0; jj < 6; ++jj) {
    const int jp = jq * 6 + jj;
    const int j = jp + 1;
    part[r][j] = (j < K) ? RP[j][gr] * acc[jj] : 0.f;
  }
  __syncthreads();
  if (tid < MM) {
    const int j = tid;
    float s = 0.f;
    if (j >= 1) {
#pragma unroll 4
      for (int rr2 = 0; rr2 < 48; ++rr2) s += part[rr2][j];
    }
    bilinP[(size_t)(b * 8 + chunk) * MM + j] = s;
  }
}

// ---------------- Kernel D: linear-space scan, full fp8 expT tile in LDS ----
__global__ __launch_bounds__(1024) void kD(
    const unsigned char* __restrict__ expb, const float* __restrict__ expTmax,
    const float* __restrict__ aff, const int* __restrict__ nreg,
    const int* __restrict__ mlist, const int* __restrict__ kcnt,
    const float* __restrict__ Em, const float* __restrict__ bilinP,
    float* __restrict__ result) {
  __shared__ unsigned int eT[RR * RR / 4];     // fp8 tile, 147456 B — fits LDS
  __shared__ float tL[2][16][28];
  __shared__ float wmax[2][16];
  __shared__ float fred[16];

  const int b = blockIdx.x;
  const int tid = threadIdx.x;
  const int w = tid >> 6;
  const int lane = tid & 63;
  const int lam = lane & 15;
  const int g = lane >> 4;
  const int nr = nreg[b];

  const int K = kcnt[b];
  if (K == 0) {
    if (tid == 0) result[b] = 0.f;
    return;
  }

  {  // stage the whole fp8 tile global -> LDS (coalesced uint4)
    const uint4* src = (const uint4*)(expb + (size_t)b * RR * RR);
    uint4* dst = (uint4*)eT;
    for (int i = tid; i < RR * RR / 16; i += 1024) dst[i] = src[i];
  }
  // first read of eT is at k=1, after the k=0 end-of-step __syncthreads

  const int myrow0 = w * 24;
  float sF[6];
#pragma unroll
  for (int p = 0; p < 6; ++p) sF[p] = expTmax[b * RR + myrow0 + p * 4 + g];

  // prefetch step-0 emissions
  float eraw[6];
  {
    const int m0 = mlist[b * MM];
    const float* arow = aff + ((size_t)(b * MM + m0)) * RR;
#pragma unroll
    for (int p = 0; p < 6; ++p) eraw[p] = arow[myrow0 + p * 4 + g];
  }

  float L = 0.f;

  for (int k = 0; k < K; ++k) {
    const int q = k & 1;

    float nraw[6] = {0, 0, 0, 0, 0, 0};
    if (k + 1 < K) {
      const int mn = mlist[b * MM + k + 1];
      const float* arow = aff + ((size_t)(b * MM + mn)) * RR;
#pragma unroll
      for (int p = 0; p < 6; ++p) nraw[p] = arow[myrow0 + p * 4 + g];
    }

    float lmaxv = 0.f;                       // t >= 0 always
    if (k == 0) {
#pragma unroll
      for (int p = 0; p < 6; ++p) {
        const int row = myrow0 + p * 4 + g;
        const float t = (row < nr) ? __expf(eraw[p]) : 0.f;
        if (lam == 15) {
          tL[q][w][p * 4 + g] = t;
          lmaxv = fmaxf(lmaxv, t);
        }
      }
    } else {
      // Z = max over previous block maxima; fold 1/Z + row scale into factor
      const float4* wm4 = (const float4*)&wmax[q ^ 1][0];
      float4 m0 = wm4[0], m1 = wm4[1], m2 = wm4[2], m3 = wm4[3];
      float4 mm01 = make_float4(fmaxf(m0.x, m1.x), fmaxf(m0.y, m1.y),
                                fmaxf(m0.z, m1.z), fmaxf(m0.w, m1.w));
      float4 mm23 = make_float4(fmaxf(m2.x, m3.x), fmaxf(m2.y, m3.y),
                                fmaxf(m2.z, m3.z), fmaxf(m2.w, m3.w));
      const float Z = fmaxf(fmaxf(fmaxf(mm01.x, mm01.y), fmaxf(mm01.z, mm01.w)),
                            fmaxf(fmaxf(mm23.x, mm23.y), fmaxf(mm23.z, mm23.w)));
      const float invZ = 1.f / Z;
      L += __logf(Z);
      float cf[6];
#pragma unroll
      for (int p = 0; p < 6; ++p) cf[p] = __expf(eraw[p]) * invZ * sF[p];

      // xr: previous t values for my 24-column chunk
      f32x2 xr2[12];
#pragma unroll
      for (int j4 = 0; j4 < 6; ++j4) {
        float4 v = *(const float4*)&tL[q ^ 1][lam][j4 * 4];
        f32x2 lo, hiw;
        lo.x = v.x; lo.y = v.y; hiw.x = v.z; hiw.y = v.w;
        xr2[j4 * 2] = lo;
        xr2[j4 * 2 + 1] = hiw;
      }

#pragma unroll
      for (int p = 0; p < 6; ++p) {
        const int row = myrow0 + p * 4 + g;
        const uint2* ep =
            (const uint2*)((const unsigned char*)eT + row * RR + lam * 24);
        uint2 ua = ep[0], ub = ep[1], uc = ep[2];
        const unsigned uu[6] = {ua.x, ua.y, ub.x, ub.y, uc.x, uc.y};
        f32x2 acc;
        acc.x = 0.f; acc.y = 0.f;
#pragma unroll
        for (int j = 0; j < 6; ++j) {
          f32x2 lo = __builtin_amdgcn_cvt_pk_f32_fp8(uu[j], false);
          f32x2 hi = __builtin_amdgcn_cvt_pk_f32_fp8(uu[j], true);
          acc += lo * xr2[2 * j];              // v_pk_fma_f32
          acc += hi * xr2[2 * j + 1];
        }
        float asum = acc.x + acc.y;
        // 16-lane inclusive scan (VALU DPP): total lands at lam==15
        asum = dpp_add<0x111>(asum);
        asum = dpp_add<0x112>(asum);
        asum = dpp_add<0x114>(asum);
        asum = dpp_add<0x118>(asum);
        const float t = asum * cf[p];
        if (lam == 15) {
          tL[q][w][p * 4 + g] = t;
          lmaxv = fmaxf(lmaxv, t);
        }
      }
    }
    // wave max (valid at lam==15 lanes; 0 elsewhere) via DPP
    lmaxv = dpp_max<0x111>(lmaxv);
    lmaxv = dpp_max<0x112>(lmaxv);
    lmaxv = dpp_max<0x114>(lmaxv);
    lmaxv = dpp_max<0x118>(lmaxv);
    lmaxv = dpp_max<0x142>(lmaxv);             // bcast15
    lmaxv = dpp_max<0x143>(lmaxv);             // bcast31
    if (lane == 63) wmax[q][w] = lmaxv;
#pragma unroll
    for (int p = 0; p < 6; ++p) eraw[p] = nraw[p];
    __syncthreads();
  }

  // epilogue: fwd = L + log(sum_r t_r); gold from precomputed bilin/Em
  const int qf = (K - 1) & 1;
  float fp = (tid < RR) ? tL[qf][tid / 24][tid % 24] : 0.f;
#pragma unroll
  for (int off = 32; off > 0; off >>= 1) fp += __shfl_xor(fp, off);
  if (lane == 0) fred[w] = fp;
  __syncthreads();
  if (tid == 0) {
    float fs = 0.f;
#pragma unroll
    for (int i = 0; i < 16; ++i) fs += fred[i];
    const float fwd = L + __logf(fmaxf(fs, 1e-37f));
    float gold = Em[b * MM + mlist[b * MM + 0]];
    for (int j = 1; j < K; ++j) {
      float bil = 0.f;
#pragma unroll
      for (int c = 0; c < 8; ++c) bil += bilinP[(size_t)(b * 8 + c) * MM + j];
      gold += bil + Em[b * MM + mlist[b * MM + j]];
    }
    result[b] = fwd - gold;
  }
}

// ---------------- Kernel E: final deterministic reduction ----------
__global__ void kE(const float* __restrict__ result, const int* __restrict__ nmen,
                   float* __restrict__ out) {
  if (threadIdx.x == 0 && blockIdx.x == 0) {
    float s = 0.f;
    int d = 0;
    for (int b = 0; b < 32; ++b) { s += result[b]; d += nmen[b]; }
    if (d < 1) d = 1;
    out[0] = s / (float)d;
  }
}

extern "C" void kernel_launch(void* const* d_in, const int* in_sizes, int n_in,
                              void* d_out, int out_size, void* d_ws, size_t ws_size,
                              hipStream_t stream) {
  const float* region = (const float*)d_in[0];
  const float* aff    = (const float*)d_in[1];
  const float* gt     = (const float*)d_in[2];
  const int*   nmen   = (const int*)d_in[3];
  const int*   nreg   = (const int*)d_in[4];
  const float* t0w    = (const float*)d_in[5];
  const float* t0b    = (const float*)d_in[6];
  const float* t1w    = (const float*)d_in[7];
  const float* t1b    = (const float*)d_in[8];
  const float* trw    = (const float*)d_in[9];
  const float* trb    = (const float*)d_in[10];
  float* out = (float*)d_out;
  char* ws = (char*)d_ws;

  size_t off = 0;
  auto alloc = [&](size_t bytes) {
    void* p = ws + off;
    off += (bytes + 255) & ~(size_t)255;
    return p;
  };
  float*         h0h1    = (float*)alloc((size_t)BB * RR * 32 * 4);       // 1.57 MB
  unsigned char* expb    = (unsigned char*)alloc((size_t)BB * RR * RR);   // 4.72 MB
  float*         expTmax = (float*)alloc((size_t)BB * RR * 4);            // 49 KB
  float*         rsum    = (float*)alloc((size_t)BB * MM * 4);
  int*           mlist   = (int*)alloc((size_t)BB * MM * 4);
  int*           kcnt    = (int*)alloc((size_t)BB * 4);
  float*         Em      = (float*)alloc((size_t)BB * MM * 4);
  float*         bilinP  = (float*)alloc((size_t)BB * 8 * MM * 4);
  float*         result  = (float*)alloc((size_t)BB * 4);

  kA<<<(BB * RR) / 32, 128, 0, stream>>>(region, t0w, t0b, t1w, t1b, h0h1);
  kCM<<<BB, 64, 0, stream>>>(gt, aff, nmen, nreg, rsum, Em, mlist, kcnt);
  kYT<<<256, 192, 0, stream>>>(h0h1, trw, trb, gt, nreg, rsum, mlist, kcnt,
                               bilinP, expb, expTmax);
  kD<<<BB, 1024, 0, stream>>>(expb, expTmax, aff, nreg, mlist, kcnt, Em,
                              bilinP, result);
  kE<<<1, 64, 0, stream>>>(result, nmen, out);
}

// Round 12
// 158.009 us; speedup vs baseline: 2.1993x; 1.0972x over previous
//
#include <hip/hip_runtime.h>

#define NEGV (-100000000.0f)
typedef __attribute__((ext_vector_type(2))) float f32x2;
typedef __attribute__((ext_vector_type(8))) short bf16x8;
typedef __attribute__((ext_vector_type(4))) float f32x4v;

constexpr int BB = 32, MM = 24, RR = 384, DD = 2048;

// pack two f32 -> two bf16 (round half-up)
static __device__ __forceinline__ unsigned pk2bf(float a, float b) {
  unsigned au = __float_as_uint(a) + 0x8000u;
  unsigned bu = __float_as_uint(b) + 0x8000u;
  return (au >> 16) | (bu & 0xffff0000u);
}

// ---------------- Kernel A: fused fp32->bf16 cast + MFMA GEMM (r11 proven) --
__global__ __launch_bounds__(128) void kA(const float* __restrict__ region,
    const float* __restrict__ t0w, const float* __restrict__ t0b,
    const float* __restrict__ t1w, const float* __restrict__ t1b,
    float* __restrict__ h0h1) {
  __shared__ unsigned short Abuf[2][32 * 128];
  __shared__ unsigned short Bbuf[2][32 * 128];
  const int tid = threadIdx.x;
  const int row0 = blockIdx.x * 32;

  const int srow = tid >> 2;
  const int sq = tid & 3;
  const float* aSrc = region + (size_t)(row0 + srow) * DD + sq * 32;
  const float* bSrc = ((srow < 16) ? (t0w + (size_t)srow * DD)
                                   : (t1w + (size_t)(srow - 16) * DD)) + sq * 32;

  float4 ra[8], rb[8];
  auto LOAD = [&](int t) {
    const int d0 = t * 128;
#pragma unroll
    for (int i = 0; i < 8; ++i) ra[i] = *(const float4*)(aSrc + d0 + i * 4);
#pragma unroll
    for (int i = 0; i < 8; ++i) rb[i] = *(const float4*)(bSrc + d0 + i * 4);
  };
  const int wbase = srow * 256 + sq * 64;
  const int wxor = (srow & 7) << 4;
  auto WRITE = [&](int buf) {
    unsigned char* Ab = (unsigned char*)&Abuf[buf][0];
    unsigned char* Bb = (unsigned char*)&Bbuf[buf][0];
#pragma unroll
    for (int i = 0; i < 4; ++i) {
      float4 x = ra[i * 2], y = ra[i * 2 + 1];
      uint4 pk;
      pk.x = pk2bf(x.x, x.y); pk.y = pk2bf(x.z, x.w);
      pk.z = pk2bf(y.x, y.y); pk.w = pk2bf(y.z, y.w);
      *(uint4*)(Ab + ((wbase + i * 16) ^ wxor)) = pk;
      float4 u = rb[i * 2], v = rb[i * 2 + 1];
      uint4 qk;
      qk.x = pk2bf(u.x, u.y); qk.y = pk2bf(u.z, u.w);
      qk.z = pk2bf(v.x, v.y); qk.w = pk2bf(v.z, v.w);
      *(uint4*)(Bb + ((wbase + i * 16) ^ wxor)) = qk;
    }
  };

  const int w = tid >> 6;
  const int lane = tid & 63;
  const int arow = w * 16 + (lane & 15);
  const int bh = lane & 15;
  const int koff = (lane >> 4) * 8;

  f32x4v acc0 = {0.f, 0.f, 0.f, 0.f}, acc1 = {0.f, 0.f, 0.f, 0.f};

  LOAD(0);
  WRITE(0);
  const int axor = (arow & 7) << 4;
  const int bxor = (bh & 7) << 4;
  for (int t = 0; t < 16; ++t) {
    __syncthreads();
    if (t < 15) LOAD(t + 1);
    const unsigned char* Ab = (const unsigned char*)&Abuf[t & 1][0];
    const unsigned char* Bb = (const unsigned char*)&Bbuf[t & 1][0];
#pragma unroll
    for (int kk = 0; kk < 4; ++kk) {
      const int kb = (kk * 32 + koff) * 2;
      bf16x8 av = *(const bf16x8*)(Ab + ((arow * 256 + kb) ^ axor));
      bf16x8 b0 = *(const bf16x8*)(Bb + ((bh * 256 + kb) ^ bxor));
      bf16x8 b1 = *(const bf16x8*)(Bb + (((bh + 16) * 256 + kb) ^ bxor));
      acc0 = __builtin_amdgcn_mfma_f32_16x16x32_bf16(av, b0, acc0, 0, 0, 0);
      acc1 = __builtin_amdgcn_mfma_f32_16x16x32_bf16(av, b1, acc1, 0, 0, 0);
    }
    if (t < 15) WRITE((t + 1) & 1);
  }

  const float bias0 = t0b[bh];
  const float bias1 = t1b[bh];
#pragma unroll
  for (int i = 0; i < 4; ++i) {
    const int rg = row0 + w * 16 + (lane >> 4) * 4 + i;
    h0h1[(size_t)rg * 32 + bh] = acc0[i] + bias0;
    h0h1[(size_t)rg * 32 + 16 + bh] = acc1[i] + bias1;
  }
}

// ---------------- Kernel YT: rsum/Em/mlist prologue + bilinP + fp8 expT -----
// grid 256 = (b x 8 chunks of 48 rows), 192 threads.
__global__ __launch_bounds__(192) void kYT(const float* __restrict__ h0h1,
    const float* __restrict__ trw, const float* __restrict__ trb,
    const float* __restrict__ gt, const float* __restrict__ aff,
    const int* __restrict__ nmen, const int* __restrict__ nreg,
    int* __restrict__ mlist, int* __restrict__ kcnt, float* __restrict__ Em,
    float* __restrict__ bilinP, unsigned char* __restrict__ expb,
    float* __restrict__ expTmax) {
  __shared__ float h1T[16][388];
  __shared__ float h0L[48][16];
  __shared__ float Tl[48][388];
  __shared__ float RP[MM][392];
  __shared__ float part[48][26];
  __shared__ float rsumL[MM], EmL[MM];
  __shared__ int mlistL[MM];
  __shared__ int kcntL;
  const int b = blockIdx.x & 31;
  const int chunk = blockIdx.x >> 5;
  const int r0 = chunk * 48;
  const int tid = threadIdx.x;
  const int lane = tid & 63;
  const int wv = tid >> 6;
  const int nm = nmen[b], nr = nreg[b];

  // ---- merged kCM prologue: per-m sums on 3 waves ----
  for (int m = wv; m < MM; m += 3) {
    const size_t bm = (size_t)(b * MM + m);
    float p = 0.f, t1 = 0.f, t2 = 0.f;
#pragma unroll
    for (int i = 0; i < 6; ++i) {
      int s = lane * 6 + i;
      float g = gt[bm * RR + s];
      float a = (g >= 0.5f && s < nr && m < nm) ? g : 0.f;
      float e = aff[bm * RR + s];
      p += a;
      t1 += a * e;
      t2 += (a > 0.f) ? a * __logf(a) : 0.f;
    }
#pragma unroll
    for (int off = 32; off > 0; off >>= 1) {
      p += __shfl_xor(p, off);
      t1 += __shfl_xor(t1, off);
      t2 += __shfl_xor(t2, off);
    }
    if (lane == 0) {
      rsumL[m] = p;
      EmL[m] = (p > 0.f) ? (t1 - t2) / p + __logf(p) : 0.f;
    }
  }
  __syncthreads();
  if (tid == 0) {
    int c = 0;
    for (int m = 0; m < MM; ++m)
      if (rsumL[m] > 0.f) mlistL[c++] = m;
    kcntL = c;
    for (int j = c; j < MM; ++j) mlistL[j] = 0;
  }
  __syncthreads();
  if (chunk == 0 && tid < MM) {
    Em[b * MM + tid] = EmL[tid];
    mlist[b * MM + tid] = mlistL[tid];
    if (tid == 0) kcnt[b] = kcntL;
  }
  const int K = kcntL;

  // ---- staging ----
  for (int h = 0; h < 16; ++h)
    for (int s = tid; s < RR; s += 192)
      h1T[h][s] = h0h1[((size_t)b * RR + s) * 32 + 16 + h];
  for (int i = tid; i < 768; i += 192) {
    int row = i >> 4, h = i & 15;
    h0L[row][h] = h0h1[((size_t)b * RR + r0 + row) * 32 + h];
  }
  for (int j = 0; j < MM; ++j) {
    if (j < K) {
      int m = mlistL[j];
      float inv = 1.f / rsumL[m];
      for (int s = tid; s < RR; s += 192) {
        float g = gt[((size_t)(b * MM + m)) * RR + s];
        RP[j][s] = (g >= 0.5f && s < nr) ? g * inv : 0.f;
      }
    } else {
      for (int s = tid; s < RR; s += 192) RP[j][s] = 0.f;
    }
  }
  float w0[16];
#pragma unroll
  for (int h = 0; h < 16; ++h) w0[h] = trw[h];
  const float tb = trb[0];
  __syncthreads();

  const int r = tid >> 2;
  const int jq = tid & 3;
  const int gr = r0 + r;

  for (int s = jq * 96; s < jq * 96 + 96; ++s) {
    float a = tb;
#pragma unroll
    for (int h = 0; h < 16; ++h)
      a += fmaxf(h0L[r][h] + h1T[h][s], 0.f) * w0[h];
    Tl[r][s] = a;
  }
  __syncthreads();

  // ---- fp8 export ----
  {
    float rmax = -3.0e38f;
    for (int c = 0; c < 96; c += 4) {
      float4 v = *(const float4*)&Tl[r][jq * 96 + c];
      rmax = fmaxf(rmax, fmaxf(fmaxf(v.x, v.y), fmaxf(v.z, v.w)));
    }
    rmax = fmaxf(rmax, __shfl_xor(rmax, 1));
    rmax = fmaxf(rmax, __shfl_xor(rmax, 2));
    if (jq == 0) expTmax[b * RR + gr] = __expf(rmax);
    unsigned char* obase = expb + ((size_t)b * RR + gr) * RR + jq * 96;
#pragma unroll
    for (int c16 = 0; c16 < 6; ++c16) {
      int w4[4];
#pragma unroll
      for (int ii = 0; ii < 4; ++ii) {
        float4 v = *(const float4*)&Tl[r][jq * 96 + c16 * 16 + ii * 4];
        int pk = __builtin_amdgcn_cvt_pk_fp8_f32(__expf(v.x - rmax),
                                                 __expf(v.y - rmax), 0, false);
        pk = __builtin_amdgcn_cvt_pk_fp8_f32(__expf(v.z - rmax),
                                             __expf(v.w - rmax), pk, true);
        w4[ii] = pk;
      }
      *(int4*)(obase + c16 * 16) = make_int4(w4[0], w4[1], w4[2], w4[3]);
    }
  }

  // ---- bilinear partials ----
  float acc[6] = {0, 0, 0, 0, 0, 0};
  for (int s0 = 0; s0 < RR; s0 += 4) {
    float4 tv = *(const float4*)&Tl[r][s0];
#pragma unroll
    for (int jj = 0; jj < 6; ++jj) {
      const float4 p0 = *(const float4*)&RP[jq * 6 + jj][s0];
      acc[jj] = fmaf(tv.x, p0.x, acc[jj]);
      acc[jj] = fmaf(tv.y, p0.y, acc[jj]);
      acc[jj] = fmaf(tv.z, p0.z, acc[jj]);
      acc[jj] = fmaf(tv.w, p0.w, acc[jj]);
    }
  }
#pragma unroll
  for (int jj = 0; jj < 6; ++jj) {
    const int jp = jq * 6 + jj;
    const int j = jp + 1;
    part[r][j] = (j < K) ? RP[j][gr] * acc[jj] : 0.f;
  }
  __syncthreads();
  if (tid < MM) {
    const int j = tid;
    float s = 0.f;
    if (j >= 1) {
#pragma unroll 4
      for (int rr2 = 0; rr2 < 48; ++rr2) s += part[rr2][j];
    }
    bilinP[(size_t)(b * 8 + chunk) * MM + j] = s;
  }
}

// ---------------- Kernel D: scan with fp8 MFMA matvec -----------------------
// 32 blocks x 768 thr (12 waves x 32 rows). eT swizzled fp8 in LDS; per step:
// B = fp8(t*256/Z) col-0 frags; D = eT . t via mfma_f32_16x16x32_fp8_fp8.
__global__ __launch_bounds__(768) void kD(
    const unsigned char* __restrict__ expb, const float* __restrict__ expTmax,
    const float* __restrict__ aff, const int* __restrict__ nreg,
    const int* __restrict__ mlist, const int* __restrict__ kcnt,
    const float* __restrict__ Em, const float* __restrict__ bilinP,
    float* __restrict__ result) {
  __shared__ long long eT8[RR * RR / 8];       // 147456 B, XOR-swizzled rows
  __shared__ float tf[2][RR];                  // t state (f32)
  __shared__ float wred[2][96];                // per-(w,rt,q) maxima
  __shared__ float fred[12];

  const int b = blockIdx.x;
  const int tid = threadIdx.x;
  const int w = tid >> 6;
  const int lane = tid & 63;
  const int r = lane & 15;
  const int q = lane >> 4;
  const bool act = (r == 0);
  const int nr = nreg[b];

  const int K = kcnt[b];
  if (K == 0) {
    if (tid == 0) result[b] = 0.f;
    return;
  }

  {  // stage fp8 tile global -> LDS with row XOR swizzle ((row&15)<<3)
    const uint4* src = (const uint4*)(expb + (size_t)b * RR * RR);
    char* dst = (char*)eT8;
    for (int i = tid; i < RR * RR / 16; i += 768) {
      uint4 v = src[i];
      const int row = i / 24, c16 = (i % 24) * 16;
      const int base = row * RR + c16;
      const int m = (row & 15) << 3;
      *(long long*)(dst + ((base) ^ m)) =
          (long long)((unsigned long long)v.x | ((unsigned long long)v.y << 32));
      *(long long*)(dst + ((base + 8) ^ m)) =
          (long long)((unsigned long long)v.z | ((unsigned long long)v.w << 32));
    }
  }

  // active lanes own rows w*32 + rt*16 + q*4 + i  (rt=0,1; i=0..3)
  float sF4[2][4], eraw4[2][4];
  if (act) {
#pragma unroll
    for (int rt = 0; rt < 2; ++rt) {
      const int rowb = w * 32 + rt * 16 + q * 4;
      *(float4*)sF4[rt] = *(const float4*)&expTmax[b * RR + rowb];
      const int m0 = mlist[b * MM];
      *(float4*)eraw4[rt] =
          *(const float4*)(aff + ((size_t)(b * MM + m0)) * RR + rowb);
    }
  }

  float L = 0.f;

  for (int k = 0; k < K; ++k) {
    const int rpar = k & 1, wpar = (k + 1) & 1;

    float nraw4[2][4] = {{0, 0, 0, 0}, {0, 0, 0, 0}};
    if (act && k + 1 < K) {
      const int mn = mlist[b * MM + k + 1];
#pragma unroll
      for (int rt = 0; rt < 2; ++rt) {
        const int rowb = w * 32 + rt * 16 + q * 4;
        *(float4*)nraw4[rt] =
            *(const float4*)(aff + ((size_t)(b * MM + mn)) * RR + rowb);
      }
    }

    float tv[2][4];
    if (k == 0) {
      if (act) {
#pragma unroll
        for (int rt = 0; rt < 2; ++rt)
#pragma unroll
          for (int i = 0; i < 4; ++i) {
            const int row = w * 32 + rt * 16 + q * 4 + i;
            tv[rt][i] = (row < nr) ? __expf(eraw4[rt][i]) : 0.f;
          }
      }
    } else {
      // Z = max over wred[rpar][0..95]
      float zm = 0.f;
      if (lane < 24) {
        float4 v = *(const float4*)&wred[rpar][lane * 4];
        zm = fmaxf(fmaxf(v.x, v.y), fmaxf(v.z, v.w));
      }
#pragma unroll
      for (int off = 1; off < 64; off <<= 1) zm = fmaxf(zm, __shfl_xor(zm, off));
      const float invZ = 1.f / zm;
      L += __logf(zm);
      const float bscale = 256.f * invZ;

      f32x4v acc0 = {0.f, 0.f, 0.f, 0.f}, acc1 = {0.f, 0.f, 0.f, 0.f};
      const char* eTB = (const char*)eT8;
      const int axor = r << 3;
      const int arow0 = (w * 32 + r) * RR;
      const int arow1 = (w * 32 + 16 + r) * RR;
#pragma unroll
      for (int kt = 0; kt < 12; ++kt) {
        long long bfrag = 0;
        if (act) {
          float4 ta = *(const float4*)&tf[rpar][kt * 32 + q * 8];
          float4 tb = *(const float4*)&tf[rpar][kt * 32 + q * 8 + 4];
          int lo = __builtin_amdgcn_cvt_pk_fp8_f32(ta.x * bscale, ta.y * bscale,
                                                   0, false);
          lo = __builtin_amdgcn_cvt_pk_fp8_f32(ta.z * bscale, ta.w * bscale,
                                               lo, true);
          int hi = __builtin_amdgcn_cvt_pk_fp8_f32(tb.x * bscale, tb.y * bscale,
                                                   0, false);
          hi = __builtin_amdgcn_cvt_pk_fp8_f32(tb.z * bscale, tb.w * bscale,
                                               hi, true);
          bfrag = (long long)((unsigned long long)(unsigned)lo |
                              ((unsigned long long)(unsigned)hi << 32));
        }
        const int kb = kt * 32 + q * 8;
        long long a0 = *(const long long*)(eTB + ((arow0 + kb) ^ axor));
        long long a1 = *(const long long*)(eTB + ((arow1 + kb) ^ axor));
        acc0 = __builtin_amdgcn_mfma_f32_16x16x32_fp8_fp8(a0, bfrag, acc0, 0, 0, 0);
        acc1 = __builtin_amdgcn_mfma_f32_16x16x32_fp8_fp8(a1, bfrag, acc1, 0, 0, 0);
      }
      if (act) {
#pragma unroll
        for (int i = 0; i < 4; ++i) {
          tv[0][i] = acc0[i] * (__expf(eraw4[0][i]) * sF4[0][i] * 0.00390625f);
          tv[1][i] = acc1[i] * (__expf(eraw4[1][i]) * sF4[1][i] * 0.00390625f);
        }
      }
    }

    if (act) {
#pragma unroll
      for (int rt = 0; rt < 2; ++rt) {
        const int rowb = w * 32 + rt * 16 + q * 4;
        *(float4*)&tf[wpar][rowb] =
            make_float4(tv[rt][0], tv[rt][1], tv[rt][2], tv[rt][3]);
        wred[wpar][w * 8 + rt * 4 + q] =
            fmaxf(fmaxf(tv[rt][0], tv[rt][1]), fmaxf(tv[rt][2], tv[rt][3]));
      }
#pragma unroll
      for (int rt = 0; rt < 2; ++rt)
#pragma unroll
        for (int i = 0; i < 4; ++i) eraw4[rt][i] = nraw4[rt][i];
    }
    __syncthreads();
  }

  // epilogue
  const int fpar = K & 1;
  float fp = (tid < RR) ? tf[fpar][tid] : 0.f;
#pragma unroll
  for (int off = 32; off > 0; off >>= 1) fp += __shfl_xor(fp, off);
  if (lane == 0) fred[w] = fp;
  __syncthreads();
  if (tid == 0) {
    float fs = 0.f;
#pragma unroll
    for (int i = 0; i < 12; ++i) fs += fred[i];
    const float fwd = L + __logf(fmaxf(fs, 1e-37f));
    float gold = Em[b * MM + mlist[b * MM + 0]];
    for (int j = 1; j < K; ++j) {
      float bil = 0.f;
#pragma unroll
      for (int c = 0; c < 8; ++c) bil += bilinP[(size_t)(b * 8 + c) * MM + j];
      gold += bil + Em[b * MM + mlist[b * MM + j]];
    }
    result[b] = fwd - gold;
  }
}

// ---------------- Kernel E: final deterministic reduction ----------
__global__ void kE(const float* __restrict__ result, const int* __restrict__ nmen,
                   float* __restrict__ out) {
  if (threadIdx.x == 0 && blockIdx.x == 0) {
    float s = 0.f;
    int d = 0;
    for (int b = 0; b < 32; ++b) { s += result[b]; d += nmen[b]; }
    if (d < 1) d = 1;
    out[0] = s / (float)d;
  }
}

extern "C" void kernel_launch(void* const* d_in, const int* in_sizes, int n_in,
                              void* d_out, int out_size, void* d_ws, size_t ws_size,
                              hipStream_t stream) {
  const float* region = (const float*)d_in[0];
  const float* aff    = (const float*)d_in[1];
  const float* gt     = (const float*)d_in[2];
  const int*   nmen   = (const int*)d_in[3];
  const int*   nreg   = (const int*)d_in[4];
  const float* t0w    = (const float*)d_in[5];
  const float* t0b    = (const float*)d_in[6];
  const float* t1w    = (const float*)d_in[7];
  const float* t1b    = (const float*)d_in[8];
  const float* trw    = (const float*)d_in[9];
  const float* trb    = (const float*)d_in[10];
  float* out = (float*)d_out;
  char* ws = (char*)d_ws;

  size_t off = 0;
  auto alloc = [&](size_t bytes) {
    void* p = ws + off;
    off += (bytes + 255) & ~(size_t)255;
    return p;
  };
  float*         h0h1    = (float*)alloc((size_t)BB * RR * 32 * 4);       // 1.57 MB
  unsigned char* expb    = (unsigned char*)alloc((size_t)BB * RR * RR);   // 4.72 MB
  float*         expTmax = (float*)alloc((size_t)BB * RR * 4);
  int*           mlist   = (int*)alloc((size_t)BB * MM * 4);
  int*           kcnt    = (int*)alloc((size_t)BB * 4);
  float*         Em      = (float*)alloc((size_t)BB * MM * 4);
  float*         bilinP  = (float*)alloc((size_t)BB * 8 * MM * 4);
  float*         result  = (float*)alloc((size_t)BB * 4);

  kA<<<(BB * RR) / 32, 128, 0, stream>>>(region, t0w, t0b, t1w, t1b, h0h1);
  kYT<<<256, 192, 0, stream>>>(h0h1, trw, trb, gt, aff, nmen, nreg,
                               mlist, kcnt, Em, bilinP, expb, expTmax);
  kD<<<BB, 768, 0, stream>>>(expb, expTmax, aff, nreg, mlist, kcnt, Em,
                             bilinP, result);
  kE<<<1, 64, 0, stream>>>(result, nmen, out);
}

// Round 13
// 156.097 us; speedup vs baseline: 2.2263x; 1.0122x over previous
//
#include <hip/hip_runtime.h>

#define NEGV (-100000000.0f)
typedef __attribute__((ext_vector_type(2))) float f32x2;
typedef __attribute__((ext_vector_type(8))) short bf16x8;
typedef __attribute__((ext_vector_type(4))) float f32x4v;

constexpr int BB = 32, MM = 24, RR = 384, DD = 2048;

// pack two f32 -> two bf16 (round half-up)
static __device__ __forceinline__ unsigned pk2bf(float a, float b) {
  unsigned au = __float_as_uint(a) + 0x8000u;
  unsigned bu = __float_as_uint(b) + 0x8000u;
  return (au >> 16) | (bu & 0xffff0000u);
}

// ---------------- Kernel A: fused fp32->bf16 cast + MFMA GEMM (r11 proven) --
__global__ __launch_bounds__(128) void kA(const float* __restrict__ region,
    const float* __restrict__ t0w, const float* __restrict__ t0b,
    const float* __restrict__ t1w, const float* __restrict__ t1b,
    float* __restrict__ h0h1) {
  __shared__ unsigned short Abuf[2][32 * 128];
  __shared__ unsigned short Bbuf[2][32 * 128];
  const int tid = threadIdx.x;
  const int row0 = blockIdx.x * 32;

  const int srow = tid >> 2;
  const int sq = tid & 3;
  const float* aSrc = region + (size_t)(row0 + srow) * DD + sq * 32;
  const float* bSrc = ((srow < 16) ? (t0w + (size_t)srow * DD)
                                   : (t1w + (size_t)(srow - 16) * DD)) + sq * 32;

  float4 ra[8], rb[8];
  auto LOAD = [&](int t) {
    const int d0 = t * 128;
#pragma unroll
    for (int i = 0; i < 8; ++i) ra[i] = *(const float4*)(aSrc + d0 + i * 4);
#pragma unroll
    for (int i = 0; i < 8; ++i) rb[i] = *(const float4*)(bSrc + d0 + i * 4);
  };
  const int wbase = srow * 256 + sq * 64;
  const int wxor = (srow & 7) << 4;
  auto WRITE = [&](int buf) {
    unsigned char* Ab = (unsigned char*)&Abuf[buf][0];
    unsigned char* Bb = (unsigned char*)&Bbuf[buf][0];
#pragma unroll
    for (int i = 0; i < 4; ++i) {
      float4 x = ra[i * 2], y = ra[i * 2 + 1];
      uint4 pk;
      pk.x = pk2bf(x.x, x.y); pk.y = pk2bf(x.z, x.w);
      pk.z = pk2bf(y.x, y.y); pk.w = pk2bf(y.z, y.w);
      *(uint4*)(Ab + ((wbase + i * 16) ^ wxor)) = pk;
      float4 u = rb[i * 2], v = rb[i * 2 + 1];
      uint4 qk;
      qk.x = pk2bf(u.x, u.y); qk.y = pk2bf(u.z, u.w);
      qk.z = pk2bf(v.x, v.y); qk.w = pk2bf(v.z, v.w);
      *(uint4*)(Bb + ((wbase + i * 16) ^ wxor)) = qk;
    }
  };

  const int w = tid >> 6;
  const int lane = tid & 63;
  const int arow = w * 16 + (lane & 15);
  const int bh = lane & 15;
  const int koff = (lane >> 4) * 8;

  f32x4v acc0 = {0.f, 0.f, 0.f, 0.f}, acc1 = {0.f, 0.f, 0.f, 0.f};

  LOAD(0);
  WRITE(0);
  const int axor = (arow & 7) << 4;
  const int bxor = (bh & 7) << 4;
  for (int t = 0; t < 16; ++t) {
    __syncthreads();
    if (t < 15) LOAD(t + 1);
    const unsigned char* Ab = (const unsigned char*)&Abuf[t & 1][0];
    const unsigned char* Bb = (const unsigned char*)&Bbuf[t & 1][0];
#pragma unroll
    for (int kk = 0; kk < 4; ++kk) {
      const int kb = (kk * 32 + koff) * 2;
      bf16x8 av = *(const bf16x8*)(Ab + ((arow * 256 + kb) ^ axor));
      bf16x8 b0 = *(const bf16x8*)(Bb + ((bh * 256 + kb) ^ bxor));
      bf16x8 b1 = *(const bf16x8*)(Bb + (((bh + 16) * 256 + kb) ^ bxor));
      acc0 = __builtin_amdgcn_mfma_f32_16x16x32_bf16(av, b0, acc0, 0, 0, 0);
      acc1 = __builtin_amdgcn_mfma_f32_16x16x32_bf16(av, b1, acc1, 0, 0, 0);
    }
    if (t < 15) WRITE((t + 1) & 1);
  }

  const float bias0 = t0b[bh];
  const float bias1 = t1b[bh];
#pragma unroll
  for (int i = 0; i < 4; ++i) {
    const int rg = row0 + w * 16 + (lane >> 4) * 4 + i;
    h0h1[(size_t)rg * 32 + bh] = acc0[i] + bias0;
    h0h1[(size_t)rg * 32 + 16 + bh] = acc1[i] + bias1;
  }
}

// ---------------- Kernel YT: rsum/Em/mlist prologue + bilinP + fp8 expT -----
// grid 256 = (b x 8 chunks of 48 rows), 192 threads.
__global__ __launch_bounds__(192) void kYT(const float* __restrict__ h0h1,
    const float* __restrict__ trw, const float* __restrict__ trb,
    const float* __restrict__ gt, const float* __restrict__ aff,
    const int* __restrict__ nmen, const int* __restrict__ nreg,
    int* __restrict__ mlist, int* __restrict__ kcnt, float* __restrict__ Em,
    float* __restrict__ bilinP, unsigned char* __restrict__ expb,
    float* __restrict__ expTmax) {
  __shared__ float h1T[16][388];
  __shared__ float h0L[48][16];
  __shared__ float Tl[48][388];
  __shared__ float RP[MM][392];
  __shared__ float part[48][26];
  __shared__ float rsumL[MM], EmL[MM];
  __shared__ int mlistL[MM];
  __shared__ int kcntL;
  const int b = blockIdx.x & 31;
  const int chunk = blockIdx.x >> 5;
  const int r0 = chunk * 48;
  const int tid = threadIdx.x;
  const int lane = tid & 63;
  const int wv = tid >> 6;
  const int nm = nmen[b], nr = nreg[b];

  // ---- merged kCM prologue: per-m sums on 3 waves ----
  for (int m = wv; m < MM; m += 3) {
    const size_t bm = (size_t)(b * MM + m);
    float p = 0.f, t1 = 0.f, t2 = 0.f;
#pragma unroll
    for (int i = 0; i < 6; ++i) {
      int s = lane * 6 + i;
      float g = gt[bm * RR + s];
      float a = (g >= 0.5f && s < nr && m < nm) ? g : 0.f;
      float e = aff[bm * RR + s];
      p += a;
      t1 += a * e;
      t2 += (a > 0.f) ? a * __logf(a) : 0.f;
    }
#pragma unroll
    for (int off = 32; off > 0; off >>= 1) {
      p += __shfl_xor(p, off);
      t1 += __shfl_xor(t1, off);
      t2 += __shfl_xor(t2, off);
    }
    if (lane == 0) {
      rsumL[m] = p;
      EmL[m] = (p > 0.f) ? (t1 - t2) / p + __logf(p) : 0.f;
    }
  }
  __syncthreads();
  if (tid == 0) {
    int c = 0;
    for (int m = 0; m < MM; ++m)
      if (rsumL[m] > 0.f) mlistL[c++] = m;
    kcntL = c;
    for (int j = c; j < MM; ++j) mlistL[j] = 0;
  }
  __syncthreads();
  if (chunk == 0 && tid < MM) {
    Em[b * MM + tid] = EmL[tid];
    mlist[b * MM + tid] = mlistL[tid];
    if (tid == 0) kcnt[b] = kcntL;
  }
  const int K = kcntL;

  // ---- staging ----
  for (int h = 0; h < 16; ++h)
    for (int s = tid; s < RR; s += 192)
      h1T[h][s] = h0h1[((size_t)b * RR + s) * 32 + 16 + h];
  for (int i = tid; i < 768; i += 192) {
    int row = i >> 4, h = i & 15;
    h0L[row][h] = h0h1[((size_t)b * RR + r0 + row) * 32 + h];
  }
  for (int j = 0; j < MM; ++j) {
    if (j < K) {
      int m = mlistL[j];
      float inv = 1.f / rsumL[m];
      for (int s = tid; s < RR; s += 192) {
        float g = gt[((size_t)(b * MM + m)) * RR + s];
        RP[j][s] = (g >= 0.5f && s < nr) ? g * inv : 0.f;
      }
    } else {
      for (int s = tid; s < RR; s += 192) RP[j][s] = 0.f;
    }
  }
  float w0[16];
#pragma unroll
  for (int h = 0; h < 16; ++h) w0[h] = trw[h];
  const float tb = trb[0];
  __syncthreads();

  const int r = tid >> 2;
  const int jq = tid & 3;
  const int gr = r0 + r;

  for (int s = jq * 96; s < jq * 96 + 96; ++s) {
    float a = tb;
#pragma unroll
    for (int h = 0; h < 16; ++h)
      a += fmaxf(h0L[r][h] + h1T[h][s], 0.f) * w0[h];
    Tl[r][s] = a;
  }
  __syncthreads();

  // ---- fp8 export ----
  {
    float rmax = -3.0e38f;
    for (int c = 0; c < 96; c += 4) {
      float4 v = *(const float4*)&Tl[r][jq * 96 + c];
      rmax = fmaxf(rmax, fmaxf(fmaxf(v.x, v.y), fmaxf(v.z, v.w)));
    }
    rmax = fmaxf(rmax, __shfl_xor(rmax, 1));
    rmax = fmaxf(rmax, __shfl_xor(rmax, 2));
    if (jq == 0) expTmax[b * RR + gr] = __expf(rmax);
    unsigned char* obase = expb + ((size_t)b * RR + gr) * RR + jq * 96;
#pragma unroll
    for (int c16 = 0; c16 < 6; ++c16) {
      int w4[4];
#pragma unroll
      for (int ii = 0; ii < 4; ++ii) {
        float4 v = *(const float4*)&Tl[r][jq * 96 + c16 * 16 + ii * 4];
        int pk = __builtin_amdgcn_cvt_pk_fp8_f32(__expf(v.x - rmax),
                                                 __expf(v.y - rmax), 0, false);
        pk = __builtin_amdgcn_cvt_pk_fp8_f32(__expf(v.z - rmax),
                                             __expf(v.w - rmax), pk, true);
        w4[ii] = pk;
      }
      *(int4*)(obase + c16 * 16) = make_int4(w4[0], w4[1], w4[2], w4[3]);
    }
  }

  // ---- bilinear partials ----
  float acc[6] = {0, 0, 0, 0, 0, 0};
  for (int s0 = 0; s0 < RR; s0 += 4) {
    float4 tv = *(const float4*)&Tl[r][s0];
#pragma unroll
    for (int jj = 0; jj < 6; ++jj) {
      const float4 p0 = *(const float4*)&RP[jq * 6 + jj][s0];
      acc[jj] = fmaf(tv.x, p0.x, acc[jj]);
      acc[jj] = fmaf(tv.y, p0.y, acc[jj]);
      acc[jj] = fmaf(tv.z, p0.z, acc[jj]);
      acc[jj] = fmaf(tv.w, p0.w, acc[jj]);
    }
  }
#pragma unroll
  for (int jj = 0; jj < 6; ++jj) {
    const int jp = jq * 6 + jj;
    const int j = jp + 1;
    part[r][j] = (j < K) ? RP[j][gr] * acc[jj] : 0.f;
  }
  __syncthreads();
  if (tid < MM) {
    const int j = tid;
    float s = 0.f;
    if (j >= 1) {
#pragma unroll 4
      for (int rr2 = 0; rr2 < 48; ++rr2) s += part[rr2][j];
    }
    bilinP[(size_t)(b * 8 + chunk) * MM + j] = s;
  }
}

// ---------------- Kernel D: scan with fp8 MFMA matvec -----------------------
// 32 blocks x 768 thr (12 waves x 32 rows). eT swizzled fp8 in LDS; per step:
// B = fp8(t*256/Z) col-0 frags; D = eT . t via mfma_f32_16x16x32_fp8_fp8.
__global__ __launch_bounds__(768) void kD(
    const unsigned char* __restrict__ expb, const float* __restrict__ expTmax,
    const float* __restrict__ aff, const int* __restrict__ nreg,
    const int* __restrict__ mlist, const int* __restrict__ kcnt,
    const float* __restrict__ Em, const float* __restrict__ bilinP,
    float* __restrict__ result) {
  __shared__ long long eT8[RR * RR / 8];       // 147456 B, XOR-swizzled rows
  __shared__ float tf[2][RR];                  // t state (f32)
  __shared__ float wred[2][96];                // per-(w,rt,q) maxima
  __shared__ float fred[12];

  const int b = blockIdx.x;
  const int tid = threadIdx.x;
  const int w = tid >> 6;
  const int lane = tid & 63;
  const int r = lane & 15;
  const int q = lane >> 4;
  const bool act = (r == 0);
  const int nr = nreg[b];

  const int K = kcnt[b];
  if (K == 0) {
    if (tid == 0) result[b] = 0.f;
    return;
  }

  {  // stage fp8 tile global -> LDS with row XOR swizzle ((row&15)<<3)
    const uint4* src = (const uint4*)(expb + (size_t)b * RR * RR);
    char* dst = (char*)eT8;
    for (int i = tid; i < RR * RR / 16; i += 768) {
      uint4 v = src[i];
      const int row = i / 24, c16 = (i % 24) * 16;
      const int base = row * RR + c16;
      const int m = (row & 15) << 3;
      *(long long*)(dst + ((base) ^ m)) =
          (long long)((unsigned long long)v.x | ((unsigned long long)v.y << 32));
      *(long long*)(dst + ((base + 8) ^ m)) =
          (long long)((unsigned long long)v.z | ((unsigned long long)v.w << 32));
    }
  }

  // active lanes own rows w*32 + rt*16 + q*4 + i  (rt=0,1; i=0..3)
  float sF4[2][4], eraw4[2][4];
  if (act) {
#pragma unroll
    for (int rt = 0; rt < 2; ++rt) {
      const int rowb = w * 32 + rt * 16 + q * 4;
      *(float4*)sF4[rt] = *(const float4*)&expTmax[b * RR + rowb];
      const int m0 = mlist[b * MM];
      *(float4*)eraw4[rt] =
          *(const float4*)(aff + ((size_t)(b * MM + m0)) * RR + rowb);
    }
  }

  float L = 0.f;

  for (int k = 0; k < K; ++k) {
    const int rpar = k & 1, wpar = (k + 1) & 1;

    float nraw4[2][4] = {{0, 0, 0, 0}, {0, 0, 0, 0}};
    if (act && k + 1 < K) {
      const int mn = mlist[b * MM + k + 1];
#pragma unroll
      for (int rt = 0; rt < 2; ++rt) {
        const int rowb = w * 32 + rt * 16 + q * 4;
        *(float4*)nraw4[rt] =
            *(const float4*)(aff + ((size_t)(b * MM + mn)) * RR + rowb);
      }
    }

    float tv[2][4];
    if (k == 0) {
      if (act) {
#pragma unroll
        for (int rt = 0; rt < 2; ++rt)
#pragma unroll
          for (int i = 0; i < 4; ++i) {
            const int row = w * 32 + rt * 16 + q * 4 + i;
            tv[rt][i] = (row < nr) ? __expf(eraw4[rt][i]) : 0.f;
          }
      }
    } else {
      // Z = max over wred[rpar][0..95]
      float zm = 0.f;
      if (lane < 24) {
        float4 v = *(const float4*)&wred[rpar][lane * 4];
        zm = fmaxf(fmaxf(v.x, v.y), fmaxf(v.z, v.w));
      }
#pragma unroll
      for (int off = 1; off < 64; off <<= 1) zm = fmaxf(zm, __shfl_xor(zm, off));
      const float invZ = 1.f / zm;
      L += __logf(zm);
      const float bscale = 256.f * invZ;

      f32x4v acc0 = {0.f, 0.f, 0.f, 0.f}, acc1 = {0.f, 0.f, 0.f, 0.f};
      const char* eTB = (const char*)eT8;
      const int axor = r << 3;
      const int arow0 = (w * 32 + r) * RR;
      const int arow1 = (w * 32 + 16 + r) * RR;
#pragma unroll
      for (int kt = 0; kt < 12; ++kt) {
        long long bfrag = 0;
        if (act) {
          float4 ta = *(const float4*)&tf[rpar][kt * 32 + q * 8];
          float4 tb = *(const float4*)&tf[rpar][kt * 32 + q * 8 + 4];
          int lo = __builtin_amdgcn_cvt_pk_fp8_f32(ta.x * bscale, ta.y * bscale,
                                                   0, false);
          lo = __builtin_amdgcn_cvt_pk_fp8_f32(ta.z * bscale, ta.w * bscale,
                                               lo, true);
          int hi = __builtin_amdgcn_cvt_pk_fp8_f32(tb.x * bscale, tb.y * bscale,
                                                   0, false);
          hi = __builtin_amdgcn_cvt_pk_fp8_f32(tb.z * bscale, tb.w * bscale,
                                               hi, true);
          bfrag = (long long)((unsigned long long)(unsigned)lo |
                              ((unsigned long long)(unsigned)hi << 32));
        }
        const int kb = kt * 32 + q * 8;
        long long a0 = *(const long long*)(eTB + ((arow0 + kb) ^ axor));
        long long a1 = *(const long long*)(eTB + ((arow1 + kb) ^ axor));
        acc0 = __builtin_amdgcn_mfma_f32_16x16x32_fp8_fp8(a0, bfrag, acc0, 0, 0, 0);
        acc1 = __builtin_amdgcn_mfma_f32_16x16x32_fp8_fp8(a1, bfrag, acc1, 0, 0, 0);
      }
      if (act) {
#pragma unroll
        for (int i = 0; i < 4; ++i) {
          tv[0][i] = acc0[i] * (__expf(eraw4[0][i]) * sF4[0][i] * 0.00390625f);
          tv[1][i] = acc1[i] * (__expf(eraw4[1][i]) * sF4[1][i] * 0.00390625f);
        }
      }
    }

    if (act) {
#pragma unroll
      for (int rt = 0; rt < 2; ++rt) {
        const int rowb = w * 32 + rt * 16 + q * 4;
        *(float4*)&tf[wpar][rowb] =
            make_float4(tv[rt][0], tv[rt][1], tv[rt][2], tv[rt][3]);
        wred[wpar][w * 8 + rt * 4 + q] =
            fmaxf(fmaxf(tv[rt][0], tv[rt][1]), fmaxf(tv[rt][2], tv[rt][3]));
      }
#pragma unroll
      for (int rt = 0; rt < 2; ++rt)
#pragma unroll
        for (int i = 0; i < 4; ++i) eraw4[rt][i] = nraw4[rt][i];
    }
    __syncthreads();
  }

  // epilogue
  const int fpar = K & 1;
  float fp = (tid < RR) ? tf[fpar][tid] : 0.f;
#pragma unroll
  for (int off = 32; off > 0; off >>= 1) fp += __shfl_xor(fp, off);
  if (lane == 0) fred[w] = fp;
  __syncthreads();
  if (tid == 0) {
    float fs = 0.f;
#pragma unroll
    for (int i = 0; i < 12; ++i) fs += fred[i];
    const float fwd = L + __logf(fmaxf(fs, 1e-37f));
    float gold = Em[b * MM + mlist[b * MM + 0]];
    for (int j = 1; j < K; ++j) {
      float bil = 0.f;
#pragma unroll
      for (int c = 0; c < 8; ++c) bil += bilinP[(size_t)(b * 8 + c) * MM + j];
      gold += bil + Em[b * MM + mlist[b * MM + j]];
    }
    result[b] = fwd - gold;
  }
}

// ---------------- Kernel E: final deterministic reduction ----------
__global__ void kE(const float* __restrict__ result, const int* __restrict__ nmen,
                   float* __restrict__ out) {
  if (threadIdx.x == 0 && blockIdx.x == 0) {
    float s = 0.f;
    int d = 0;
    for (int b = 0; b < 32; ++b) { s += result[b]; d += nmen[b]; }
    if (d < 1) d = 1;
    out[0] = s / (float)d;
  }
}

extern "C" void kernel_launch(void* const* d_in, const int* in_sizes, int n_in,
                              void* d_out, int out_size, void* d_ws, size_t ws_size,
                              hipStream_t stream) {
  const float* region = (const float*)d_in[0];
  const float* aff    = (const float*)d_in[1];
  const float* gt     = (const float*)d_in[2];
  const int*   nmen   = (const int*)d_in[3];
  const int*   nreg   = (const int*)d_in[4];
  const float* t0w    = (const float*)d_in[5];
  const float* t0b    = (const float*)d_in[6];
  const float* t1w    = (const float*)d_in[7];
  const float* t1b    = (const float*)d_in[8];
  const float* trw    = (const float*)d_in[9];
  const float* trb    = (const float*)d_in[10];
  float* out = (float*)d_out;
  char* ws = (char*)d_ws;

  size_t off = 0;
  auto alloc = [&](size_t bytes) {
    void* p = ws + off;
    off += (bytes + 255) & ~(size_t)255;
    return p;
  };
  float*         h0h1    = (float*)alloc((size_t)BB * RR * 32 * 4);       // 1.57 MB
  unsigned char* expb    = (unsigned char*)alloc((size_t)BB * RR * RR);   // 4.72 MB
  float*         expTmax = (float*)alloc((size_t)BB * RR * 4);
  int*           mlist   = (int*)alloc((size_t)BB * MM * 4);
  int*           kcnt    = (int*)alloc((size_t)BB * 4);
  float*         Em      = (float*)alloc((size_t)BB * MM * 4);
  float*         bilinP  = (float*)alloc((size_t)BB * 8 * MM * 4);
  float*         result  = (float*)alloc((size_t)BB * 4);

  kA<<<(BB * RR) / 32, 128, 0, stream>>>(region, t0w, t0b, t1w, t1b, h0h1);
  kYT<<<256, 192, 0, stream>>>(h0h1, trw, trb, gt, aff, nmen, nreg,
                               mlist, kcnt, Em, bilinP, expb, expTmax);
  kD<<<BB, 768, 0, stream>>>(expb, expTmax, aff, nreg, mlist, kcnt, Em,
                             bilinP, result);
  kE<<<1, 64, 0, stream>>>(result, nmen, out);
}

// Round 14
// 151.972 us; speedup vs baseline: 2.2867x; 1.0271x over previous
//
#include <hip/hip_runtime.h>

#define NEGV (-100000000.0f)
typedef __attribute__((ext_vector_type(2))) float f32x2;
typedef __attribute__((ext_vector_type(8))) short bf16x8;
typedef __attribute__((ext_vector_type(4))) float f32x4v;

constexpr int BB = 32, MM = 24, RR = 384, DD = 2048;
constexpr int EPITCH = 400;   // eT row pitch (bytes): 100 dwords = 4 mod 32 banks

// pack two f32 -> two bf16 (round half-up)
static __device__ __forceinline__ unsigned pk2bf(float a, float b) {
  unsigned au = __float_as_uint(a) + 0x8000u;
  unsigned bu = __float_as_uint(b) + 0x8000u;
  return (au >> 16) | (bu & 0xffff0000u);
}

// ---------------- Kernel A: fused fp32->bf16 cast + MFMA GEMM (r11 proven) --
__global__ __launch_bounds__(128) void kA(const float* __restrict__ region,
    const float* __restrict__ t0w, const float* __restrict__ t0b,
    const float* __restrict__ t1w, const float* __restrict__ t1b,
    float* __restrict__ h0h1) {
  __shared__ unsigned short Abuf[2][32 * 128];
  __shared__ unsigned short Bbuf[2][32 * 128];
  const int tid = threadIdx.x;
  const int row0 = blockIdx.x * 32;

  const int srow = tid >> 2;
  const int sq = tid & 3;
  const float* aSrc = region + (size_t)(row0 + srow) * DD + sq * 32;
  const float* bSrc = ((srow < 16) ? (t0w + (size_t)srow * DD)
                                   : (t1w + (size_t)(srow - 16) * DD)) + sq * 32;

  float4 ra[8], rb[8];
  auto LOAD = [&](int t) {
    const int d0 = t * 128;
#pragma unroll
    for (int i = 0; i < 8; ++i) ra[i] = *(const float4*)(aSrc + d0 + i * 4);
#pragma unroll
    for (int i = 0; i < 8; ++i) rb[i] = *(const float4*)(bSrc + d0 + i * 4);
  };
  const int wbase = srow * 256 + sq * 64;
  const int wxor = (srow & 7) << 4;
  auto WRITE = [&](int buf) {
    unsigned char* Ab = (unsigned char*)&Abuf[buf][0];
    unsigned char* Bb = (unsigned char*)&Bbuf[buf][0];
#pragma unroll
    for (int i = 0; i < 4; ++i) {
      float4 x = ra[i * 2], y = ra[i * 2 + 1];
      uint4 pk;
      pk.x = pk2bf(x.x, x.y); pk.y = pk2bf(x.z, x.w);
      pk.z = pk2bf(y.x, y.y); pk.w = pk2bf(y.z, y.w);
      *(uint4*)(Ab + ((wbase + i * 16) ^ wxor)) = pk;
      float4 u = rb[i * 2], v = rb[i * 2 + 1];
      uint4 qk;
      qk.x = pk2bf(u.x, u.y); qk.y = pk2bf(u.z, u.w);
      qk.z = pk2bf(v.x, v.y); qk.w = pk2bf(v.z, v.w);
      *(uint4*)(Bb + ((wbase + i * 16) ^ wxor)) = qk;
    }
  };

  const int w = tid >> 6;
  const int lane = tid & 63;
  const int arow = w * 16 + (lane & 15);
  const int bh = lane & 15;
  const int koff = (lane >> 4) * 8;

  f32x4v acc0 = {0.f, 0.f, 0.f, 0.f}, acc1 = {0.f, 0.f, 0.f, 0.f};

  LOAD(0);
  WRITE(0);
  const int axor = (arow & 7) << 4;
  const int bxor = (bh & 7) << 4;
  for (int t = 0; t < 16; ++t) {
    __syncthreads();
    if (t < 15) LOAD(t + 1);
    const unsigned char* Ab = (const unsigned char*)&Abuf[t & 1][0];
    const unsigned char* Bb = (const unsigned char*)&Bbuf[t & 1][0];
#pragma unroll
    for (int kk = 0; kk < 4; ++kk) {
      const int kb = (kk * 32 + koff) * 2;
      bf16x8 av = *(const bf16x8*)(Ab + ((arow * 256 + kb) ^ axor));
      bf16x8 b0 = *(const bf16x8*)(Bb + ((bh * 256 + kb) ^ bxor));
      bf16x8 b1 = *(const bf16x8*)(Bb + (((bh + 16) * 256 + kb) ^ bxor));
      acc0 = __builtin_amdgcn_mfma_f32_16x16x32_bf16(av, b0, acc0, 0, 0, 0);
      acc1 = __builtin_amdgcn_mfma_f32_16x16x32_bf16(av, b1, acc1, 0, 0, 0);
    }
    if (t < 15) WRITE((t + 1) & 1);
  }

  const float bias0 = t0b[bh];
  const float bias1 = t1b[bh];
#pragma unroll
  for (int i = 0; i < 4; ++i) {
    const int rg = row0 + w * 16 + (lane >> 4) * 4 + i;
    h0h1[(size_t)rg * 32 + bh] = acc0[i] + bias0;
    h0h1[(size_t)rg * 32 + 16 + bh] = acc1[i] + bias1;
  }
}

// ---------------- Kernel YT: rsum/Em/mlist prologue + bilinP + fp8 expT -----
__global__ __launch_bounds__(192) void kYT(const float* __restrict__ h0h1,
    const float* __restrict__ trw, const float* __restrict__ trb,
    const float* __restrict__ gt, const float* __restrict__ aff,
    const int* __restrict__ nmen, const int* __restrict__ nreg,
    int* __restrict__ mlist, int* __restrict__ kcnt, float* __restrict__ Em,
    float* __restrict__ bilinP, unsigned char* __restrict__ expb,
    float* __restrict__ expTmax) {
  __shared__ float h1T[16][388];
  __shared__ float h0L[48][16];
  __shared__ float Tl[48][388];
  __shared__ float RP[MM][392];
  __shared__ float part[48][26];
  __shared__ float rsumL[MM], EmL[MM];
  __shared__ int mlistL[MM];
  __shared__ int kcntL;
  const int b = blockIdx.x & 31;
  const int chunk = blockIdx.x >> 5;
  const int r0 = chunk * 48;
  const int tid = threadIdx.x;
  const int lane = tid & 63;
  const int wv = tid >> 6;
  const int nm = nmen[b], nr = nreg[b];

  for (int m = wv; m < MM; m += 3) {
    const size_t bm = (size_t)(b * MM + m);
    float p = 0.f, t1 = 0.f, t2 = 0.f;
#pragma unroll
    for (int i = 0; i < 6; ++i) {
      int s = lane * 6 + i;
      float g = gt[bm * RR + s];
      float a = (g >= 0.5f && s < nr && m < nm) ? g : 0.f;
      float e = aff[bm * RR + s];
      p += a;
      t1 += a * e;
      t2 += (a > 0.f) ? a * __logf(a) : 0.f;
    }
#pragma unroll
    for (int off = 32; off > 0; off >>= 1) {
      p += __shfl_xor(p, off);
      t1 += __shfl_xor(t1, off);
      t2 += __shfl_xor(t2, off);
    }
    if (lane == 0) {
      rsumL[m] = p;
      EmL[m] = (p > 0.f) ? (t1 - t2) / p + __logf(p) : 0.f;
    }
  }
  __syncthreads();
  if (tid == 0) {
    int c = 0;
    for (int m = 0; m < MM; ++m)
      if (rsumL[m] > 0.f) mlistL[c++] = m;
    kcntL = c;
    for (int j = c; j < MM; ++j) mlistL[j] = 0;
  }
  __syncthreads();
  if (chunk == 0 && tid < MM) {
    Em[b * MM + tid] = EmL[tid];
    mlist[b * MM + tid] = mlistL[tid];
    if (tid == 0) kcnt[b] = kcntL;
  }
  const int K = kcntL;

  for (int h = 0; h < 16; ++h)
    for (int s = tid; s < RR; s += 192)
      h1T[h][s] = h0h1[((size_t)b * RR + s) * 32 + 16 + h];
  for (int i = tid; i < 768; i += 192) {
    int row = i >> 4, h = i & 15;
    h0L[row][h] = h0h1[((size_t)b * RR + r0 + row) * 32 + h];
  }
  for (int j = 0; j < MM; ++j) {
    if (j < K) {
      int m = mlistL[j];
      float inv = 1.f / rsumL[m];
      for (int s = tid; s < RR; s += 192) {
        float g = gt[((size_t)(b * MM + m)) * RR + s];
        RP[j][s] = (g >= 0.5f && s < nr) ? g * inv : 0.f;
      }
    } else {
      for (int s = tid; s < RR; s += 192) RP[j][s] = 0.f;
    }
  }
  float w0[16];
#pragma unroll
  for (int h = 0; h < 16; ++h) w0[h] = trw[h];
  const float tb = trb[0];
  __syncthreads();

  const int r = tid >> 2;
  const int jq = tid & 3;
  const int gr = r0 + r;

  for (int s = jq * 96; s < jq * 96 + 96; ++s) {
    float a = tb;
#pragma unroll
    for (int h = 0; h < 16; ++h)
      a += fmaxf(h0L[r][h] + h1T[h][s], 0.f) * w0[h];
    Tl[r][s] = a;
  }
  __syncthreads();

  {
    float rmax = -3.0e38f;
    for (int c = 0; c < 96; c += 4) {
      float4 v = *(const float4*)&Tl[r][jq * 96 + c];
      rmax = fmaxf(rmax, fmaxf(fmaxf(v.x, v.y), fmaxf(v.z, v.w)));
    }
    rmax = fmaxf(rmax, __shfl_xor(rmax, 1));
    rmax = fmaxf(rmax, __shfl_xor(rmax, 2));
    if (jq == 0) expTmax[b * RR + gr] = __expf(rmax);
    unsigned char* obase = expb + ((size_t)b * RR + gr) * RR + jq * 96;
#pragma unroll
    for (int c16 = 0; c16 < 6; ++c16) {
      int w4[4];
#pragma unroll
      for (int ii = 0; ii < 4; ++ii) {
        float4 v = *(const float4*)&Tl[r][jq * 96 + c16 * 16 + ii * 4];
        int pk = __builtin_amdgcn_cvt_pk_fp8_f32(__expf(v.x - rmax),
                                                 __expf(v.y - rmax), 0, false);
        pk = __builtin_amdgcn_cvt_pk_fp8_f32(__expf(v.z - rmax),
                                             __expf(v.w - rmax), pk, true);
        w4[ii] = pk;
      }
      *(int4*)(obase + c16 * 16) = make_int4(w4[0], w4[1], w4[2], w4[3]);
    }
  }

  float acc[6] = {0, 0, 0, 0, 0, 0};
  for (int s0 = 0; s0 < RR; s0 += 4) {
    float4 tv = *(const float4*)&Tl[r][s0];
#pragma unroll
    for (int jj = 0; jj < 6; ++jj) {
      const float4 p0 = *(const float4*)&RP[jq * 6 + jj][s0];
      acc[jj] = fmaf(tv.x, p0.x, acc[jj]);
      acc[jj] = fmaf(tv.y, p0.y, acc[jj]);
      acc[jj] = fmaf(tv.z, p0.z, acc[jj]);
      acc[jj] = fmaf(tv.w, p0.w, acc[jj]);
    }
  }
#pragma unroll
  for (int jj = 0; jj < 6; ++jj) {
    const int jp = jq * 6 + jj;
    const int j = jp + 1;
    part[r][j] = (j < K) ? RP[j][gr] * acc[jj] : 0.f;
  }
  __syncthreads();
  if (tid < MM) {
    const int j = tid;
    float s = 0.f;
    if (j >= 1) {
#pragma unroll 4
      for (int rr2 = 0; rr2 < 48; ++rr2) s += part[rr2][j];
    }
    bilinP[(size_t)(b * 8 + chunk) * MM + j] = s;
  }
}

// ---------------- Kernel D: fp8 MFMA scan, padded-pitch LDS (no swizzle) ----
// 32 blocks x 768 thr (12 waves x 32 rows). eT rows padded to 400 B: bank
// stride 4 -> b64 A-frag reads are 2-way (free); frag addr = base + imm offset.
__global__ __launch_bounds__(768) void kD(
    const unsigned char* __restrict__ expb, const float* __restrict__ expTmax,
    const float* __restrict__ aff, const int* __restrict__ nreg,
    const int* __restrict__ mlist, const int* __restrict__ kcnt,
    const float* __restrict__ Em, const float* __restrict__ bilinP,
    float* __restrict__ result) {
  __shared__ unsigned char eT[RR * EPITCH];    // 153600 B
  __shared__ float tf[2][RR];
  __shared__ float wred[2][12];
  __shared__ float fred[12];

  const int b = blockIdx.x;
  const int tid = threadIdx.x;
  const int w = tid >> 6;
  const int lane = tid & 63;
  const int r = lane & 15;
  const int q = lane >> 4;
  const bool act = (r == 0);
  const int nr = nreg[b];

  const int K = kcnt[b];
  if (K == 0) {
    if (tid == 0) result[b] = 0.f;
    return;
  }

  {  // stage fp8 tile -> padded LDS rows (plain copy, coalesced reads)
    const uint4* src = (const uint4*)(expb + (size_t)b * RR * RR);
#pragma unroll
    for (int j = 0; j < 12; ++j) {
      const int i = tid + j * 768;
      uint4 v = src[i];
      const int row = i / 24;
      const int c = (i - row * 24) * 16;
      *(uint4*)(eT + row * EPITCH + c) = v;
    }
  }

  // per-thread A-frag base (row-tile 0; row-tile 1 = +16*EPITCH via imm)
  const int abase = (w * 32 + r) * EPITCH + q * 8;

  float sF4[2][4], eraw4[2][4];
  if (act) {
#pragma unroll
    for (int rt = 0; rt < 2; ++rt) {
      const int rowb = w * 32 + rt * 16 + q * 4;
      *(float4*)sF4[rt] = *(const float4*)&expTmax[b * RR + rowb];
      const int m0 = mlist[b * MM];
      *(float4*)eraw4[rt] =
          *(const float4*)(aff + ((size_t)(b * MM + m0)) * RR + rowb);
    }
  }

  float L = 0.f;

  for (int k = 0; k < K; ++k) {
    const int rpar = k & 1, wpar = (k + 1) & 1;

    float nraw4[2][4] = {{0, 0, 0, 0}, {0, 0, 0, 0}};
    if (act && k + 1 < K) {
      const int mn = mlist[b * MM + k + 1];
#pragma unroll
      for (int rt = 0; rt < 2; ++rt) {
        const int rowb = w * 32 + rt * 16 + q * 4;
        *(float4*)nraw4[rt] =
            *(const float4*)(aff + ((size_t)(b * MM + mn)) * RR + rowb);
      }
    }

    float tv[2][4] = {{0, 0, 0, 0}, {0, 0, 0, 0}};
    if (k == 0) {
      if (act) {
#pragma unroll
        for (int rt = 0; rt < 2; ++rt)
#pragma unroll
          for (int i = 0; i < 4; ++i) {
            const int row = w * 32 + rt * 16 + q * 4 + i;
            tv[rt][i] = (row < nr) ? __expf(eraw4[rt][i]) : 0.f;
          }
      }
    } else {
      // Z = max over 12 per-wave maxima (3 float4 + 11 v_max, no shuffles)
      float4 z0 = *(const float4*)&wred[rpar][0];
      float4 z1 = *(const float4*)&wred[rpar][4];
      float4 z2 = *(const float4*)&wred[rpar][8];
      float zm = fmaxf(fmaxf(fmaxf(z0.x, z0.y), fmaxf(z0.z, z0.w)),
                       fmaxf(fmaxf(fmaxf(z1.x, z1.y), fmaxf(z1.z, z1.w)),
                             fmaxf(fmaxf(z2.x, z2.y), fmaxf(z2.z, z2.w))));
      const float invZ = 1.f / zm;
      L += __logf(zm);
      const float bscale = 256.f * invZ;

      f32x4v acc0 = {0.f, 0.f, 0.f, 0.f}, acc1 = {0.f, 0.f, 0.f, 0.f};
#pragma unroll
      for (int kt = 0; kt < 12; ++kt) {
        long long bfrag = 0;
        if (act) {
          float4 ta = *(const float4*)&tf[rpar][kt * 32 + q * 8];
          float4 tb = *(const float4*)&tf[rpar][kt * 32 + q * 8 + 4];
          int lo = __builtin_amdgcn_cvt_pk_fp8_f32(ta.x * bscale, ta.y * bscale,
                                                   0, false);
          lo = __builtin_amdgcn_cvt_pk_fp8_f32(ta.z * bscale, ta.w * bscale,
                                               lo, true);
          int hi = __builtin_amdgcn_cvt_pk_fp8_f32(tb.x * bscale, tb.y * bscale,
                                                   0, false);
          hi = __builtin_amdgcn_cvt_pk_fp8_f32(tb.z * bscale, tb.w * bscale,
                                               hi, true);
          bfrag = (long long)((unsigned long long)(unsigned)lo |
                              ((unsigned long long)(unsigned)hi << 32));
        }
        long long a0 = *(const long long*)(eT + abase + kt * 32);
        long long a1 = *(const long long*)(eT + abase + 16 * EPITCH + kt * 32);
        acc0 = __builtin_amdgcn_mfma_f32_16x16x32_fp8_fp8(a0, bfrag, acc0, 0, 0, 0);
        acc1 = __builtin_amdgcn_mfma_f32_16x16x32_fp8_fp8(a1, bfrag, acc1, 0, 0, 0);
      }
      if (act) {
#pragma unroll
        for (int i = 0; i < 4; ++i) {
          tv[0][i] = acc0[i] * (__expf(eraw4[0][i]) * sF4[0][i] * 0.00390625f);
          tv[1][i] = acc1[i] * (__expf(eraw4[1][i]) * sF4[1][i] * 0.00390625f);
        }
      }
    }

    // per-wave max via 2 shuffles; write t state
    float lm = 0.f;
    if (act) {
#pragma unroll
      for (int rt = 0; rt < 2; ++rt) {
        const int rowb = w * 32 + rt * 16 + q * 4;
        *(float4*)&tf[wpar][rowb] =
            make_float4(tv[rt][0], tv[rt][1], tv[rt][2], tv[rt][3]);
        lm = fmaxf(lm, fmaxf(fmaxf(tv[rt][0], tv[rt][1]),
                             fmaxf(tv[rt][2], tv[rt][3])));
      }
#pragma unroll
      for (int rt = 0; rt < 2; ++rt)
#pragma unroll
        for (int i = 0; i < 4; ++i) eraw4[rt][i] = nraw4[rt][i];
    }
    lm = fmaxf(lm, __shfl_xor(lm, 16));
    lm = fmaxf(lm, __shfl_xor(lm, 32));
    if (lane == 0) wred[wpar][w] = lm;
    __syncthreads();
  }

  // epilogue
  const int fpar = K & 1;
  float fp = (tid < RR) ? tf[fpar][tid] : 0.f;
#pragma unroll
  for (int off = 32; off > 0; off >>= 1) fp += __shfl_xor(fp, off);
  if (lane == 0) fred[w] = fp;
  __syncthreads();
  if (tid == 0) {
    float fs = 0.f;
#pragma unroll
    for (int i = 0; i < 12; ++i) fs += fred[i];
    const float fwd = L + __logf(fmaxf(fs, 1e-37f));
    float gold = Em[b * MM + mlist[b * MM + 0]];
    for (int j = 1; j < K; ++j) {
      float bil = 0.f;
#pragma unroll
      for (int c = 0; c < 8; ++c) bil += bilinP[(size_t)(b * 8 + c) * MM + j];
      gold += bil + Em[b * MM + mlist[b * MM + j]];
    }
    result[b] = fwd - gold;
  }
}

// ---------------- Kernel E: final deterministic reduction ----------
__global__ void kE(const float* __restrict__ result, const int* __restrict__ nmen,
                   float* __restrict__ out) {
  if (threadIdx.x == 0 && blockIdx.x == 0) {
    float s = 0.f;
    int d = 0;
    for (int b = 0; b < 32; ++b) { s += result[b]; d += nmen[b]; }
    if (d < 1) d = 1;
    out[0] = s / (float)d;
  }
}

extern "C" void kernel_launch(void* const* d_in, const int* in_sizes, int n_in,
                              void* d_out, int out_size, void* d_ws, size_t ws_size,
                              hipStream_t stream) {
  const float* region = (const float*)d_in[0];
  const float* aff    = (const float*)d_in[1];
  const float* gt     = (const float*)d_in[2];
  const int*   nmen   = (const int*)d_in[3];
  const int*   nreg   = (const int*)d_in[4];
  const float* t0w    = (const float*)d_in[5];
  const float* t0b    = (const float*)d_in[6];
  const float* t1w    = (const float*)d_in[7];
  const float* t1b    = (const float*)d_in[8];
  const float* trw    = (const float*)d_in[9];
  const float* trb    = (const float*)d_in[10];
  float* out = (float*)d_out;
  char* ws = (char*)d_ws;

  size_t off = 0;
  auto alloc = [&](size_t bytes) {
    void* p = ws + off;
    off += (bytes + 255) & ~(size_t)255;
    return p;
  };
  float*         h0h1    = (float*)alloc((size_t)BB * RR * 32 * 4);       // 1.57 MB
  unsigned char* expb    = (unsigned char*)alloc((size_t)BB * RR * RR);   // 4.72 MB
  float*         expTmax = (float*)alloc((size_t)BB * RR * 4);
  int*           mlist   = (int*)alloc((size_t)BB * MM * 4);
  int*           kcnt    = (int*)alloc((size_t)BB * 4);
  float*         Em      = (float*)alloc((size_t)BB * MM * 4);
  float*         bilinP  = (float*)alloc((size_t)BB * 8 * MM * 4);
  float*         result  = (float*)alloc((size_t)BB * 4);

  kA<<<(BB * RR) / 32, 128, 0, stream>>>(region, t0w, t0b, t1w, t1b, h0h1);
  kYT<<<256, 192, 0, stream>>>(h0h1, trw, trb, gt, aff, nmen, nreg,
                               mlist, kcnt, Em, bilinP, expb, expTmax);
  kD<<<BB, 768, 0, stream>>>(expb, expTmax, aff, nreg, mlist, kcnt, Em,
                             bilinP, result);
  kE<<<1, 64, 0, stream>>>(result, nmen, out);
}

// Round 15
// 143.268 us; speedup vs baseline: 2.4256x; 1.0607x over previous
//
#include <hip/hip_runtime.h>

#define NEGV (-100000000.0f)
typedef __attribute__((ext_vector_type(2))) float f32x2;
typedef __attribute__((ext_vector_type(8))) short bf16x8;
typedef __attribute__((ext_vector_type(4))) float f32x4v;

constexpr int BB = 32, MM = 24, RR = 384, DD = 2048;
constexpr int EPITCH = 400;   // eT row pitch (bytes): 100 dwords = 4 mod 32 banks

// pack two f32 -> two bf16 (round half-up)
static __device__ __forceinline__ unsigned pk2bf(float a, float b) {
  unsigned au = __float_as_uint(a) + 0x8000u;
  unsigned bu = __float_as_uint(b) + 0x8000u;
  return (au >> 16) | (bu & 0xffff0000u);
}

// ---------------- Kernel A: fused fp32->bf16 cast + MFMA GEMM (r11 proven) --
__global__ __launch_bounds__(128) void kA(const float* __restrict__ region,
    const float* __restrict__ t0w, const float* __restrict__ t0b,
    const float* __restrict__ t1w, const float* __restrict__ t1b,
    float* __restrict__ h0h1) {
  __shared__ unsigned short Abuf[2][32 * 128];
  __shared__ unsigned short Bbuf[2][32 * 128];
  const int tid = threadIdx.x;
  const int row0 = blockIdx.x * 32;

  const int srow = tid >> 2;
  const int sq = tid & 3;
  const float* aSrc = region + (size_t)(row0 + srow) * DD + sq * 32;
  const float* bSrc = ((srow < 16) ? (t0w + (size_t)srow * DD)
                                   : (t1w + (size_t)(srow - 16) * DD)) + sq * 32;

  float4 ra[8], rb[8];
  auto LOAD = [&](int t) {
    const int d0 = t * 128;
#pragma unroll
    for (int i = 0; i < 8; ++i) ra[i] = *(const float4*)(aSrc + d0 + i * 4);
#pragma unroll
    for (int i = 0; i < 8; ++i) rb[i] = *(const float4*)(bSrc + d0 + i * 4);
  };
  const int wbase = srow * 256 + sq * 64;
  const int wxor = (srow & 7) << 4;
  auto WRITE = [&](int buf) {
    unsigned char* Ab = (unsigned char*)&Abuf[buf][0];
    unsigned char* Bb = (unsigned char*)&Bbuf[buf][0];
#pragma unroll
    for (int i = 0; i < 4; ++i) {
      float4 x = ra[i * 2], y = ra[i * 2 + 1];
      uint4 pk;
      pk.x = pk2bf(x.x, x.y); pk.y = pk2bf(x.z, x.w);
      pk.z = pk2bf(y.x, y.y); pk.w = pk2bf(y.z, y.w);
      *(uint4*)(Ab + ((wbase + i * 16) ^ wxor)) = pk;
      float4 u = rb[i * 2], v = rb[i * 2 + 1];
      uint4 qk;
      qk.x = pk2bf(u.x, u.y); qk.y = pk2bf(u.z, u.w);
      qk.z = pk2bf(v.x, v.y); qk.w = pk2bf(v.z, v.w);
      *(uint4*)(Bb + ((wbase + i * 16) ^ wxor)) = qk;
    }
  };

  const int w = tid >> 6;
  const int lane = tid & 63;
  const int arow = w * 16 + (lane & 15);
  const int bh = lane & 15;
  const int koff = (lane >> 4) * 8;

  f32x4v acc0 = {0.f, 0.f, 0.f, 0.f}, acc1 = {0.f, 0.f, 0.f, 0.f};

  LOAD(0);
  WRITE(0);
  const int axor = (arow & 7) << 4;
  const int bxor = (bh & 7) << 4;
  for (int t = 0; t < 16; ++t) {
    __syncthreads();
    if (t < 15) LOAD(t + 1);
    const unsigned char* Ab = (const unsigned char*)&Abuf[t & 1][0];
    const unsigned char* Bb = (const unsigned char*)&Bbuf[t & 1][0];
#pragma unroll
    for (int kk = 0; kk < 4; ++kk) {
      const int kb = (kk * 32 + koff) * 2;
      bf16x8 av = *(const bf16x8*)(Ab + ((arow * 256 + kb) ^ axor));
      bf16x8 b0 = *(const bf16x8*)(Bb + ((bh * 256 + kb) ^ bxor));
      bf16x8 b1 = *(const bf16x8*)(Bb + (((bh + 16) * 256 + kb) ^ bxor));
      acc0 = __builtin_amdgcn_mfma_f32_16x16x32_bf16(av, b0, acc0, 0, 0, 0);
      acc1 = __builtin_amdgcn_mfma_f32_16x16x32_bf16(av, b1, acc1, 0, 0, 0);
    }
    if (t < 15) WRITE((t + 1) & 1);
  }

  const float bias0 = t0b[bh];
  const float bias1 = t1b[bh];
#pragma unroll
  for (int i = 0; i < 4; ++i) {
    const int rg = row0 + w * 16 + (lane >> 4) * 4 + i;
    h0h1[(size_t)rg * 32 + bh] = acc0[i] + bias0;
    h0h1[(size_t)rg * 32 + 16 + bh] = acc1[i] + bias1;
  }
}

// ---------------- Kernel YT: rsum/Em/mlist prologue + bilinP + fp8 expT -----
__global__ __launch_bounds__(192) void kYT(const float* __restrict__ h0h1,
    const float* __restrict__ trw, const float* __restrict__ trb,
    const float* __restrict__ gt, const float* __restrict__ aff,
    const int* __restrict__ nmen, const int* __restrict__ nreg,
    int* __restrict__ mlist, int* __restrict__ kcnt, float* __restrict__ Em,
    float* __restrict__ bilinP, unsigned char* __restrict__ expb,
    float* __restrict__ expTmax) {
  __shared__ float h1T[16][388];
  __shared__ float h0L[48][16];
  __shared__ float Tl[48][388];
  __shared__ float RP[MM][392];
  __shared__ float part[48][26];
  __shared__ float rsumL[MM], EmL[MM];
  __shared__ int mlistL[MM];
  __shared__ int kcntL;
  const int b = blockIdx.x & 31;
  const int chunk = blockIdx.x >> 5;
  const int r0 = chunk * 48;
  const int tid = threadIdx.x;
  const int lane = tid & 63;
  const int wv = tid >> 6;
  const int nm = nmen[b], nr = nreg[b];

  for (int m = wv; m < MM; m += 3) {
    const size_t bm = (size_t)(b * MM + m);
    float p = 0.f, t1 = 0.f, t2 = 0.f;
#pragma unroll
    for (int i = 0; i < 6; ++i) {
      int s = lane * 6 + i;
      float g = gt[bm * RR + s];
      float a = (g >= 0.5f && s < nr && m < nm) ? g : 0.f;
      float e = aff[bm * RR + s];
      p += a;
      t1 += a * e;
      t2 += (a > 0.f) ? a * __logf(a) : 0.f;
    }
#pragma unroll
    for (int off = 32; off > 0; off >>= 1) {
      p += __shfl_xor(p, off);
      t1 += __shfl_xor(t1, off);
      t2 += __shfl_xor(t2, off);
    }
    if (lane == 0) {
      rsumL[m] = p;
      EmL[m] = (p > 0.f) ? (t1 - t2) / p + __logf(p) : 0.f;
    }
  }
  __syncthreads();
  if (tid == 0) {
    int c = 0;
    for (int m = 0; m < MM; ++m)
      if (rsumL[m] > 0.f) mlistL[c++] = m;
    kcntL = c;
    for (int j = c; j < MM; ++j) mlistL[j] = 0;
  }
  __syncthreads();
  if (chunk == 0 && tid < MM) {
    Em[b * MM + tid] = EmL[tid];
    mlist[b * MM + tid] = mlistL[tid];
    if (tid == 0) kcnt[b] = kcntL;
  }
  const int K = kcntL;

  for (int h = 0; h < 16; ++h)
    for (int s = tid; s < RR; s += 192)
      h1T[h][s] = h0h1[((size_t)b * RR + s) * 32 + 16 + h];
  for (int i = tid; i < 768; i += 192) {
    int row = i >> 4, h = i & 15;
    h0L[row][h] = h0h1[((size_t)b * RR + r0 + row) * 32 + h];
  }
  for (int j = 0; j < MM; ++j) {
    if (j < K) {
      int m = mlistL[j];
      float inv = 1.f / rsumL[m];
      for (int s = tid; s < RR; s += 192) {
        float g = gt[((size_t)(b * MM + m)) * RR + s];
        RP[j][s] = (g >= 0.5f && s < nr) ? g * inv : 0.f;
      }
    } else {
      for (int s = tid; s < RR; s += 192) RP[j][s] = 0.f;
    }
  }
  float w0[16];
#pragma unroll
  for (int h = 0; h < 16; ++h) w0[h] = trw[h];
  const float tb = trb[0];
  __syncthreads();

  const int r = tid >> 2;
  const int jq = tid & 3;
  const int gr = r0 + r;

  for (int s = jq * 96; s < jq * 96 + 96; ++s) {
    float a = tb;
#pragma unroll
    for (int h = 0; h < 16; ++h)
      a += fmaxf(h0L[r][h] + h1T[h][s], 0.f) * w0[h];
    Tl[r][s] = a;
  }
  __syncthreads();

  {
    float rmax = -3.0e38f;
    for (int c = 0; c < 96; c += 4) {
      float4 v = *(const float4*)&Tl[r][jq * 96 + c];
      rmax = fmaxf(rmax, fmaxf(fmaxf(v.x, v.y), fmaxf(v.z, v.w)));
    }
    rmax = fmaxf(rmax, __shfl_xor(rmax, 1));
    rmax = fmaxf(rmax, __shfl_xor(rmax, 2));
    if (jq == 0) expTmax[b * RR + gr] = __expf(rmax);
    unsigned char* obase = expb + ((size_t)b * RR + gr) * RR + jq * 96;
#pragma unroll
    for (int c16 = 0; c16 < 6; ++c16) {
      int w4[4];
#pragma unroll
      for (int ii = 0; ii < 4; ++ii) {
        float4 v = *(const float4*)&Tl[r][jq * 96 + c16 * 16 + ii * 4];
        int pk = __builtin_amdgcn_cvt_pk_fp8_f32(__expf(v.x - rmax),
                                                 __expf(v.y - rmax), 0, false);
        pk = __builtin_amdgcn_cvt_pk_fp8_f32(__expf(v.z - rmax),
                                             __expf(v.w - rmax), pk, true);
        w4[ii] = pk;
      }
      *(int4*)(obase + c16 * 16) = make_int4(w4[0], w4[1], w4[2], w4[3]);
    }
  }

  float acc[6] = {0, 0, 0, 0, 0, 0};
  for (int s0 = 0; s0 < RR; s0 += 4) {
    float4 tv = *(const float4*)&Tl[r][s0];
#pragma unroll
    for (int jj = 0; jj < 6; ++jj) {
      const float4 p0 = *(const float4*)&RP[jq * 6 + jj][s0];
      acc[jj] = fmaf(tv.x, p0.x, acc[jj]);
      acc[jj] = fmaf(tv.y, p0.y, acc[jj]);
      acc[jj] = fmaf(tv.z, p0.z, acc[jj]);
      acc[jj] = fmaf(tv.w, p0.w, acc[jj]);
    }
  }
#pragma unroll
  for (int jj = 0; jj < 6; ++jj) {
    const int jp = jq * 6 + jj;
    const int j = jp + 1;
    part[r][j] = (j < K) ? RP[j][gr] * acc[jj] : 0.f;
  }
  __syncthreads();
  if (tid < MM) {
    const int j = tid;
    float s = 0.f;
    if (j >= 1) {
#pragma unroll 4
      for (int rr2 = 0; rr2 < 48; ++rr2) s += part[rr2][j];
    }
    bilinP[(size_t)(b * 8 + chunk) * MM + j] = s;
  }
}

// ---------------- Kernel D: fp8 MFMA scan, shared quantized B ---------------
// 32 blocks x 768 thr. Per step: phase A = MFMA with B read from shared fp8
// tq[] (one broadcast ds_read_b64/kt); phase B = 96 threads quantize new t.
__global__ __launch_bounds__(768) void kD(
    const unsigned char* __restrict__ expb, const float* __restrict__ expTmax,
    const float* __restrict__ aff, const int* __restrict__ nreg,
    const int* __restrict__ mlist, const int* __restrict__ kcnt,
    const float* __restrict__ Em, const float* __restrict__ bilinP,
    float* __restrict__ result) {
  __shared__ unsigned char eT[RR * EPITCH];    // 153600 B, padded rows
  __shared__ float tf[2][RR];
  __shared__ unsigned int tq[RR / 4];          // fp8 t vector (single buffer)
  __shared__ float wred[2][12];
  __shared__ float fred[12];

  const int b = blockIdx.x;
  const int tid = threadIdx.x;
  const int w = tid >> 6;
  const int lane = tid & 63;
  const int r = lane & 15;
  const int q = lane >> 4;
  const bool act = (r == 0);
  const int nr = nreg[b];

  const int K = kcnt[b];
  if (K == 0) {
    if (tid == 0) result[b] = 0.f;
    return;
  }

  {  // stage fp8 tile -> padded LDS rows (plain copy, coalesced reads)
    const uint4* src = (const uint4*)(expb + (size_t)b * RR * RR);
#pragma unroll
    for (int j = 0; j < 12; ++j) {
      const int i = tid + j * 768;
      uint4 v = src[i];
      const int row = i / 24;
      const int c = (i - row * 24) * 16;
      *(uint4*)(eT + row * EPITCH + c) = v;
    }
  }

  const int abase = (w * 32 + r) * EPITCH + q * 8;

  float sF4[2][4], eraw4[2][4];
  if (act) {
#pragma unroll
    for (int rt = 0; rt < 2; ++rt) {
      const int rowb = w * 32 + rt * 16 + q * 4;
      *(float4*)sF4[rt] = *(const float4*)&expTmax[b * RR + rowb];
      const int m0 = mlist[b * MM];
      *(float4*)eraw4[rt] =
          *(const float4*)(aff + ((size_t)(b * MM + m0)) * RR + rowb);
    }
  }

  float L = 0.f;

  for (int k = 0; k < K; ++k) {
    const int wpar = (k + 1) & 1;

    float nraw4[2][4] = {{0, 0, 0, 0}, {0, 0, 0, 0}};
    if (act && k + 1 < K) {
      const int mn = mlist[b * MM + k + 1];
#pragma unroll
      for (int rt = 0; rt < 2; ++rt) {
        const int rowb = w * 32 + rt * 16 + q * 4;
        *(float4*)nraw4[rt] =
            *(const float4*)(aff + ((size_t)(b * MM + mn)) * RR + rowb);
      }
    }

    float tv[2][4] = {{0, 0, 0, 0}, {0, 0, 0, 0}};
    if (k == 0) {
      if (act) {
#pragma unroll
        for (int rt = 0; rt < 2; ++rt)
#pragma unroll
          for (int i = 0; i < 4; ++i) {
            const int row = w * 32 + rt * 16 + q * 4 + i;
            tv[rt][i] = (row < nr) ? __expf(eraw4[rt][i]) : 0.f;
          }
      }
    } else {
      // phase A: MFMA matvec; B-frag is one broadcast b64 from shared tq
      f32x4v acc0 = {0.f, 0.f, 0.f, 0.f}, acc1 = {0.f, 0.f, 0.f, 0.f};
#pragma unroll
      for (int kt = 0; kt < 12; ++kt) {
        long long bf =
            *(const long long*)((const unsigned char*)tq + kt * 32 + q * 8);
        bf = act ? bf : 0ll;   // only column 0 carries B
        long long a0 = *(const long long*)(eT + abase + kt * 32);
        long long a1 = *(const long long*)(eT + abase + 16 * EPITCH + kt * 32);
        acc0 = __builtin_amdgcn_mfma_f32_16x16x32_fp8_fp8(a0, bf, acc0, 0, 0, 0);
        acc1 = __builtin_amdgcn_mfma_f32_16x16x32_fp8_fp8(a1, bf, acc1, 0, 0, 0);
      }
      if (act) {
#pragma unroll
        for (int i = 0; i < 4; ++i) {
          tv[0][i] = acc0[i] * (__expf(eraw4[0][i]) * sF4[0][i] * 0.00390625f);
          tv[1][i] = acc1[i] * (__expf(eraw4[1][i]) * sF4[1][i] * 0.00390625f);
        }
      }
    }

    // write t state + per-wave max
    float lm = 0.f;
    if (act) {
#pragma unroll
      for (int rt = 0; rt < 2; ++rt) {
        const int rowb = w * 32 + rt * 16 + q * 4;
        *(float4*)&tf[wpar][rowb] =
            make_float4(tv[rt][0], tv[rt][1], tv[rt][2], tv[rt][3]);
        lm = fmaxf(lm, fmaxf(fmaxf(tv[rt][0], tv[rt][1]),
                             fmaxf(tv[rt][2], tv[rt][3])));
      }
#pragma unroll
      for (int rt = 0; rt < 2; ++rt)
#pragma unroll
        for (int i = 0; i < 4; ++i) eraw4[rt][i] = nraw4[rt][i];
    }
    lm = fmaxf(lm, __shfl_xor(lm, 16));
    lm = fmaxf(lm, __shfl_xor(lm, 32));
    if (lane == 0) wred[wpar][w] = lm;
    __syncthreads();                         // barrier 1

    // phase B: quantize new t into tq with scale 256/Z (skip after last step)
    if (k + 1 < K) {
      float4 z0 = *(const float4*)&wred[wpar][0];
      float4 z1 = *(const float4*)&wred[wpar][4];
      float4 z2 = *(const float4*)&wred[wpar][8];
      float zm = fmaxf(fmaxf(fmaxf(z0.x, z0.y), fmaxf(z0.z, z0.w)),
                       fmaxf(fmaxf(fmaxf(z1.x, z1.y), fmaxf(z1.z, z1.w)),
                             fmaxf(fmaxf(z2.x, z2.y), fmaxf(z2.z, z2.w))));
      L += __logf(zm);
      const float bscale = 256.f / zm;
      if (tid < 96) {
        float4 v = *(const float4*)&tf[wpar][tid * 4];
        int pk = __builtin_amdgcn_cvt_pk_fp8_f32(v.x * bscale, v.y * bscale,
                                                 0, false);
        pk = __builtin_amdgcn_cvt_pk_fp8_f32(v.z * bscale, v.w * bscale,
                                             pk, true);
        tq[tid] = (unsigned)pk;
      }
      __syncthreads();                       // barrier 2
    }
  }

  // epilogue
  const int fpar = K & 1;
  float fp = (tid < RR) ? tf[fpar][tid] : 0.f;
#pragma unroll
  for (int off = 32; off > 0; off >>= 1) fp += __shfl_xor(fp, off);
  if (lane == 0) fred[w] = fp;
  __syncthreads();
  if (tid == 0) {
    float fs = 0.f;
#pragma unroll
    for (int i = 0; i < 12; ++i) fs += fred[i];
    const float fwd = L + __logf(fmaxf(fs, 1e-37f));
    float gold = Em[b * MM + mlist[b * MM + 0]];
    for (int j = 1; j < K; ++j) {
      float bil = 0.f;
#pragma unroll
      for (int c = 0; c < 8; ++c) bil += bilinP[(size_t)(b * 8 + c) * MM + j];
      gold += bil + Em[b * MM + mlist[b * MM + j]];
    }
    result[b] = fwd - gold;
  }
}

// ---------------- Kernel E: final deterministic reduction ----------
__global__ void kE(const float* __restrict__ result, const int* __restrict__ nmen,
                   float* __restrict__ out) {
  if (threadIdx.x == 0 && blockIdx.x == 0) {
    float s = 0.f;
    int d = 0;
    for (int b = 0; b < 32; ++b) { s += result[b]; d += nmen[b]; }
    if (d < 1) d = 1;
    out[0] = s / (float)d;
  }
}

extern "C" void kernel_launch(void* const* d_in, const int* in_sizes, int n_in,
                              void* d_out, int out_size, void* d_ws, size_t ws_size,
                              hipStream_t stream) {
  const float* region = (const float*)d_in[0];
  const float* aff    = (const float*)d_in[1];
  const float* gt     = (const float*)d_in[2];
  const int*   nmen   = (const int*)d_in[3];
  const int*   nreg   = (const int*)d_in[4];
  const float* t0w    = (const float*)d_in[5];
  const float* t0b    = (const float*)d_in[6];
  const float* t1w    = (const float*)d_in[7];
  const float* t1b    = (const float*)d_in[8];
  const float* trw    = (const float*)d_in[9];
  const float* trb    = (const float*)d_in[10];
  float* out = (float*)d_out;
  char* ws = (char*)d_ws;

  size_t off = 0;
  auto alloc = [&](size_t bytes) {
    void* p = ws + off;
    off += (bytes + 255) & ~(size_t)255;
    return p;
  };
  float*         h0h1    = (float*)alloc((size_t)BB * RR * 32 * 4);       // 1.57 MB
  unsigned char* expb    = (unsigned char*)alloc((size_t)BB * RR * RR);   // 4.72 MB
  float*         expTmax = (float*)alloc((size_t)BB * RR * 4);
  int*           mlist   = (int*)alloc((size_t)BB * MM * 4);
  int*           kcnt    = (int*)alloc((size_t)BB * 4);
  float*         Em      = (float*)alloc((size_t)BB * MM * 4);
  float*         bilinP  = (float*)alloc((size_t)BB * 8 * MM * 4);
  float*         result  = (float*)alloc((size_t)BB * 4);

  kA<<<(BB * RR) / 32, 128, 0, stream>>>(region, t0w, t0b, t1w, t1b, h0h1);
  kYT<<<256, 192, 0, stream>>>(h0h1, trw, trb, gt, aff, nmen, nreg,
                               mlist, kcnt, Em, bilinP, expb, expTmax);
  kD<<<BB, 768, 0, stream>>>(expb, expTmax, aff, nreg, mlist, kcnt, Em,
                             bilinP, result);
  kE<<<1, 64, 0, stream>>>(result, nmen, out);
}

// Round 16
// 129.944 us; speedup vs baseline: 2.6743x; 1.1025x over previous
//
#include <hip/hip_runtime.h>

#define NEGV (-100000000.0f)
typedef __attribute__((ext_vector_type(2))) float f32x2;
typedef __attribute__((ext_vector_type(8))) short bf16x8;
typedef __attribute__((ext_vector_type(4))) float f32x4v;

constexpr int BB = 32, MM = 24, RR = 384, DD = 2048;
constexpr int EPITCH = 400;   // eT row pitch (bytes): 100 dwords = 4 mod 32 banks

// pack two f32 -> two bf16 (round half-up)
static __device__ __forceinline__ unsigned pk2bf(float a, float b) {
  unsigned au = __float_as_uint(a) + 0x8000u;
  unsigned bu = __float_as_uint(b) + 0x8000u;
  return (au >> 16) | (bu & 0xffff0000u);
}

// ---------------- Kernel A: fused fp32->bf16 cast + MFMA GEMM (r11 proven) --
__global__ __launch_bounds__(128) void kA(const float* __restrict__ region,
    const float* __restrict__ t0w, const float* __restrict__ t0b,
    const float* __restrict__ t1w, const float* __restrict__ t1b,
    float* __restrict__ h0h1) {
  __shared__ unsigned short Abuf[2][32 * 128];
  __shared__ unsigned short Bbuf[2][32 * 128];
  const int tid = threadIdx.x;
  const int row0 = blockIdx.x * 32;

  const int srow = tid >> 2;
  const int sq = tid & 3;
  const float* aSrc = region + (size_t)(row0 + srow) * DD + sq * 32;
  const float* bSrc = ((srow < 16) ? (t0w + (size_t)srow * DD)
                                   : (t1w + (size_t)(srow - 16) * DD)) + sq * 32;

  float4 ra[8], rb[8];
  auto LOAD = [&](int t) {
    const int d0 = t * 128;
#pragma unroll
    for (int i = 0; i < 8; ++i) ra[i] = *(const float4*)(aSrc + d0 + i * 4);
#pragma unroll
    for (int i = 0; i < 8; ++i) rb[i] = *(const float4*)(bSrc + d0 + i * 4);
  };
  const int wbase = srow * 256 + sq * 64;
  const int wxor = (srow & 7) << 4;
  auto WRITE = [&](int buf) {
    unsigned char* Ab = (unsigned char*)&Abuf[buf][0];
    unsigned char* Bb = (unsigned char*)&Bbuf[buf][0];
#pragma unroll
    for (int i = 0; i < 4; ++i) {
      float4 x = ra[i * 2], y = ra[i * 2 + 1];
      uint4 pk;
      pk.x = pk2bf(x.x, x.y); pk.y = pk2bf(x.z, x.w);
      pk.z = pk2bf(y.x, y.y); pk.w = pk2bf(y.z, y.w);
      *(uint4*)(Ab + ((wbase + i * 16) ^ wxor)) = pk;
      float4 u = rb[i * 2], v = rb[i * 2 + 1];
      uint4 qk;
      qk.x = pk2bf(u.x, u.y); qk.y = pk2bf(u.z, u.w);
      qk.z = pk2bf(v.x, v.y); qk.w = pk2bf(v.z, v.w);
      *(uint4*)(Bb + ((wbase + i * 16) ^ wxor)) = qk;
    }
  };

  const int w = tid >> 6;
  const int lane = tid & 63;
  const int arow = w * 16 + (lane & 15);
  const int bh = lane & 15;
  const int koff = (lane >> 4) * 8;

  f32x4v acc0 = {0.f, 0.f, 0.f, 0.f}, acc1 = {0.f, 0.f, 0.f, 0.f};

  LOAD(0);
  WRITE(0);
  const int axor = (arow & 7) << 4;
  const int bxor = (bh & 7) << 4;
  for (int t = 0; t < 16; ++t) {
    __syncthreads();
    if (t < 15) LOAD(t + 1);
    const unsigned char* Ab = (const unsigned char*)&Abuf[t & 1][0];
    const unsigned char* Bb = (const unsigned char*)&Bbuf[t & 1][0];
#pragma unroll
    for (int kk = 0; kk < 4; ++kk) {
      const int kb = (kk * 32 + koff) * 2;
      bf16x8 av = *(const bf16x8*)(Ab + ((arow * 256 + kb) ^ axor));
      bf16x8 b0 = *(const bf16x8*)(Bb + ((bh * 256 + kb) ^ bxor));
      bf16x8 b1 = *(const bf16x8*)(Bb + (((bh + 16) * 256 + kb) ^ bxor));
      acc0 = __builtin_amdgcn_mfma_f32_16x16x32_bf16(av, b0, acc0, 0, 0, 0);
      acc1 = __builtin_amdgcn_mfma_f32_16x16x32_bf16(av, b1, acc1, 0, 0, 0);
    }
    if (t < 15) WRITE((t + 1) & 1);
  }

  const float bias0 = t0b[bh];
  const float bias1 = t1b[bh];
#pragma unroll
  for (int i = 0; i < 4; ++i) {
    const int rg = row0 + w * 16 + (lane >> 4) * 4 + i;
    h0h1[(size_t)rg * 32 + bh] = acc0[i] + bias0;
    h0h1[(size_t)rg * 32 + 16 + bh] = acc1[i] + bias1;
  }
}

// ---------------- Kernel YT: rsum/Em/mlist prologue + bilinP + fp8 expT -----
__global__ __launch_bounds__(192) void kYT(const float* __restrict__ h0h1,
    const float* __restrict__ trw, const float* __restrict__ trb,
    const float* __restrict__ gt, const float* __restrict__ aff,
    const int* __restrict__ nmen, const int* __restrict__ nreg,
    int* __restrict__ mlist, int* __restrict__ kcnt, float* __restrict__ Em,
    float* __restrict__ bilinP, unsigned char* __restrict__ expb,
    float* __restrict__ expTmax) {
  __shared__ float h1T[16][388];
  __shared__ float h0L[48][16];
  __shared__ float Tl[48][388];
  __shared__ float RP[MM][392];
  __shared__ float part[48][26];
  __shared__ float rsumL[MM], EmL[MM];
  __shared__ int mlistL[MM];
  __shared__ int kcntL;
  const int b = blockIdx.x & 31;
  const int chunk = blockIdx.x >> 5;
  const int r0 = chunk * 48;
  const int tid = threadIdx.x;
  const int lane = tid & 63;
  const int wv = tid >> 6;
  const int nm = nmen[b], nr = nreg[b];

  for (int m = wv; m < MM; m += 3) {
    const size_t bm = (size_t)(b * MM + m);
    float p = 0.f, t1 = 0.f, t2 = 0.f;
#pragma unroll
    for (int i = 0; i < 6; ++i) {
      int s = lane * 6 + i;
      float g = gt[bm * RR + s];
      float a = (g >= 0.5f && s < nr && m < nm) ? g : 0.f;
      float e = aff[bm * RR + s];
      p += a;
      t1 += a * e;
      t2 += (a > 0.f) ? a * __logf(a) : 0.f;
    }
#pragma unroll
    for (int off = 32; off > 0; off >>= 1) {
      p += __shfl_xor(p, off);
      t1 += __shfl_xor(t1, off);
      t2 += __shfl_xor(t2, off);
    }
    if (lane == 0) {
      rsumL[m] = p;
      EmL[m] = (p > 0.f) ? (t1 - t2) / p + __logf(p) : 0.f;
    }
  }
  __syncthreads();
  if (tid == 0) {
    int c = 0;
    for (int m = 0; m < MM; ++m)
      if (rsumL[m] > 0.f) mlistL[c++] = m;
    kcntL = c;
    for (int j = c; j < MM; ++j) mlistL[j] = 0;
  }
  __syncthreads();
  if (chunk == 0 && tid < MM) {
    Em[b * MM + tid] = EmL[tid];
    mlist[b * MM + tid] = mlistL[tid];
    if (tid == 0) kcnt[b] = kcntL;
  }
  const int K = kcntL;

  for (int h = 0; h < 16; ++h)
    for (int s = tid; s < RR; s += 192)
      h1T[h][s] = h0h1[((size_t)b * RR + s) * 32 + 16 + h];
  for (int i = tid; i < 768; i += 192) {
    int row = i >> 4, h = i & 15;
    h0L[row][h] = h0h1[((size_t)b * RR + r0 + row) * 32 + h];
  }
  for (int j = 0; j < MM; ++j) {
    if (j < K) {
      int m = mlistL[j];
      float inv = 1.f / rsumL[m];
      for (int s = tid; s < RR; s += 192) {
        float g = gt[((size_t)(b * MM + m)) * RR + s];
        RP[j][s] = (g >= 0.5f && s < nr) ? g * inv : 0.f;
      }
    } else {
      for (int s = tid; s < RR; s += 192) RP[j][s] = 0.f;
    }
  }
  float w0[16];
#pragma unroll
  for (int h = 0; h < 16; ++h) w0[h] = trw[h];
  const float tb = trb[0];
  __syncthreads();

  const int r = tid >> 2;
  const int jq = tid & 3;
  const int gr = r0 + r;

  for (int s = jq * 96; s < jq * 96 + 96; ++s) {
    float a = tb;
#pragma unroll
    for (int h = 0; h < 16; ++h)
      a += fmaxf(h0L[r][h] + h1T[h][s], 0.f) * w0[h];
    Tl[r][s] = a;
  }
  __syncthreads();

  {
    float rmax = -3.0e38f;
    for (int c = 0; c < 96; c += 4) {
      float4 v = *(const float4*)&Tl[r][jq * 96 + c];
      rmax = fmaxf(rmax, fmaxf(fmaxf(v.x, v.y), fmaxf(v.z, v.w)));
    }
    rmax = fmaxf(rmax, __shfl_xor(rmax, 1));
    rmax = fmaxf(rmax, __shfl_xor(rmax, 2));
    if (jq == 0) expTmax[b * RR + gr] = __expf(rmax);
    unsigned char* obase = expb + ((size_t)b * RR + gr) * RR + jq * 96;
#pragma unroll
    for (int c16 = 0; c16 < 6; ++c16) {
      int w4[4];
#pragma unroll
      for (int ii = 0; ii < 4; ++ii) {
        float4 v = *(const float4*)&Tl[r][jq * 96 + c16 * 16 + ii * 4];
        int pk = __builtin_amdgcn_cvt_pk_fp8_f32(__expf(v.x - rmax),
                                                 __expf(v.y - rmax), 0, false);
        pk = __builtin_amdgcn_cvt_pk_fp8_f32(__expf(v.z - rmax),
                                             __expf(v.w - rmax), pk, true);
        w4[ii] = pk;
      }
      *(int4*)(obase + c16 * 16) = make_int4(w4[0], w4[1], w4[2], w4[3]);
    }
  }

  float acc[6] = {0, 0, 0, 0, 0, 0};
  for (int s0 = 0; s0 < RR; s0 += 4) {
    float4 tv = *(const float4*)&Tl[r][s0];
#pragma unroll
    for (int jj = 0; jj < 6; ++jj) {
      const float4 p0 = *(const float4*)&RP[jq * 6 + jj][s0];
      acc[jj] = fmaf(tv.x, p0.x, acc[jj]);
      acc[jj] = fmaf(tv.y, p0.y, acc[jj]);
      acc[jj] = fmaf(tv.z, p0.z, acc[jj]);
      acc[jj] = fmaf(tv.w, p0.w, acc[jj]);
    }
  }
#pragma unroll
  for (int jj = 0; jj < 6; ++jj) {
    const int jp = jq * 6 + jj;
    const int j = jp + 1;
    part[r][j] = (j < K) ? RP[j][gr] * acc[jj] : 0.f;
  }
  __syncthreads();
  if (tid < MM) {
    const int j = tid;
    float s = 0.f;
    if (j >= 1) {
#pragma unroll 4
      for (int rr2 = 0; rr2 < 48; ++rr2) s += part[rr2][j];
    }
    bilinP[(size_t)(b * 8 + chunk) * MM + j] = s;
  }
}

// ---------------- Kernel D: fp8 MFMA scan, A-frags hoisted to registers -----
// 32 blocks x 512 thr (8 waves x 48 rows). eT loaded to VGPRs once; step =
// 12 broadcast tq reads + 36 reg-operand MFMAs + quantize phase.
__global__ __launch_bounds__(512, 1) void kD(
    const unsigned char* __restrict__ expb, const float* __restrict__ expTmax,
    const float* __restrict__ aff, const int* __restrict__ nreg,
    const int* __restrict__ mlist, const int* __restrict__ kcnt,
    const float* __restrict__ Em, const float* __restrict__ bilinP,
    float* __restrict__ result) {
  __shared__ unsigned char eT[RR * EPITCH];    // 153600 B, padded rows
  __shared__ float tf[2][RR];
  __shared__ unsigned int tq[RR / 4];
  __shared__ float wred[2][8];
  __shared__ float fred[8];

  const int b = blockIdx.x;
  const int tid = threadIdx.x;
  const int w = tid >> 6;
  const int lane = tid & 63;
  const int r = lane & 15;
  const int q = lane >> 4;
  const bool act = (r == 0);
  const int nr = nreg[b];

  const int K = kcnt[b];
  if (K == 0) {
    if (tid == 0) result[b] = 0.f;
    return;
  }

  {  // stage fp8 tile -> padded LDS rows
    const uint4* src = (const uint4*)(expb + (size_t)b * RR * RR);
#pragma unroll
    for (int j = 0; j < 18; ++j) {
      const int i = tid + j * 512;
      uint4 v = src[i];
      const int row = i / 24;
      const int c = (i - row * 24) * 16;
      *(uint4*)(eT + row * EPITCH + c) = v;
    }
  }
  __syncthreads();

  // hoist my 36 A-fragments (3 row-tiles x 12 kt) into registers
  long long af0[12], af1[12], af2[12];
  {
    const int base = (w * 48 + r) * EPITCH + q * 8;
#pragma unroll
    for (int kt = 0; kt < 12; ++kt) {
      af0[kt] = *(const long long*)(eT + base + kt * 32);
      af1[kt] = *(const long long*)(eT + base + 16 * EPITCH + kt * 32);
      af2[kt] = *(const long long*)(eT + base + 32 * EPITCH + kt * 32);
    }
  }

  float sF4[3][4], eraw4[3][4];
  if (act) {
#pragma unroll
    for (int rt = 0; rt < 3; ++rt) {
      const int rowb = w * 48 + rt * 16 + q * 4;
      *(float4*)sF4[rt] = *(const float4*)&expTmax[b * RR + rowb];
      const int m0 = mlist[b * MM];
      *(float4*)eraw4[rt] =
          *(const float4*)(aff + ((size_t)(b * MM + m0)) * RR + rowb);
    }
  }

  float L = 0.f;

  for (int k = 0; k < K; ++k) {
    const int wpar = (k + 1) & 1;

    float nraw4[3][4] = {{0, 0, 0, 0}, {0, 0, 0, 0}, {0, 0, 0, 0}};
    if (act && k + 1 < K) {
      const int mn = mlist[b * MM + k + 1];
#pragma unroll
      for (int rt = 0; rt < 3; ++rt) {
        const int rowb = w * 48 + rt * 16 + q * 4;
        *(float4*)nraw4[rt] =
            *(const float4*)(aff + ((size_t)(b * MM + mn)) * RR + rowb);
      }
    }

    float tv[3][4] = {{0, 0, 0, 0}, {0, 0, 0, 0}, {0, 0, 0, 0}};
    if (k == 0) {
      if (act) {
#pragma unroll
        for (int rt = 0; rt < 3; ++rt)
#pragma unroll
          for (int i = 0; i < 4; ++i) {
            const int row = w * 48 + rt * 16 + q * 4 + i;
            tv[rt][i] = (row < nr) ? __expf(eraw4[rt][i]) : 0.f;
          }
      }
    } else {
      f32x4v acc0 = {0.f, 0.f, 0.f, 0.f}, acc1 = {0.f, 0.f, 0.f, 0.f},
             acc2 = {0.f, 0.f, 0.f, 0.f};
#pragma unroll
      for (int kt = 0; kt < 12; ++kt) {
        long long bf =
            *(const long long*)((const unsigned char*)tq + kt * 32 + q * 8);
        bf = act ? bf : 0ll;   // only column 0 carries B
        acc0 = __builtin_amdgcn_mfma_f32_16x16x32_fp8_fp8(af0[kt], bf, acc0, 0, 0, 0);
        acc1 = __builtin_amdgcn_mfma_f32_16x16x32_fp8_fp8(af1[kt], bf, acc1, 0, 0, 0);
        acc2 = __builtin_amdgcn_mfma_f32_16x16x32_fp8_fp8(af2[kt], bf, acc2, 0, 0, 0);
      }
      if (act) {
#pragma unroll
        for (int i = 0; i < 4; ++i) {
          tv[0][i] = acc0[i] * (__expf(eraw4[0][i]) * sF4[0][i] * 0.00390625f);
          tv[1][i] = acc1[i] * (__expf(eraw4[1][i]) * sF4[1][i] * 0.00390625f);
          tv[2][i] = acc2[i] * (__expf(eraw4[2][i]) * sF4[2][i] * 0.00390625f);
        }
      }
    }

    float lm = 0.f;
    if (act) {
#pragma unroll
      for (int rt = 0; rt < 3; ++rt) {
        const int rowb = w * 48 + rt * 16 + q * 4;
        *(float4*)&tf[wpar][rowb] =
            make_float4(tv[rt][0], tv[rt][1], tv[rt][2], tv[rt][3]);
        lm = fmaxf(lm, fmaxf(fmaxf(tv[rt][0], tv[rt][1]),
                             fmaxf(tv[rt][2], tv[rt][3])));
      }
#pragma unroll
      for (int rt = 0; rt < 3; ++rt)
#pragma unroll
        for (int i = 0; i < 4; ++i) eraw4[rt][i] = nraw4[rt][i];
    }
    lm = fmaxf(lm, __shfl_xor(lm, 16));
    lm = fmaxf(lm, __shfl_xor(lm, 32));
    if (lane == 0) wred[wpar][w] = lm;
    __syncthreads();                         // barrier 1

    if (k + 1 < K) {
      float4 z0 = *(const float4*)&wred[wpar][0];
      float4 z1 = *(const float4*)&wred[wpar][4];
      float zm = fmaxf(fmaxf(fmaxf(z0.x, z0.y), fmaxf(z0.z, z0.w)),
                       fmaxf(fmaxf(z1.x, z1.y), fmaxf(z1.z, z1.w)));
      L += __logf(zm);
      const float bscale = 256.f / zm;
      if (tid < 96) {
        float4 v = *(const float4*)&tf[wpar][tid * 4];
        int pk = __builtin_amdgcn_cvt_pk_fp8_f32(v.x * bscale, v.y * bscale,
                                                 0, false);
        pk = __builtin_amdgcn_cvt_pk_fp8_f32(v.z * bscale, v.w * bscale,
                                             pk, true);
        tq[tid] = (unsigned)pk;
      }
      __syncthreads();                       // barrier 2
    }
  }

  // epilogue
  const int fpar = K & 1;
  float fp = (tid < RR) ? tf[fpar][tid] : 0.f;
#pragma unroll
  for (int off = 32; off > 0; off >>= 1) fp += __shfl_xor(fp, off);
  if (lane == 0) fred[w] = fp;
  __syncthreads();
  if (tid == 0) {
    float fs = 0.f;
#pragma unroll
    for (int i = 0; i < 8; ++i) fs += fred[i];
    const float fwd = L + __logf(fmaxf(fs, 1e-37f));
    float gold = Em[b * MM + mlist[b * MM + 0]];
    for (int j = 1; j < K; ++j) {
      float bil = 0.f;
#pragma unroll
      for (int c = 0; c < 8; ++c) bil += bilinP[(size_t)(b * 8 + c) * MM + j];
      gold += bil + Em[b * MM + mlist[b * MM + j]];
    }
    result[b] = fwd - gold;
  }
}

// ---------------- Kernel E: final deterministic reduction ----------
__global__ void kE(const float* __restrict__ result, const int* __restrict__ nmen,
                   float* __restrict__ out) {
  if (threadIdx.x == 0 && blockIdx.x == 0) {
    float s = 0.f;
    int d = 0;
    for (int b = 0; b < 32; ++b) { s += result[b]; d += nmen[b]; }
    if (d < 1) d = 1;
    out[0] = s / (float)d;
  }
}

extern "C" void kernel_launch(void* const* d_in, const int* in_sizes, int n_in,
                              void* d_out, int out_size, void* d_ws, size_t ws_size,
                              hipStream_t stream) {
  const float* region = (const float*)d_in[0];
  const float* aff    = (const float*)d_in[1];
  const float* gt     = (const float*)d_in[2];
  const int*   nmen   = (const int*)d_in[3];
  const int*   nreg   = (const int*)d_in[4];
  const float* t0w    = (const float*)d_in[5];
  const float* t0b    = (const float*)d_in[6];
  const float* t1w    = (const float*)d_in[7];
  const float* t1b    = (const float*)d_in[8];
  const float* trw    = (const float*)d_in[9];
  const float* trb    = (const float*)d_in[10];
  float* out = (float*)d_out;
  char* ws = (char*)d_ws;

  size_t off = 0;
  auto alloc = [&](size_t bytes) {
    void* p = ws + off;
    off += (bytes + 255) & ~(size_t)255;
    return p;
  };
  float*         h0h1    = (float*)alloc((size_t)BB * RR * 32 * 4);       // 1.57 MB
  unsigned char* expb    = (unsigned char*)alloc((size_t)BB * RR * RR);   // 4.72 MB
  float*         expTmax = (float*)alloc((size_t)BB * RR * 4);
  int*           mlist   = (int*)alloc((size_t)BB * MM * 4);
  int*           kcnt    = (int*)alloc((size_t)BB * 4);
  float*         Em      = (float*)alloc((size_t)BB * MM * 4);
  float*         bilinP  = (float*)alloc((size_t)BB * 8 * MM * 4);
  float*         result  = (float*)alloc((size_t)BB * 4);

  kA<<<(BB * RR) / 32, 128, 0, stream>>>(region, t0w, t0b, t1w, t1b, h0h1);
  kYT<<<256, 192, 0, stream>>>(h0h1, trw, trb, gt, aff, nmen, nreg,
                               mlist, kcnt, Em, bilinP, expb, expTmax);
  kD<<<BB, 512, 0, stream>>>(expb, expTmax, aff, nreg, mlist, kcnt, Em,
                             bilinP, result);
  kE<<<1, 64, 0, stream>>>(result, nmen, out);
}

// Round 17
// 113.179 us; speedup vs baseline: 3.0705x; 1.1481x over previous
//
#include <hip/hip_runtime.h>

#define NEGV (-100000000.0f)
typedef __attribute__((ext_vector_type(2))) float f32x2;
typedef __attribute__((ext_vector_type(8))) short bf16x8;
typedef __attribute__((ext_vector_type(4))) float f32x4v;

constexpr int BB = 32, MM = 24, RR = 384, DD = 2048;
constexpr int EPITCH = 400;   // eT row pitch (bytes): 100 dwords = 4 mod 32 banks

// pack two f32 -> two bf16 (round half-up)
static __device__ __forceinline__ unsigned pk2bf(float a, float b) {
  unsigned au = __float_as_uint(a) + 0x8000u;
  unsigned bu = __float_as_uint(b) + 0x8000u;
  return (au >> 16) | (bu & 0xffff0000u);
}

// ---------------- Kernel A: fused fp32->bf16 cast + MFMA GEMM (r11 proven) --
__global__ __launch_bounds__(128) void kA(const float* __restrict__ region,
    const float* __restrict__ t0w, const float* __restrict__ t0b,
    const float* __restrict__ t1w, const float* __restrict__ t1b,
    float* __restrict__ h0h1) {
  __shared__ unsigned short Abuf[2][32 * 128];
  __shared__ unsigned short Bbuf[2][32 * 128];
  const int tid = threadIdx.x;
  const int row0 = blockIdx.x * 32;

  const int srow = tid >> 2;
  const int sq = tid & 3;
  const float* aSrc = region + (size_t)(row0 + srow) * DD + sq * 32;
  const float* bSrc = ((srow < 16) ? (t0w + (size_t)srow * DD)
                                   : (t1w + (size_t)(srow - 16) * DD)) + sq * 32;

  float4 ra[8], rb[8];
  auto LOAD = [&](int t) {
    const int d0 = t * 128;
#pragma unroll
    for (int i = 0; i < 8; ++i) ra[i] = *(const float4*)(aSrc + d0 + i * 4);
#pragma unroll
    for (int i = 0; i < 8; ++i) rb[i] = *(const float4*)(bSrc + d0 + i * 4);
  };
  const int wbase = srow * 256 + sq * 64;
  const int wxor = (srow & 7) << 4;
  auto WRITE = [&](int buf) {
    unsigned char* Ab = (unsigned char*)&Abuf[buf][0];
    unsigned char* Bb = (unsigned char*)&Bbuf[buf][0];
#pragma unroll
    for (int i = 0; i < 4; ++i) {
      float4 x = ra[i * 2], y = ra[i * 2 + 1];
      uint4 pk;
      pk.x = pk2bf(x.x, x.y); pk.y = pk2bf(x.z, x.w);
      pk.z = pk2bf(y.x, y.y); pk.w = pk2bf(y.z, y.w);
      *(uint4*)(Ab + ((wbase + i * 16) ^ wxor)) = pk;
      float4 u = rb[i * 2], v = rb[i * 2 + 1];
      uint4 qk;
      qk.x = pk2bf(u.x, u.y); qk.y = pk2bf(u.z, u.w);
      qk.z = pk2bf(v.x, v.y); qk.w = pk2bf(v.z, v.w);
      *(uint4*)(Bb + ((wbase + i * 16) ^ wxor)) = qk;
    }
  };

  const int w = tid >> 6;
  const int lane = tid & 63;
  const int arow = w * 16 + (lane & 15);
  const int bh = lane & 15;
  const int koff = (lane >> 4) * 8;

  f32x4v acc0 = {0.f, 0.f, 0.f, 0.f}, acc1 = {0.f, 0.f, 0.f, 0.f};

  LOAD(0);
  WRITE(0);
  const int axor = (arow & 7) << 4;
  const int bxor = (bh & 7) << 4;
  for (int t = 0; t < 16; ++t) {
    __syncthreads();
    if (t < 15) LOAD(t + 1);
    const unsigned char* Ab = (const unsigned char*)&Abuf[t & 1][0];
    const unsigned char* Bb = (const unsigned char*)&Bbuf[t & 1][0];
#pragma unroll
    for (int kk = 0; kk < 4; ++kk) {
      const int kb = (kk * 32 + koff) * 2;
      bf16x8 av = *(const bf16x8*)(Ab + ((arow * 256 + kb) ^ axor));
      bf16x8 b0 = *(const bf16x8*)(Bb + ((bh * 256 + kb) ^ bxor));
      bf16x8 b1 = *(const bf16x8*)(Bb + (((bh + 16) * 256 + kb) ^ bxor));
      acc0 = __builtin_amdgcn_mfma_f32_16x16x32_bf16(av, b0, acc0, 0, 0, 0);
      acc1 = __builtin_amdgcn_mfma_f32_16x16x32_bf16(av, b1, acc1, 0, 0, 0);
    }
    if (t < 15) WRITE((t + 1) & 1);
  }

  const float bias0 = t0b[bh];
  const float bias1 = t1b[bh];
#pragma unroll
  for (int i = 0; i < 4; ++i) {
    const int rg = row0 + w * 16 + (lane >> 4) * 4 + i;
    h0h1[(size_t)rg * 32 + bh] = acc0[i] + bias0;
    h0h1[(size_t)rg * 32 + 16 + bh] = acc1[i] + bias1;
  }
}

// ---------------- Kernel YT: 384 thr (6 waves) — latency-hiding remap -------
// grid 256 = (b x 8 chunks of 48 rows). thread = (r 0..47, jq 0..7).
__global__ __launch_bounds__(384) void kYT(const float* __restrict__ h0h1,
    const float* __restrict__ trw, const float* __restrict__ trb,
    const float* __restrict__ gt, const float* __restrict__ aff,
    const int* __restrict__ nmen, const int* __restrict__ nreg,
    int* __restrict__ mlist, int* __restrict__ kcnt, float* __restrict__ Em,
    float* __restrict__ bilinP, unsigned char* __restrict__ expb,
    float* __restrict__ expTmax) {
  __shared__ float h1T[16][388];
  __shared__ float h0L[48][16];
  __shared__ float Tl[48][388];
  __shared__ float RP[MM][392];
  __shared__ float part[48][26];
  __shared__ float rsumL[MM], EmL[MM];
  __shared__ int mlistL[MM];
  __shared__ int kcntL;
  const int b = blockIdx.x & 31;
  const int chunk = blockIdx.x >> 5;
  const int r0 = chunk * 48;
  const int tid = threadIdx.x;
  const int lane = tid & 63;
  const int wv = tid >> 6;
  const int nm = nmen[b], nr = nreg[b];

  // ---- kCM prologue on 6 waves ----
  for (int m = wv; m < MM; m += 6) {
    const size_t bm = (size_t)(b * MM + m);
    float p = 0.f, t1 = 0.f, t2 = 0.f;
#pragma unroll
    for (int i = 0; i < 6; ++i) {
      int s = lane * 6 + i;
      float g = gt[bm * RR + s];
      float a = (g >= 0.5f && s < nr && m < nm) ? g : 0.f;
      float e = aff[bm * RR + s];
      p += a;
      t1 += a * e;
      t2 += (a > 0.f) ? a * __logf(a) : 0.f;
    }
#pragma unroll
    for (int off = 32; off > 0; off >>= 1) {
      p += __shfl_xor(p, off);
      t1 += __shfl_xor(t1, off);
      t2 += __shfl_xor(t2, off);
    }
    if (lane == 0) {
      rsumL[m] = p;
      EmL[m] = (p > 0.f) ? (t1 - t2) / p + __logf(p) : 0.f;
    }
  }
  __syncthreads();
  if (tid == 0) {
    int c = 0;
    for (int m = 0; m < MM; ++m)
      if (rsumL[m] > 0.f) mlistL[c++] = m;
    kcntL = c;
    for (int j = c; j < MM; ++j) mlistL[j] = 0;
  }
  __syncthreads();
  if (chunk == 0 && tid < MM) {
    Em[b * MM + tid] = EmL[tid];
    mlist[b * MM + tid] = mlistL[tid];
    if (tid == 0) kcnt[b] = kcntL;
  }
  const int K = kcntL;

  // ---- staging ----
  for (int h = 0; h < 16; ++h)
    for (int s = tid; s < RR; s += 384)
      h1T[h][s] = h0h1[((size_t)b * RR + s) * 32 + 16 + h];
  for (int i = tid; i < 768; i += 384) {
    int row = i >> 4, h = i & 15;
    h0L[row][h] = h0h1[((size_t)b * RR + r0 + row) * 32 + h];
  }
  for (int j = 0; j < MM; ++j) {
    if (j < K) {
      int m = mlistL[j];
      float inv = 1.f / rsumL[m];
      for (int s = tid; s < RR; s += 384) {
        float g = gt[((size_t)(b * MM + m)) * RR + s];
        RP[j][s] = (g >= 0.5f && s < nr) ? g * inv : 0.f;
      }
    } else {
      for (int s = tid; s < RR; s += 384) RP[j][s] = 0.f;
    }
  }
  float w0[16];
#pragma unroll
  for (int h = 0; h < 16; ++h) w0[h] = trw[h];
  const float tb = trb[0];
  __syncthreads();

  const int r = tid >> 3;        // 0..47
  const int jq = tid & 7;        // 0..7, owns s in [jq*48, jq*48+48)
  const int gr = r0 + r;

  for (int s = jq * 48; s < jq * 48 + 48; ++s) {
    float a = tb;
#pragma unroll
    for (int h = 0; h < 16; ++h)
      a += fmaxf(h0L[r][h] + h1T[h][s], 0.f) * w0[h];
    Tl[r][s] = a;
  }
  __syncthreads();

  // ---- fp8 export: row max over 8 jq lanes ----
  {
    float rmax = -3.0e38f;
    for (int c = 0; c < 48; c += 4) {
      float4 v = *(const float4*)&Tl[r][jq * 48 + c];
      rmax = fmaxf(rmax, fmaxf(fmaxf(v.x, v.y), fmaxf(v.z, v.w)));
    }
    rmax = fmaxf(rmax, __shfl_xor(rmax, 1));
    rmax = fmaxf(rmax, __shfl_xor(rmax, 2));
    rmax = fmaxf(rmax, __shfl_xor(rmax, 4));
    if (jq == 0) expTmax[b * RR + gr] = __expf(rmax);
    unsigned char* obase = expb + ((size_t)b * RR + gr) * RR + jq * 48;
#pragma unroll
    for (int c16 = 0; c16 < 3; ++c16) {
      int w4[4];
#pragma unroll
      for (int ii = 0; ii < 4; ++ii) {
        float4 v = *(const float4*)&Tl[r][jq * 48 + c16 * 16 + ii * 4];
        int pk = __builtin_amdgcn_cvt_pk_fp8_f32(__expf(v.x - rmax),
                                                 __expf(v.y - rmax), 0, false);
        pk = __builtin_amdgcn_cvt_pk_fp8_f32(__expf(v.z - rmax),
                                             __expf(v.w - rmax), pk, true);
        w4[ii] = pk;
      }
      *(int4*)(obase + c16 * 16) = make_int4(w4[0], w4[1], w4[2], w4[3]);
    }
  }

  // ---- bilinear partials: 3 j's per thread ----
  float acc[3] = {0, 0, 0};
  for (int s0 = 0; s0 < RR; s0 += 4) {
    float4 tv = *(const float4*)&Tl[r][s0];
#pragma unroll
    for (int jj = 0; jj < 3; ++jj) {
      const float4 p0 = *(const float4*)&RP[jq * 3 + jj][s0];
      acc[jj] = fmaf(tv.x, p0.x, acc[jj]);
      acc[jj] = fmaf(tv.y, p0.y, acc[jj]);
      acc[jj] = fmaf(tv.z, p0.z, acc[jj]);
      acc[jj] = fmaf(tv.w, p0.w, acc[jj]);
    }
  }
#pragma unroll
  for (int jj = 0; jj < 3; ++jj) {
    const int jp = jq * 3 + jj;      // acc[jj] = (T rp_jp)[gr]
    const int j = jp + 1;            // contributes to bilin_j
    part[r][j] = (j < K) ? RP[j][gr] * acc[jj] : 0.f;
  }
  __syncthreads();
  if (tid < MM) {
    const int j = tid;
    float s = 0.f;
    if (j >= 1) {
#pragma unroll 4
      for (int rr2 = 0; rr2 < 48; ++rr2) s += part[rr2][j];
    }
    bilinP[(size_t)(b * 8 + chunk) * MM + j] = s;
  }
}

// ---------------- Kernel D: fp8 MFMA scan, A-frags hoisted to registers -----
__global__ __launch_bounds__(512, 1) void kD(
    const unsigned char* __restrict__ expb, const float* __restrict__ expTmax,
    const float* __restrict__ aff, const int* __restrict__ nreg,
    const int* __restrict__ mlist, const int* __restrict__ kcnt,
    const float* __restrict__ Em, const float* __restrict__ bilinP,
    float* __restrict__ result) {
  __shared__ unsigned char eT[RR * EPITCH];    // 153600 B, padded rows
  __shared__ float tf[2][RR];
  __shared__ unsigned int tq[RR / 4];
  __shared__ float wred[2][8];
  __shared__ float fred[8];

  const int b = blockIdx.x;
  const int tid = threadIdx.x;
  const int w = tid >> 6;
  const int lane = tid & 63;
  const int r = lane & 15;
  const int q = lane >> 4;
  const bool act = (r == 0);
  const int nr = nreg[b];

  const int K = kcnt[b];
  if (K == 0) {
    if (tid == 0) result[b] = 0.f;
    return;
  }

  {  // stage fp8 tile -> padded LDS rows
    const uint4* src = (const uint4*)(expb + (size_t)b * RR * RR);
#pragma unroll
    for (int j = 0; j < 18; ++j) {
      const int i = tid + j * 512;
      uint4 v = src[i];
      const int row = i / 24;
      const int c = (i - row * 24) * 16;
      *(uint4*)(eT + row * EPITCH + c) = v;
    }
  }
  __syncthreads();

  // hoist my 36 A-fragments (3 row-tiles x 12 kt) into registers
  long long af0[12], af1[12], af2[12];
  {
    const int base = (w * 48 + r) * EPITCH + q * 8;
#pragma unroll
    for (int kt = 0; kt < 12; ++kt) {
      af0[kt] = *(const long long*)(eT + base + kt * 32);
      af1[kt] = *(const long long*)(eT + base + 16 * EPITCH + kt * 32);
      af2[kt] = *(const long long*)(eT + base + 32 * EPITCH + kt * 32);
    }
  }

  float sF4[3][4], eraw4[3][4];
  if (act) {
#pragma unroll
    for (int rt = 0; rt < 3; ++rt) {
      const int rowb = w * 48 + rt * 16 + q * 4;
      *(float4*)sF4[rt] = *(const float4*)&expTmax[b * RR + rowb];
      const int m0 = mlist[b * MM];
      *(float4*)eraw4[rt] =
          *(const float4*)(aff + ((size_t)(b * MM + m0)) * RR + rowb);
    }
  }

  float L = 0.f;

  for (int k = 0; k < K; ++k) {
    const int wpar = (k + 1) & 1;

    float nraw4[3][4] = {{0, 0, 0, 0}, {0, 0, 0, 0}, {0, 0, 0, 0}};
    if (act && k + 1 < K) {
      const int mn = mlist[b * MM + k + 1];
#pragma unroll
      for (int rt = 0; rt < 3; ++rt) {
        const int rowb = w * 48 + rt * 16 + q * 4;
        *(float4*)nraw4[rt] =
            *(const float4*)(aff + ((size_t)(b * MM + mn)) * RR + rowb);
      }
    }

    float tv[3][4] = {{0, 0, 0, 0}, {0, 0, 0, 0}, {0, 0, 0, 0}};
    if (k == 0) {
      if (act) {
#pragma unroll
        for (int rt = 0; rt < 3; ++rt)
#pragma unroll
          for (int i = 0; i < 4; ++i) {
            const int row = w * 48 + rt * 16 + q * 4 + i;
            tv[rt][i] = (row < nr) ? __expf(eraw4[rt][i]) : 0.f;
          }
      }
    } else {
      f32x4v acc0 = {0.f, 0.f, 0.f, 0.f}, acc1 = {0.f, 0.f, 0.f, 0.f},
             acc2 = {0.f, 0.f, 0.f, 0.f};
#pragma unroll
      for (int kt = 0; kt < 12; ++kt) {
        long long bf =
            *(const long long*)((const unsigned char*)tq + kt * 32 + q * 8);
        bf = act ? bf : 0ll;   // only column 0 carries B
        acc0 = __builtin_amdgcn_mfma_f32_16x16x32_fp8_fp8(af0[kt], bf, acc0, 0, 0, 0);
        acc1 = __builtin_amdgcn_mfma_f32_16x16x32_fp8_fp8(af1[kt], bf, acc1, 0, 0, 0);
        acc2 = __builtin_amdgcn_mfma_f32_16x16x32_fp8_fp8(af2[kt], bf, acc2, 0, 0, 0);
      }
      if (act) {
#pragma unroll
        for (int i = 0; i < 4; ++i) {
          tv[0][i] = acc0[i] * (__expf(eraw4[0][i]) * sF4[0][i] * 0.00390625f);
          tv[1][i] = acc1[i] * (__expf(eraw4[1][i]) * sF4[1][i] * 0.00390625f);
          tv[2][i] = acc2[i] * (__expf(eraw4[2][i]) * sF4[2][i] * 0.00390625f);
        }
      }
    }

    float lm = 0.f;
    if (act) {
#pragma unroll
      for (int rt = 0; rt < 3; ++rt) {
        const int rowb = w * 48 + rt * 16 + q * 4;
        *(float4*)&tf[wpar][rowb] =
            make_float4(tv[rt][0], tv[rt][1], tv[rt][2], tv[rt][3]);
        lm = fmaxf(lm, fmaxf(fmaxf(tv[rt][0], tv[rt][1]),
                             fmaxf(tv[rt][2], tv[rt][3])));
      }
#pragma unroll
      for (int rt = 0; rt < 3; ++rt)
#pragma unroll
        for (int i = 0; i < 4; ++i) eraw4[rt][i] = nraw4[rt][i];
    }
    lm = fmaxf(lm, __shfl_xor(lm, 16));
    lm = fmaxf(lm, __shfl_xor(lm, 32));
    if (lane == 0) wred[wpar][w] = lm;
    __syncthreads();                         // barrier 1

    if (k + 1 < K) {
      float4 z0 = *(const float4*)&wred[wpar][0];
      float4 z1 = *(const float4*)&wred[wpar][4];
      float zm = fmaxf(fmaxf(fmaxf(z0.x, z0.y), fmaxf(z0.z, z0.w)),
                       fmaxf(fmaxf(z1.x, z1.y), fmaxf(z1.z, z1.w)));
      L += __logf(zm);
      const float bscale = 256.f / zm;
      if (tid < 96) {
        float4 v = *(const float4*)&tf[wpar][tid * 4];
        int pk = __builtin_amdgcn_cvt_pk_fp8_f32(v.x * bscale, v.y * bscale,
                                                 0, false);
        pk = __builtin_amdgcn_cvt_pk_fp8_f32(v.z * bscale, v.w * bscale,
                                             pk, true);
        tq[tid] = (unsigned)pk;
      }
      __syncthreads();                       // barrier 2
    }
  }

  // epilogue
  const int fpar = K & 1;
  float fp = (tid < RR) ? tf[fpar][tid] : 0.f;
#pragma unroll
  for (int off = 32; off > 0; off >>= 1) fp += __shfl_xor(fp, off);
  if (lane == 0) fred[w] = fp;
  __syncthreads();
  if (tid == 0) {
    float fs = 0.f;
#pragma unroll
    for (int i = 0; i < 8; ++i) fs += fred[i];
    const float fwd = L + __logf(fmaxf(fs, 1e-37f));
    float gold = Em[b * MM + mlist[b * MM + 0]];
    for (int j = 1; j < K; ++j) {
      float bil = 0.f;
#pragma unroll
      for (int c = 0; c < 8; ++c) bil += bilinP[(size_t)(b * 8 + c) * MM + j];
      gold += bil + Em[b * MM + mlist[b * MM + j]];
    }
    result[b] = fwd - gold;
  }
}

// ---------------- Kernel E: final deterministic reduction ----------
__global__ void kE(const float* __restrict__ result, const int* __restrict__ nmen,
                   float* __restrict__ out) {
  if (threadIdx.x == 0 && blockIdx.x == 0) {
    float s = 0.f;
    int d = 0;
    for (int b = 0; b < 32; ++b) { s += result[b]; d += nmen[b]; }
    if (d < 1) d = 1;
    out[0] = s / (float)d;
  }
}

extern "C" void kernel_launch(void* const* d_in, const int* in_sizes, int n_in,
                              void* d_out, int out_size, void* d_ws, size_t ws_size,
                              hipStream_t stream) {
  const float* region = (const float*)d_in[0];
  const float* aff    = (const float*)d_in[1];
  const float* gt     = (const float*)d_in[2];
  const int*   nmen   = (const int*)d_in[3];
  const int*   nreg   = (const int*)d_in[4];
  const float* t0w    = (const float*)d_in[5];
  const float* t0b    = (const float*)d_in[6];
  const float* t1w    = (const float*)d_in[7];
  const float* t1b    = (const float*)d_in[8];
  const float* trw    = (const float*)d_in[9];
  const float* trb    = (const float*)d_in[10];
  float* out = (float*)d_out;
  char* ws = (char*)d_ws;

  size_t off = 0;
  auto alloc = [&](size_t bytes) {
    void* p = ws + off;
    off += (bytes + 255) & ~(size_t)255;
    return p;
  };
  float*         h0h1    = (float*)alloc((size_t)BB * RR * 32 * 4);       // 1.57 MB
  unsigned char* expb    = (unsigned char*)alloc((size_t)BB * RR * RR);   // 4.72 MB
  float*         expTmax = (float*)alloc((size_t)BB * RR * 4);
  int*           mlist   = (int*)alloc((size_t)BB * MM * 4);
  int*           kcnt    = (int*)alloc((size_t)BB * 4);
  float*         Em      = (float*)alloc((size_t)BB * MM * 4);
  float*         bilinP  = (float*)alloc((size_t)BB * 8 * MM * 4);
  float*         result  = (float*)alloc((size_t)BB * 4);

  kA<<<(BB * RR) / 32, 128, 0, stream>>>(region, t0w, t0b, t1w, t1b, h0h1);
  kYT<<<256, 384, 0, stream>>>(h0h1, trw, trb, gt, aff, nmen, nreg,
                               mlist, kcnt, Em, bilinP, expb, expTmax);
  kD<<<BB, 512, 0, stream>>>(expb, expTmax, aff, nreg, mlist, kcnt, Em,
                             bilinP, result);
  kE<<<1, 64, 0, stream>>>(result, nmen, out);
}

// Round 18
// 105.294 us; speedup vs baseline: 3.3004x; 1.0749x over previous
//
#include <hip/hip_runtime.h>

#define NEGV (-100000000.0f)
typedef __attribute__((ext_vector_type(2))) float f32x2;
typedef __attribute__((ext_vector_type(8))) short bf16x8;
typedef __attribute__((ext_vector_type(4))) float f32x4v;

constexpr int BB = 32, MM = 24, RR = 384, DD = 2048;
constexpr int EPITCH = 400;   // eT row pitch (bytes): 100 dwords = 4 mod 32 banks

// pack two f32 -> two bf16 (round half-up)
static __device__ __forceinline__ unsigned pk2bf(float a, float b) {
  unsigned au = __float_as_uint(a) + 0x8000u;
  unsigned bu = __float_as_uint(b) + 0x8000u;
  return (au >> 16) | (bu & 0xffff0000u);
}

// ---------------- Kernel A: cast+MFMA GEMM, 256 thr (4 waves) ----------------
// 384 blocks; 32 rows x 32 h per block; K-tiles of 128, double-buffered LDS.
// Staging: (srow=tid>>3, sq=tid&7) loads 4 float4/array. MFMA: wave w owns
// row-tile (w&1), h-tile (w>>1) -> 1 acc, 4 MFMA per K-tile.
__global__ __launch_bounds__(256) void kA(const float* __restrict__ region,
    const float* __restrict__ t0w, const float* __restrict__ t0b,
    const float* __restrict__ t1w, const float* __restrict__ t1b,
    float* __restrict__ h0h1) {
  __shared__ unsigned short Abuf[2][32 * 128];
  __shared__ unsigned short Bbuf[2][32 * 128];
  const int tid = threadIdx.x;
  const int row0 = blockIdx.x * 32;

  const int srow = tid >> 3;       // 0..31
  const int sq = tid & 7;          // eighth of the 128-k tile (16 floats)
  const float* aSrc = region + (size_t)(row0 + srow) * DD + sq * 16;
  const float* bSrc = ((srow < 16) ? (t0w + (size_t)srow * DD)
                                   : (t1w + (size_t)(srow - 16) * DD)) + sq * 16;

  float4 ra[4], rb[4];
  auto LOAD = [&](int t) {
    const int d0 = t * 128;
#pragma unroll
    for (int i = 0; i < 4; ++i) ra[i] = *(const float4*)(aSrc + d0 + i * 4);
#pragma unroll
    for (int i = 0; i < 4; ++i) rb[i] = *(const float4*)(bSrc + d0 + i * 4);
  };
  const int wbase = srow * 256 + sq * 32;      // byte offset in a buffer
  const int wxor = (srow & 7) << 4;
  auto WRITE = [&](int buf) {
    unsigned char* Ab = (unsigned char*)&Abuf[buf][0];
    unsigned char* Bb = (unsigned char*)&Bbuf[buf][0];
#pragma unroll
    for (int i = 0; i < 2; ++i) {
      float4 x = ra[i * 2], y = ra[i * 2 + 1];
      uint4 pk;
      pk.x = pk2bf(x.x, x.y); pk.y = pk2bf(x.z, x.w);
      pk.z = pk2bf(y.x, y.y); pk.w = pk2bf(y.z, y.w);
      *(uint4*)(Ab + ((wbase + i * 16) ^ wxor)) = pk;
      float4 u = rb[i * 2], v = rb[i * 2 + 1];
      uint4 qk;
      qk.x = pk2bf(u.x, u.y); qk.y = pk2bf(u.z, u.w);
      qk.z = pk2bf(v.x, v.y); qk.w = pk2bf(v.z, v.w);
      *(uint4*)(Bb + ((wbase + i * 16) ^ wxor)) = qk;
    }
  };

  const int w = tid >> 6;                 // wave 0..3
  const int rt = w & 1;                   // row-tile
  const int ht = w >> 1;                  // h-tile
  const int lane = tid & 63;
  const int arow = rt * 16 + (lane & 15);
  const int bh = lane & 15;
  const int brow = ht * 16 + bh;
  const int koff = (lane >> 4) * 8;

  f32x4v acc = {0.f, 0.f, 0.f, 0.f};

  LOAD(0);
  WRITE(0);
  const int axor = (arow & 7) << 4;
  const int bxor = (brow & 7) << 4;
  for (int t = 0; t < 16; ++t) {
    __syncthreads();
    if (t < 15) LOAD(t + 1);
    const unsigned char* Ab = (const unsigned char*)&Abuf[t & 1][0];
    const unsigned char* Bb = (const unsigned char*)&Bbuf[t & 1][0];
#pragma unroll
    for (int kk = 0; kk < 4; ++kk) {
      const int kb = (kk * 32 + koff) * 2;
      bf16x8 av = *(const bf16x8*)(Ab + ((arow * 256 + kb) ^ axor));
      bf16x8 bv = *(const bf16x8*)(Bb + ((brow * 256 + kb) ^ bxor));
      acc = __builtin_amdgcn_mfma_f32_16x16x32_bf16(av, bv, acc, 0, 0, 0);
    }
    if (t < 15) WRITE((t + 1) & 1);
  }

  // epilogue: C/D layout col=lane&15, row=(lane>>4)*4+reg
  const float bias = (ht == 0) ? t0b[bh] : t1b[bh];
#pragma unroll
  for (int i = 0; i < 4; ++i) {
    const int rg = row0 + rt * 16 + (lane >> 4) * 4 + i;
    h0h1[(size_t)rg * 32 + ht * 16 + bh] = acc[i] + bias;
  }
}

// ---------------- Kernel YT: 384 thr (6 waves) — latency-hiding remap -------
// grid 256 = (b x 8 chunks of 48 rows). thread = (r 0..47, jq 0..7).
__global__ __launch_bounds__(384) void kYT(const float* __restrict__ h0h1,
    const float* __restrict__ trw, const float* __restrict__ trb,
    const float* __restrict__ gt, const float* __restrict__ aff,
    const int* __restrict__ nmen, const int* __restrict__ nreg,
    int* __restrict__ mlist, int* __restrict__ kcnt, float* __restrict__ Em,
    float* __restrict__ bilinP, unsigned char* __restrict__ expb,
    float* __restrict__ expTmax) {
  __shared__ float h1T[16][388];
  __shared__ float h0L[48][16];
  __shared__ float Tl[48][388];
  __shared__ float RP[MM][392];
  __shared__ float part[48][26];
  __shared__ float rsumL[MM], EmL[MM];
  __shared__ int mlistL[MM];
  __shared__ int kcntL;
  const int b = blockIdx.x & 31;
  const int chunk = blockIdx.x >> 5;
  const int r0 = chunk * 48;
  const int tid = threadIdx.x;
  const int lane = tid & 63;
  const int wv = tid >> 6;
  const int nm = nmen[b], nr = nreg[b];

  // ---- kCM prologue on 6 waves ----
  for (int m = wv; m < MM; m += 6) {
    const size_t bm = (size_t)(b * MM + m);
    float p = 0.f, t1 = 0.f, t2 = 0.f;
#pragma unroll
    for (int i = 0; i < 6; ++i) {
      int s = lane * 6 + i;
      float g = gt[bm * RR + s];
      float a = (g >= 0.5f && s < nr && m < nm) ? g : 0.f;
      float e = aff[bm * RR + s];
      p += a;
      t1 += a * e;
      t2 += (a > 0.f) ? a * __logf(a) : 0.f;
    }
#pragma unroll
    for (int off = 32; off > 0; off >>= 1) {
      p += __shfl_xor(p, off);
      t1 += __shfl_xor(t1, off);
      t2 += __shfl_xor(t2, off);
    }
    if (lane == 0) {
      rsumL[m] = p;
      EmL[m] = (p > 0.f) ? (t1 - t2) / p + __logf(p) : 0.f;
    }
  }
  __syncthreads();
  if (tid == 0) {
    int c = 0;
    for (int m = 0; m < MM; ++m)
      if (rsumL[m] > 0.f) mlistL[c++] = m;
    kcntL = c;
    for (int j = c; j < MM; ++j) mlistL[j] = 0;
  }
  __syncthreads();
  if (chunk == 0 && tid < MM) {
    Em[b * MM + tid] = EmL[tid];
    mlist[b * MM + tid] = mlistL[tid];
    if (tid == 0) kcnt[b] = kcntL;
  }
  const int K = kcntL;

  // ---- staging ----
  for (int h = 0; h < 16; ++h)
    for (int s = tid; s < RR; s += 384)
      h1T[h][s] = h0h1[((size_t)b * RR + s) * 32 + 16 + h];
  for (int i = tid; i < 768; i += 384) {
    int row = i >> 4, h = i & 15;
    h0L[row][h] = h0h1[((size_t)b * RR + r0 + row) * 32 + h];
  }
  for (int j = 0; j < MM; ++j) {
    if (j < K) {
      int m = mlistL[j];
      float inv = 1.f / rsumL[m];
      for (int s = tid; s < RR; s += 384) {
        float g = gt[((size_t)(b * MM + m)) * RR + s];
        RP[j][s] = (g >= 0.5f && s < nr) ? g * inv : 0.f;
      }
    } else {
      for (int s = tid; s < RR; s += 384) RP[j][s] = 0.f;
    }
  }
  float w0[16];
#pragma unroll
  for (int h = 0; h < 16; ++h) w0[h] = trw[h];
  const float tb = trb[0];
  __syncthreads();

  const int r = tid >> 3;        // 0..47
  const int jq = tid & 7;        // 0..7, owns s in [jq*48, jq*48+48)
  const int gr = r0 + r;

  for (int s = jq * 48; s < jq * 48 + 48; ++s) {
    float a = tb;
#pragma unroll
    for (int h = 0; h < 16; ++h)
      a += fmaxf(h0L[r][h] + h1T[h][s], 0.f) * w0[h];
    Tl[r][s] = a;
  }
  __syncthreads();

  // ---- fp8 export: row max over 8 jq lanes ----
  {
    float rmax = -3.0e38f;
    for (int c = 0; c < 48; c += 4) {
      float4 v = *(const float4*)&Tl[r][jq * 48 + c];
      rmax = fmaxf(rmax, fmaxf(fmaxf(v.x, v.y), fmaxf(v.z, v.w)));
    }
    rmax = fmaxf(rmax, __shfl_xor(rmax, 1));
    rmax = fmaxf(rmax, __shfl_xor(rmax, 2));
    rmax = fmaxf(rmax, __shfl_xor(rmax, 4));
    if (jq == 0) expTmax[b * RR + gr] = __expf(rmax);
    unsigned char* obase = expb + ((size_t)b * RR + gr) * RR + jq * 48;
#pragma unroll
    for (int c16 = 0; c16 < 3; ++c16) {
      int w4[4];
#pragma unroll
      for (int ii = 0; ii < 4; ++ii) {
        float4 v = *(const float4*)&Tl[r][jq * 48 + c16 * 16 + ii * 4];
        int pk = __builtin_amdgcn_cvt_pk_fp8_f32(__expf(v.x - rmax),
                                                 __expf(v.y - rmax), 0, false);
        pk = __builtin_amdgcn_cvt_pk_fp8_f32(__expf(v.z - rmax),
                                             __expf(v.w - rmax), pk, true);
        w4[ii] = pk;
      }
      *(int4*)(obase + c16 * 16) = make_int4(w4[0], w4[1], w4[2], w4[3]);
    }
  }

  // ---- bilinear partials: 3 j's per thread ----
  float acc[3] = {0, 0, 0};
  for (int s0 = 0; s0 < RR; s0 += 4) {
    float4 tv = *(const float4*)&Tl[r][s0];
#pragma unroll
    for (int jj = 0; jj < 3; ++jj) {
      const float4 p0 = *(const float4*)&RP[jq * 3 + jj][s0];
      acc[jj] = fmaf(tv.x, p0.x, acc[jj]);
      acc[jj] = fmaf(tv.y, p0.y, acc[jj]);
      acc[jj] = fmaf(tv.z, p0.z, acc[jj]);
      acc[jj] = fmaf(tv.w, p0.w, acc[jj]);
    }
  }
#pragma unroll
  for (int jj = 0; jj < 3; ++jj) {
    const int jp = jq * 3 + jj;
    const int j = jp + 1;
    part[r][j] = (j < K) ? RP[j][gr] * acc[jj] : 0.f;
  }
  __syncthreads();
  if (tid < MM) {
    const int j = tid;
    float s = 0.f;
    if (j >= 1) {
#pragma unroll 4
      for (int rr2 = 0; rr2 < 48; ++rr2) s += part[rr2][j];
    }
    bilinP[(size_t)(b * 8 + chunk) * MM + j] = s;
  }
}

// ---------------- Kernel D: fp8 MFMA scan, A-frags hoisted to registers -----
__global__ __launch_bounds__(512, 1) void kD(
    const unsigned char* __restrict__ expb, const float* __restrict__ expTmax,
    const float* __restrict__ aff, const int* __restrict__ nreg,
    const int* __restrict__ mlist, const int* __restrict__ kcnt,
    const float* __restrict__ Em, const float* __restrict__ bilinP,
    float* __restrict__ result) {
  __shared__ unsigned char eT[RR * EPITCH];    // 153600 B, padded rows
  __shared__ float tf[2][RR];
  __shared__ unsigned int tq[RR / 4];
  __shared__ float wred[2][8];
  __shared__ float fred[8];

  const int b = blockIdx.x;
  const int tid = threadIdx.x;
  const int w = tid >> 6;
  const int lane = tid & 63;
  const int r = lane & 15;
  const int q = lane >> 4;
  const bool act = (r == 0);
  const int nr = nreg[b];

  const int K = kcnt[b];
  if (K == 0) {
    if (tid == 0) result[b] = 0.f;
    return;
  }

  {  // stage fp8 tile -> padded LDS rows
    const uint4* src = (const uint4*)(expb + (size_t)b * RR * RR);
#pragma unroll
    for (int j = 0; j < 18; ++j) {
      const int i = tid + j * 512;
      uint4 v = src[i];
      const int row = i / 24;
      const int c = (i - row * 24) * 16;
      *(uint4*)(eT + row * EPITCH + c) = v;
    }
  }
  __syncthreads();

  // hoist my 36 A-fragments (3 row-tiles x 12 kt) into registers
  long long af0[12], af1[12], af2[12];
  {
    const int base = (w * 48 + r) * EPITCH + q * 8;
#pragma unroll
    for (int kt = 0; kt < 12; ++kt) {
      af0[kt] = *(const long long*)(eT + base + kt * 32);
      af1[kt] = *(const long long*)(eT + base + 16 * EPITCH + kt * 32);
      af2[kt] = *(const long long*)(eT + base + 32 * EPITCH + kt * 32);
    }
  }

  float sF4[3][4], eraw4[3][4];
  if (act) {
#pragma unroll
    for (int rt = 0; rt < 3; ++rt) {
      const int rowb = w * 48 + rt * 16 + q * 4;
      *(float4*)sF4[rt] = *(const float4*)&expTmax[b * RR + rowb];
      const int m0 = mlist[b * MM];
      *(float4*)eraw4[rt] =
          *(const float4*)(aff + ((size_t)(b * MM + m0)) * RR + rowb);
    }
  }

  float L = 0.f;

  for (int k = 0; k < K; ++k) {
    const int wpar = (k + 1) & 1;

    float nraw4[3][4] = {{0, 0, 0, 0}, {0, 0, 0, 0}, {0, 0, 0, 0}};
    if (act && k + 1 < K) {
      const int mn = mlist[b * MM + k + 1];
#pragma unroll
      for (int rt = 0; rt < 3; ++rt) {
        const int rowb = w * 48 + rt * 16 + q * 4;
        *(float4*)nraw4[rt] =
            *(const float4*)(aff + ((size_t)(b * MM + mn)) * RR + rowb);
      }
    }

    float tv[3][4] = {{0, 0, 0, 0}, {0, 0, 0, 0}, {0, 0, 0, 0}};
    if (k == 0) {
      if (act) {
#pragma unroll
        for (int rt = 0; rt < 3; ++rt)
#pragma unroll
          for (int i = 0; i < 4; ++i) {
            const int row = w * 48 + rt * 16 + q * 4 + i;
            tv[rt][i] = (row < nr) ? __expf(eraw4[rt][i]) : 0.f;
          }
      }
    } else {
      f32x4v acc0 = {0.f, 0.f, 0.f, 0.f}, acc1 = {0.f, 0.f, 0.f, 0.f},
             acc2 = {0.f, 0.f, 0.f, 0.f};
#pragma unroll
      for (int kt = 0; kt < 12; ++kt) {
        long long bf =
            *(const long long*)((const unsigned char*)tq + kt * 32 + q * 8);
        bf = act ? bf : 0ll;   // only column 0 carries B
        acc0 = __builtin_amdgcn_mfma_f32_16x16x32_fp8_fp8(af0[kt], bf, acc0, 0, 0, 0);
        acc1 = __builtin_amdgcn_mfma_f32_16x16x32_fp8_fp8(af1[kt], bf, acc1, 0, 0, 0);
        acc2 = __builtin_amdgcn_mfma_f32_16x16x32_fp8_fp8(af2[kt], bf, acc2, 0, 0, 0);
      }
      if (act) {
#pragma unroll
        for (int i = 0; i < 4; ++i) {
          tv[0][i] = acc0[i] * (__expf(eraw4[0][i]) * sF4[0][i] * 0.00390625f);
          tv[1][i] = acc1[i] * (__expf(eraw4[1][i]) * sF4[1][i] * 0.00390625f);
          tv[2][i] = acc2[i] * (__expf(eraw4[2][i]) * sF4[2][i] * 0.00390625f);
        }
      }
    }

    float lm = 0.f;
    if (act) {
#pragma unroll
      for (int rt = 0; rt < 3; ++rt) {
        const int rowb = w * 48 + rt * 16 + q * 4;
        *(float4*)&tf[wpar][rowb] =
            make_float4(tv[rt][0], tv[rt][1], tv[rt][2], tv[rt][3]);
        lm = fmaxf(lm, fmaxf(fmaxf(tv[rt][0], tv[rt][1]),
                             fmaxf(tv[rt][2], tv[rt][3])));
      }
#pragma unroll
      for (int rt = 0; rt < 3; ++rt)
#pragma unroll
        for (int i = 0; i < 4; ++i) eraw4[rt][i] = nraw4[rt][i];
    }
    lm = fmaxf(lm, __shfl_xor(lm, 16));
    lm = fmaxf(lm, __shfl_xor(lm, 32));
    if (lane == 0) wred[wpar][w] = lm;
    __syncthreads();                         // barrier 1

    if (k + 1 < K) {
      float4 z0 = *(const float4*)&wred[wpar][0];
      float4 z1 = *(const float4*)&wred[wpar][4];
      float zm = fmaxf(fmaxf(fmaxf(z0.x, z0.y), fmaxf(z0.z, z0.w)),
                       fmaxf(fmaxf(z1.x, z1.y), fmaxf(z1.z, z1.w)));
      L += __logf(zm);
      const float bscale = 256.f / zm;
      if (tid < 96) {
        float4 v = *(const float4*)&tf[wpar][tid * 4];
        int pk = __builtin_amdgcn_cvt_pk_fp8_f32(v.x * bscale, v.y * bscale,
                                                 0, false);
        pk = __builtin_amdgcn_cvt_pk_fp8_f32(v.z * bscale, v.w * bscale,
                                             pk, true);
        tq[tid] = (unsigned)pk;
      }
      __syncthreads();                       // barrier 2
    }
  }

  // epilogue
  const int fpar = K & 1;
  float fp = (tid < RR) ? tf[fpar][tid] : 0.f;
#pragma unroll
  for (int off = 32; off > 0; off >>= 1) fp += __shfl_xor(fp, off);
  if (lane == 0) fred[w] = fp;
  __syncthreads();
  if (tid == 0) {
    float fs = 0.f;
#pragma unroll
    for (int i = 0; i < 8; ++i) fs += fred[i];
    const float fwd = L + __logf(fmaxf(fs, 1e-37f));
    float gold = Em[b * MM + mlist[b * MM + 0]];
    for (int j = 1; j < K; ++j) {
      float bil = 0.f;
#pragma unroll
      for (int c = 0; c < 8; ++c) bil += bilinP[(size_t)(b * 8 + c) * MM + j];
      gold += bil + Em[b * MM + mlist[b * MM + j]];
    }
    result[b] = fwd - gold;
  }
}

// ---------------- Kernel E: final deterministic reduction ----------
__global__ void kE(const float* __restrict__ result, const int* __restrict__ nmen,
                   float* __restrict__ out) {
  if (threadIdx.x == 0 && blockIdx.x == 0) {
    float s = 0.f;
    int d = 0;
    for (int b = 0; b < 32; ++b) { s += result[b]; d += nmen[b]; }
    if (d < 1) d = 1;
    out[0] = s / (float)d;
  }
}

extern "C" void kernel_launch(void* const* d_in, const int* in_sizes, int n_in,
                              void* d_out, int out_size, void* d_ws, size_t ws_size,
                              hipStream_t stream) {
  const float* region = (const float*)d_in[0];
  const float* aff    = (const float*)d_in[1];
  const float* gt     = (const float*)d_in[2];
  const int*   nmen   = (const int*)d_in[3];
  const int*   nreg   = (const int*)d_in[4];
  const float* t0w    = (const float*)d_in[5];
  const float* t0b    = (const float*)d_in[6];
  const float* t1w    = (const float*)d_in[7];
  const float* t1b    = (const float*)d_in[8];
  const float* trw    = (const float*)d_in[9];
  const float* trb    = (const float*)d_in[10];
  float* out = (float*)d_out;
  char* ws = (char*)d_ws;

  size_t off = 0;
  auto alloc = [&](size_t bytes) {
    void* p = ws + off;
    off += (bytes + 255) & ~(size_t)255;
    return p;
  };
  float*         h0h1    = (float*)alloc((size_t)BB * RR * 32 * 4);       // 1.57 MB
  unsigned char* expb    = (unsigned char*)alloc((size_t)BB * RR * RR);   // 4.72 MB
  float*         expTmax = (float*)alloc((size_t)BB * RR * 4);
  int*           mlist   = (int*)alloc((size_t)BB * MM * 4);
  int*           kcnt    = (int*)alloc((size_t)BB * 4);
  float*         Em      = (float*)alloc((size_t)BB * MM * 4);
  float*         bilinP  = (float*)alloc((size_t)BB * 8 * MM * 4);
  float*         result  = (float*)alloc((size_t)BB * 4);

  kA<<<(BB * RR) / 32, 256, 0, stream>>>(region, t0w, t0b, t1w, t1b, h0h1);
  kYT<<<256, 384, 0, stream>>>(h0h1, trw, trb, gt, aff, nmen, nreg,
                               mlist, kcnt, Em, bilinP, expb, expTmax);
  kD<<<BB, 512, 0, stream>>>(expb, expTmax, aff, nreg, mlist, kcnt, Em,
                             bilinP, result);
  kE<<<1, 64, 0, stream>>>(result, nmen, out);
}

// Round 19
// 105.233 us; speedup vs baseline: 3.3023x; 1.0006x over previous
//
#include <hip/hip_runtime.h>

#define NEGV (-100000000.0f)
typedef __attribute__((ext_vector_type(2))) float f32x2;
typedef __attribute__((ext_vector_type(8))) short bf16x8;
typedef __attribute__((ext_vector_type(4))) float f32x4v;

constexpr int BB = 32, MM = 24, RR = 384, DD = 2048;
constexpr int EPITCH = 400;   // eT row pitch (bytes): 100 dwords = 4 mod 32 banks

// pack two f32 -> two bf16 (round half-up)
static __device__ __forceinline__ unsigned pk2bf(float a, float b) {
  unsigned au = __float_as_uint(a) + 0x8000u;
  unsigned bu = __float_as_uint(b) + 0x8000u;
  return (au >> 16) | (bu & 0xffff0000u);
}

// ---------------- Kernel A: cast+MFMA GEMM, 256 thr, depth-3 reg pipeline ---
// 384 blocks; 32 rows x 32 h; K-tiles of 128, double-buffered LDS. Each LOAD
// is in flight ~2 phases before its WRITE (hides ~HBM latency).
__global__ __launch_bounds__(256) void kA(const float* __restrict__ region,
    const float* __restrict__ t0w, const float* __restrict__ t0b,
    const float* __restrict__ t1w, const float* __restrict__ t1b,
    float* __restrict__ h0h1) {
  __shared__ unsigned short Abuf[2][32 * 128];
  __shared__ unsigned short Bbuf[2][32 * 128];
  const int tid = threadIdx.x;
  const int row0 = blockIdx.x * 32;

  const int srow = tid >> 3;       // 0..31
  const int sq = tid & 7;          // eighth of the 128-k tile (16 floats)
  const float* aSrc = region + (size_t)(row0 + srow) * DD + sq * 16;
  const float* bSrc = ((srow < 16) ? (t0w + (size_t)srow * DD)
                                   : (t1w + (size_t)(srow - 16) * DD)) + sq * 16;

  auto LOADS = [&](float4* s, int t) {
    const int d0 = t * 128;
#pragma unroll
    for (int i = 0; i < 4; ++i) s[i] = *(const float4*)(aSrc + d0 + i * 4);
#pragma unroll
    for (int i = 0; i < 4; ++i) s[4 + i] = *(const float4*)(bSrc + d0 + i * 4);
  };
  const int wbase = srow * 256 + sq * 32;
  const int wxor = (srow & 7) << 4;
  auto WRITES = [&](const float4* s, int buf) {
    unsigned char* Ab = (unsigned char*)&Abuf[buf][0];
    unsigned char* Bb = (unsigned char*)&Bbuf[buf][0];
#pragma unroll
    for (int i = 0; i < 2; ++i) {
      float4 x = s[i * 2], y = s[i * 2 + 1];
      uint4 pk;
      pk.x = pk2bf(x.x, x.y); pk.y = pk2bf(x.z, x.w);
      pk.z = pk2bf(y.x, y.y); pk.w = pk2bf(y.z, y.w);
      *(uint4*)(Ab + ((wbase + i * 16) ^ wxor)) = pk;
      float4 u = s[4 + i * 2], v = s[4 + i * 2 + 1];
      uint4 qk;
      qk.x = pk2bf(u.x, u.y); qk.y = pk2bf(u.z, u.w);
      qk.z = pk2bf(v.x, v.y); qk.w = pk2bf(v.z, v.w);
      *(uint4*)(Bb + ((wbase + i * 16) ^ wxor)) = qk;
    }
  };

  const int w = tid >> 6;                 // wave 0..3
  const int rt = w & 1;
  const int ht = w >> 1;
  const int lane = tid & 63;
  const int arow = rt * 16 + (lane & 15);
  const int bh = lane & 15;
  const int brow = ht * 16 + bh;
  const int koff = (lane >> 4) * 8;
  const int axor = (arow & 7) << 4;
  const int bxor = (brow & 7) << 4;

  f32x4v acc = {0.f, 0.f, 0.f, 0.f};
  auto MFMAT = [&](int buf) {
    const unsigned char* Ab = (const unsigned char*)&Abuf[buf][0];
    const unsigned char* Bb = (const unsigned char*)&Bbuf[buf][0];
#pragma unroll
    for (int kk = 0; kk < 4; ++kk) {
      const int kb = (kk * 32 + koff) * 2;
      bf16x8 av = *(const bf16x8*)(Ab + ((arow * 256 + kb) ^ axor));
      bf16x8 bv = *(const bf16x8*)(Bb + ((brow * 256 + kb) ^ bxor));
      acc = __builtin_amdgcn_mfma_f32_16x16x32_bf16(av, bv, acc, 0, 0, 0);
    }
  };

  float4 sA[8], sB[8], sC[8];
  LOADS(sA, 0);
  WRITES(sA, 0);
  LOADS(sB, 1);
  LOADS(sC, 2);
  for (int t = 0; t < 16; t += 3) {
    // phase 0: tile t
    __syncthreads();
    if (t + 1 < 16) WRITES(sB, (t + 1) & 1);
    if (t + 3 < 16) LOADS(sA, t + 3);
    MFMAT(t & 1);
    // phase 1: tile t+1
    if (t + 1 < 16) {
      __syncthreads();
      if (t + 2 < 16) WRITES(sC, (t + 2) & 1);
      if (t + 4 < 16) LOADS(sB, t + 4);
      MFMAT((t + 1) & 1);
    }
    // phase 2: tile t+2
    if (t + 2 < 16) {
      __syncthreads();
      if (t + 3 < 16) WRITES(sA, (t + 3) & 1);
      if (t + 5 < 16) LOADS(sC, t + 5);
      MFMAT(t & 1);
    }
  }

  // epilogue: C/D layout col=lane&15, row=(lane>>4)*4+reg
  const float bias = (ht == 0) ? t0b[bh] : t1b[bh];
#pragma unroll
  for (int i = 0; i < 4; ++i) {
    const int rg = row0 + rt * 16 + (lane >> 4) * 4 + i;
    h0h1[(size_t)rg * 32 + ht * 16 + bh] = acc[i] + bias;
  }
}

// ---------------- Kernel YT: 384 thr; interleaved tran-write columns --------
// grid 256 = (b x 8 chunks of 48 rows). thread = (r 0..47, jq 0..7).
__global__ __launch_bounds__(384) void kYT(const float* __restrict__ h0h1,
    const float* __restrict__ trw, const float* __restrict__ trb,
    const float* __restrict__ gt, const float* __restrict__ aff,
    const int* __restrict__ nmen, const int* __restrict__ nreg,
    int* __restrict__ mlist, int* __restrict__ kcnt, float* __restrict__ Em,
    float* __restrict__ bilinP, unsigned char* __restrict__ expb,
    float* __restrict__ expTmax) {
  __shared__ float h1T[16][388];
  __shared__ float h0L[48][16];
  __shared__ float Tl[48][388];
  __shared__ float RP[MM][392];
  __shared__ float part[48][26];
  __shared__ float rsumL[MM], EmL[MM];
  __shared__ int mlistL[MM];
  __shared__ int kcntL;
  const int b = blockIdx.x & 31;
  const int chunk = blockIdx.x >> 5;
  const int r0 = chunk * 48;
  const int tid = threadIdx.x;
  const int lane = tid & 63;
  const int wv = tid >> 6;
  const int nm = nmen[b], nr = nreg[b];

  // ---- kCM prologue on 6 waves ----
  for (int m = wv; m < MM; m += 6) {
    const size_t bm = (size_t)(b * MM + m);
    float p = 0.f, t1 = 0.f, t2 = 0.f;
#pragma unroll
    for (int i = 0; i < 6; ++i) {
      int s = lane * 6 + i;
      float g = gt[bm * RR + s];
      float a = (g >= 0.5f && s < nr && m < nm) ? g : 0.f;
      float e = aff[bm * RR + s];
      p += a;
      t1 += a * e;
      t2 += (a > 0.f) ? a * __logf(a) : 0.f;
    }
#pragma unroll
    for (int off = 32; off > 0; off >>= 1) {
      p += __shfl_xor(p, off);
      t1 += __shfl_xor(t1, off);
      t2 += __shfl_xor(t2, off);
    }
    if (lane == 0) {
      rsumL[m] = p;
      EmL[m] = (p > 0.f) ? (t1 - t2) / p + __logf(p) : 0.f;
    }
  }
  __syncthreads();
  if (tid == 0) {
    int c = 0;
    for (int m = 0; m < MM; ++m)
      if (rsumL[m] > 0.f) mlistL[c++] = m;
    kcntL = c;
    for (int j = c; j < MM; ++j) mlistL[j] = 0;
  }
  __syncthreads();
  if (chunk == 0 && tid < MM) {
    Em[b * MM + tid] = EmL[tid];
    mlist[b * MM + tid] = mlistL[tid];
    if (tid == 0) kcnt[b] = kcntL;
  }
  const int K = kcntL;

  // ---- staging ----
  for (int h = 0; h < 16; ++h)
    for (int s = tid; s < RR; s += 384)
      h1T[h][s] = h0h1[((size_t)b * RR + s) * 32 + 16 + h];
  for (int i = tid; i < 768; i += 384) {
    int row = i >> 4, h = i & 15;
    h0L[row][h] = h0h1[((size_t)b * RR + r0 + row) * 32 + h];
  }
  for (int j = 0; j < MM; ++j) {
    if (j < K) {
      int m = mlistL[j];
      float inv = 1.f / rsumL[m];
      for (int s = tid; s < RR; s += 384) {
        float g = gt[((size_t)(b * MM + m)) * RR + s];
        RP[j][s] = (g >= 0.5f && s < nr) ? g * inv : 0.f;
      }
    } else {
      for (int s = tid; s < RR; s += 384) RP[j][s] = 0.f;
    }
  }
  float w0[16];
#pragma unroll
  for (int h = 0; h < 16; ++h) w0[h] = trw[h];
  const float tb = trb[0];
  __syncthreads();

  const int r = tid >> 3;        // 0..47
  const int jq = tid & 7;        // 0..7
  const int gr = r0 + r;

  // tran: thread (r,jq) owns interleaved columns s = jq + 8*i
  // write bank = (4r + jq + 8i) mod 32 -> ~2-way (free), was 8-way
  for (int i = 0; i < 48; ++i) {
    const int s = jq + 8 * i;
    float a = tb;
#pragma unroll
    for (int h = 0; h < 16; ++h)
      a += fmaxf(h0L[r][h] + h1T[h][s], 0.f) * w0[h];
    Tl[r][s] = a;
  }
  __syncthreads();

  // ---- fp8 export: row max over 8 jq lanes (contiguous 48-col slices) ----
  {
    float rmax = -3.0e38f;
    for (int c = 0; c < 48; c += 4) {
      float4 v = *(const float4*)&Tl[r][jq * 48 + c];
      rmax = fmaxf(rmax, fmaxf(fmaxf(v.x, v.y), fmaxf(v.z, v.w)));
    }
    rmax = fmaxf(rmax, __shfl_xor(rmax, 1));
    rmax = fmaxf(rmax, __shfl_xor(rmax, 2));
    rmax = fmaxf(rmax, __shfl_xor(rmax, 4));
    if (jq == 0) expTmax[b * RR + gr] = __expf(rmax);
    unsigned char* obase = expb + ((size_t)b * RR + gr) * RR + jq * 48;
#pragma unroll
    for (int c16 = 0; c16 < 3; ++c16) {
      int w4[4];
#pragma unroll
      for (int ii = 0; ii < 4; ++ii) {
        float4 v = *(const float4*)&Tl[r][jq * 48 + c16 * 16 + ii * 4];
        int pk = __builtin_amdgcn_cvt_pk_fp8_f32(__expf(v.x - rmax),
                                                 __expf(v.y - rmax), 0, false);
        pk = __builtin_amdgcn_cvt_pk_fp8_f32(__expf(v.z - rmax),
                                             __expf(v.w - rmax), pk, true);
        w4[ii] = pk;
      }
      *(int4*)(obase + c16 * 16) = make_int4(w4[0], w4[1], w4[2], w4[3]);
    }
  }

  // ---- bilinear partials: 3 j's per thread ----
  float acc[3] = {0, 0, 0};
  for (int s0 = 0; s0 < RR; s0 += 4) {
    float4 tv = *(const float4*)&Tl[r][s0];
#pragma unroll
    for (int jj = 0; jj < 3; ++jj) {
      const float4 p0 = *(const float4*)&RP[jq * 3 + jj][s0];
      acc[jj] = fmaf(tv.x, p0.x, acc[jj]);
      acc[jj] = fmaf(tv.y, p0.y, acc[jj]);
      acc[jj] = fmaf(tv.z, p0.z, acc[jj]);
      acc[jj] = fmaf(tv.w, p0.w, acc[jj]);
    }
  }
#pragma unroll
  for (int jj = 0; jj < 3; ++jj) {
    const int jp = jq * 3 + jj;
    const int j = jp + 1;
    part[r][j] = (j < K) ? RP[j][gr] * acc[jj] : 0.f;
  }
  __syncthreads();
  if (tid < MM) {
    const int j = tid;
    float s = 0.f;
    if (j >= 1) {
#pragma unroll 4
      for (int rr2 = 0; rr2 < 48; ++rr2) s += part[rr2][j];
    }
    bilinP[(size_t)(b * 8 + chunk) * MM + j] = s;
  }
}

// ---------------- Kernel D: fp8 MFMA scan, A-frags hoisted to registers -----
__global__ __launch_bounds__(512, 1) void kD(
    const unsigned char* __restrict__ expb, const float* __restrict__ expTmax,
    const float* __restrict__ aff, const int* __restrict__ nreg,
    const int* __restrict__ mlist, const int* __restrict__ kcnt,
    const float* __restrict__ Em, const float* __restrict__ bilinP,
    float* __restrict__ result) {
  __shared__ unsigned char eT[RR * EPITCH];    // 153600 B, padded rows
  __shared__ float tf[2][RR];
  __shared__ unsigned int tq[RR / 4];
  __shared__ float wred[2][8];
  __shared__ float fred[8];

  const int b = blockIdx.x;
  const int tid = threadIdx.x;
  const int w = tid >> 6;
  const int lane = tid & 63;
  const int r = lane & 15;
  const int q = lane >> 4;
  const bool act = (r == 0);
  const int nr = nreg[b];

  const int K = kcnt[b];
  if (K == 0) {
    if (tid == 0) result[b] = 0.f;
    return;
  }

  {  // stage fp8 tile -> padded LDS rows
    const uint4* src = (const uint4*)(expb + (size_t)b * RR * RR);
#pragma unroll
    for (int j = 0; j < 18; ++j) {
      const int i = tid + j * 512;
      uint4 v = src[i];
      const int row = i / 24;
      const int c = (i - row * 24) * 16;
      *(uint4*)(eT + row * EPITCH + c) = v;
    }
  }
  __syncthreads();

  // hoist my 36 A-fragments (3 row-tiles x 12 kt) into registers
  long long af0[12], af1[12], af2[12];
  {
    const int base = (w * 48 + r) * EPITCH + q * 8;
#pragma unroll
    for (int kt = 0; kt < 12; ++kt) {
      af0[kt] = *(const long long*)(eT + base + kt * 32);
      af1[kt] = *(const long long*)(eT + base + 16 * EPITCH + kt * 32);
      af2[kt] = *(const long long*)(eT + base + 32 * EPITCH + kt * 32);
    }
  }

  float sF4[3][4], eraw4[3][4];
  if (act) {
#pragma unroll
    for (int rt = 0; rt < 3; ++rt) {
      const int rowb = w * 48 + rt * 16 + q * 4;
      *(float4*)sF4[rt] = *(const float4*)&expTmax[b * RR + rowb];
      const int m0 = mlist[b * MM];
      *(float4*)eraw4[rt] =
          *(const float4*)(aff + ((size_t)(b * MM + m0)) * RR + rowb);
    }
  }

  float L = 0.f;

  for (int k = 0; k < K; ++k) {
    const int wpar = (k + 1) & 1;

    float nraw4[3][4] = {{0, 0, 0, 0}, {0, 0, 0, 0}, {0, 0, 0, 0}};
    if (act && k + 1 < K) {
      const int mn = mlist[b * MM + k + 1];
#pragma unroll
      for (int rt = 0; rt < 3; ++rt) {
        const int rowb = w * 48 + rt * 16 + q * 4;
        *(float4*)nraw4[rt] =
            *(const float4*)(aff + ((size_t)(b * MM + mn)) * RR + rowb);
      }
    }

    float tv[3][4] = {{0, 0, 0, 0}, {0, 0, 0, 0}, {0, 0, 0, 0}};
    if (k == 0) {
      if (act) {
#pragma unroll
        for (int rt = 0; rt < 3; ++rt)
#pragma unroll
          for (int i = 0; i < 4; ++i) {
            const int row = w * 48 + rt * 16 + q * 4 + i;
            tv[rt][i] = (row < nr) ? __expf(eraw4[rt][i]) : 0.f;
          }
      }
    } else {
      f32x4v acc0 = {0.f, 0.f, 0.f, 0.f}, acc1 = {0.f, 0.f, 0.f, 0.f},
             acc2 = {0.f, 0.f, 0.f, 0.f};
#pragma unroll
      for (int kt = 0; kt < 12; ++kt) {
        long long bf =
            *(const long long*)((const unsigned char*)tq + kt * 32 + q * 8);
        bf = act ? bf : 0ll;   // only column 0 carries B
        acc0 = __builtin_amdgcn_mfma_f32_16x16x32_fp8_fp8(af0[kt], bf, acc0, 0, 0, 0);
        acc1 = __builtin_amdgcn_mfma_f32_16x16x32_fp8_fp8(af1[kt], bf, acc1, 0, 0, 0);
        acc2 = __builtin_amdgcn_mfma_f32_16x16x32_fp8_fp8(af2[kt], bf, acc2, 0, 0, 0);
      }
      if (act) {
#pragma unroll
        for (int i = 0; i < 4; ++i) {
          tv[0][i] = acc0[i] * (__expf(eraw4[0][i]) * sF4[0][i] * 0.00390625f);
          tv[1][i] = acc1[i] * (__expf(eraw4[1][i]) * sF4[1][i] * 0.00390625f);
          tv[2][i] = acc2[i] * (__expf(eraw4[2][i]) * sF4[2][i] * 0.00390625f);
        }
      }
    }

    float lm = 0.f;
    if (act) {
#pragma unroll
      for (int rt = 0; rt < 3; ++rt) {
        const int rowb = w * 48 + rt * 16 + q * 4;
        *(float4*)&tf[wpar][rowb] =
            make_float4(tv[rt][0], tv[rt][1], tv[rt][2], tv[rt][3]);
        lm = fmaxf(lm, fmaxf(fmaxf(tv[rt][0], tv[rt][1]),
                             fmaxf(tv[rt][2], tv[rt][3])));
      }
#pragma unroll
      for (int rt = 0; rt < 3; ++rt)
#pragma unroll
        for (int i = 0; i < 4; ++i) eraw4[rt][i] = nraw4[rt][i];
    }
    lm = fmaxf(lm, __shfl_xor(lm, 16));
    lm = fmaxf(lm, __shfl_xor(lm, 32));
    if (lane == 0) wred[wpar][w] = lm;
    __syncthreads();                         // barrier 1

    if (k + 1 < K) {
      float4 z0 = *(const float4*)&wred[wpar][0];
      float4 z1 = *(const float4*)&wred[wpar][4];
      float zm = fmaxf(fmaxf(fmaxf(z0.x, z0.y), fmaxf(z0.z, z0.w)),
                       fmaxf(fmaxf(z1.x, z1.y), fmaxf(z1.z, z1.w)));
      L += __logf(zm);
      const float bscale = 256.f / zm;
      if (tid < 96) {
        float4 v = *(const float4*)&tf[wpar][tid * 4];
        int pk = __builtin_amdgcn_cvt_pk_fp8_f32(v.x * bscale, v.y * bscale,
                                                 0, false);
        pk = __builtin_amdgcn_cvt_pk_fp8_f32(v.z * bscale, v.w * bscale,
                                             pk, true);
        tq[tid] = (unsigned)pk;
      }
      __syncthreads();                       // barrier 2
    }
  }

  // epilogue
  const int fpar = K & 1;
  float fp = (tid < RR) ? tf[fpar][tid] : 0.f;
#pragma unroll
  for (int off = 32; off > 0; off >>= 1) fp += __shfl_xor(fp, off);
  if (lane == 0) fred[w] = fp;
  __syncthreads();
  if (tid == 0) {
    float fs = 0.f;
#pragma unroll
    for (int i = 0; i < 8; ++i) fs += fred[i];
    const float fwd = L + __logf(fmaxf(fs, 1e-37f));
    float gold = Em[b * MM + mlist[b * MM + 0]];
    for (int j = 1; j < K; ++j) {
      float bil = 0.f;
#pragma unroll
      for (int c = 0; c < 8; ++c) bil += bilinP[(size_t)(b * 8 + c) * MM + j];
      gold += bil + Em[b * MM + mlist[b * MM + j]];
    }
    result[b] = fwd - gold;
  }
}

// ---------------- Kernel E: final deterministic reduction ----------
__global__ void kE(const float* __restrict__ result, const int* __restrict__ nmen,
                   float* __restrict__ out) {
  if (threadIdx.x == 0 && blockIdx.x == 0) {
    float s = 0.f;
    int d = 0;
    for (int b = 0; b < 32; ++b) { s += result[b]; d += nmen[b]; }
    if (d < 1) d = 1;
    out[0] = s / (float)d;
  }
}

extern "C" void kernel_launch(void* const* d_in, const int* in_sizes, int n_in,
                              void* d_out, int out_size, void* d_ws, size_t ws_size,
                              hipStream_t stream) {
  const float* region = (const float*)d_in[0];
  const float* aff    = (const float*)d_in[1];
  const float* gt     = (const float*)d_in[2];
  const int*   nmen   = (const int*)d_in[3];
  const int*   nreg   = (const int*)d_in[4];
  const float* t0w    = (const float*)d_in[5];
  const float* t0b    = (const float*)d_in[6];
  const float* t1w    = (const float*)d_in[7];
  const float* t1b    = (const float*)d_in[8];
  const float* trw    = (const float*)d_in[9];
  const float* trb    = (const float*)d_in[10];
  float* out = (float*)d_out;
  char* ws = (char*)d_ws;

  size_t off = 0;
  auto alloc = [&](size_t bytes) {
    void* p = ws + off;
    off += (bytes + 255) & ~(size_t)255;
    return p;
  };
  float*         h0h1    = (float*)alloc((size_t)BB * RR * 32 * 4);       // 1.57 MB
  unsigned char* expb    = (unsigned char*)alloc((size_t)BB * RR * RR);   // 4.72 MB
  float*         expTmax = (float*)alloc((size_t)BB * RR * 4);
  int*           mlist   = (int*)alloc((size_t)BB * MM * 4);
  int*           kcnt    = (int*)alloc((size_t)BB * 4);
  float*         Em      = (float*)alloc((size_t)BB * MM * 4);
  float*         bilinP  = (float*)alloc((size_t)BB * 8 * MM * 4);
  float*         result  = (float*)alloc((size_t)BB * 4);

  kA<<<(BB * RR) / 32, 256, 0, stream>>>(region, t0w, t0b, t1w, t1b, h0h1);
  kYT<<<256, 384, 0, stream>>>(h0h1, trw, trb, gt, aff, nmen, nreg,
                               mlist, kcnt, Em, bilinP, expb, expTmax);
  kD<<<BB, 512, 0, stream>>>(expb, expTmax, aff, nreg, mlist, kcnt, Em,
                             bilinP, result);
  kE<<<1, 64, 0, stream>>>(result, nmen, out);
}